// Round 1
// baseline (1724.923 us; speedup 1.0000x reference)
//
#include <hip/hip_runtime.h>
#include <math.h>

// ---------------- CSR build ----------------

__global__ void init_kernel(int* cnt, int* fil, int n) {
    int i = blockIdx.x * blockDim.x + threadIdx.x;
    if (i < n) { cnt[i] = 0; fil[i] = 0; }
}

__global__ void hist_kernel(const int* __restrict__ col, int* __restrict__ cnt, int e) {
    int i = blockIdx.x * blockDim.x + threadIdx.x;
    if (i < e) atomicAdd(&cnt[col[i]], 1);
}

__global__ void dis_kernel(const int* __restrict__ cnt, float* __restrict__ dis, int n) {
    int i = blockIdx.x * blockDim.x + threadIdx.x;
    if (i < n) dis[i] = rsqrtf((float)cnt[i] + 1.0f);  // deg includes self-loop
}

// exclusive scan of cnt -> off (3-kernel, chunk=512)
__global__ void scan1(const int* __restrict__ cnt, int* __restrict__ off,
                      int* __restrict__ bsum, int n) {
    __shared__ int s[512];
    int t = threadIdx.x;
    int i = blockIdx.x * 512 + t;
    int v = (i < n) ? cnt[i] : 0;
    s[t] = v; __syncthreads();
    for (int d = 1; d < 512; d <<= 1) {
        int a = (t >= d) ? s[t - d] : 0;
        __syncthreads();
        s[t] += a;
        __syncthreads();
    }
    if (i < n) off[i] = s[t] - v;          // block-local exclusive
    if (t == 511) bsum[blockIdx.x] = s[511];
}

__global__ void scan2(int* bsum, int nb) {
    __shared__ int s[256];
    int t = threadIdx.x;
    int v = (t < nb) ? bsum[t] : 0;
    s[t] = v; __syncthreads();
    for (int d = 1; d < 256; d <<= 1) {
        int a = (t >= d) ? s[t - d] : 0;
        __syncthreads();
        s[t] += a;
        __syncthreads();
    }
    if (t < nb) bsum[t] = s[t] - v;        // exclusive block offsets
}

__global__ void scan3(int* off, const int* __restrict__ bsum, int n) {
    int i = blockIdx.x * 512 + threadIdx.x;
    if (i < n) off[i] += bsum[blockIdx.x];
}

__global__ void fill_kernel(const int* __restrict__ erow, const int* __restrict__ ecol,
                            const int* __restrict__ off, int* __restrict__ fil,
                            const float* __restrict__ dis,
                            int* __restrict__ srcs, float* __restrict__ wts, int e) {
    int i = blockIdx.x * blockDim.x + threadIdx.x;
    if (i < e) {
        int r = erow[i], c = ecol[i];
        int slot = off[c] + atomicAdd(&fil[c], 1);
        srcs[slot] = r;
        wts[slot] = dis[r] * dis[c];
    }
}

// ---------------- fp32 tiled GEMM: C[M,N] = A[M,K] @ B[K,N] ----------------
// BM=BN=64, BK=8, 256 threads, 4x4 micro-tile per thread.
// accum==0: C = acc (+bias[col] if bias); accum==1: C += acc.

__global__ __launch_bounds__(256) void gemm_f32(
    const float* __restrict__ A, const float* __restrict__ B,
    const float* __restrict__ bias, float* __restrict__ C,
    int M, int N, int K, int accum)
{
    __shared__ __align__(16) float As[8][64];   // As[k][m]
    __shared__ __align__(16) float Bs[8][64];   // Bs[k][n]
    int tid = threadIdx.x;
    int tx = tid & 15, ty = tid >> 4;
    int br = blockIdx.y * 64, bc = blockIdx.x * 64;
    float acc[4][4] = {};
    for (int k0 = 0; k0 < K; k0 += 8) {
        #pragma unroll
        for (int l = 0; l < 2; ++l) {
            int e = l * 256 + tid;
            int m = e >> 3, kk = e & 7;
            int gr = br + m;
            As[kk][m] = (gr < M) ? A[(size_t)gr * K + k0 + kk] : 0.f;
            int k2 = e >> 6, nn = e & 63;
            int gc = bc + nn;
            Bs[k2][nn] = (gc < N) ? B[(size_t)(k0 + k2) * N + gc] : 0.f;
        }
        __syncthreads();
        #pragma unroll
        for (int kk = 0; kk < 8; ++kk) {
            float4 a4 = *(const float4*)&As[kk][ty * 4];
            float4 b4 = *(const float4*)&Bs[kk][tx * 4];
            float av[4] = {a4.x, a4.y, a4.z, a4.w};
            float bv[4] = {b4.x, b4.y, b4.z, b4.w};
            #pragma unroll
            for (int i = 0; i < 4; ++i)
                #pragma unroll
                for (int j = 0; j < 4; ++j)
                    acc[i][j] = fmaf(av[i], bv[j], acc[i][j]);
        }
        __syncthreads();
    }
    #pragma unroll
    for (int i = 0; i < 4; ++i) {
        int r = br + ty * 4 + i;
        if (r >= M) continue;
        #pragma unroll
        for (int j = 0; j < 4; ++j) {
            int c = bc + tx * 4 + j;
            if (c >= N) continue;
            size_t idx = (size_t)r * N + c;
            if (accum) C[idx] += acc[i][j];
            else       C[idx] = acc[i][j] + (bias ? bias[c] : 0.f);
        }
    }
}

// ---------------- aggregation (propagate), F=256: one block per node ----------------
// out[i][f] = relu( bias[f] + dis[i]^2*ht[i][f] + sum_e wts[e]*ht[srcs[e]][f] )

__global__ __launch_bounds__(256) void agg256_kernel(
    const float* __restrict__ ht,
    const int* __restrict__ off, const int* __restrict__ cnt,
    const int* __restrict__ srcs, const float* __restrict__ wts,
    const float* __restrict__ dis, const float* __restrict__ bias,
    float* __restrict__ out, int n)
{
    int i = blockIdx.x;
    int f = threadIdx.x;
    float d = dis[i];
    float acc = ht[(size_t)i * 256 + f] * d * d;
    int beg = off[i], num = cnt[i];
    for (int e = 0; e < num; ++e) {
        int s = srcs[beg + e];
        float w = wts[beg + e];
        acc += ht[(size_t)s * 256 + f] * w;
    }
    out[(size_t)i * 256 + f] = fmaxf(acc + bias[f], 0.f);
}

// F=40 variant: 4 nodes per block, one wave per node (lanes 0..39 active)
__global__ __launch_bounds__(256) void agg40_kernel(
    const float* __restrict__ ht,
    const int* __restrict__ off, const int* __restrict__ cnt,
    const int* __restrict__ srcs, const float* __restrict__ wts,
    const float* __restrict__ dis, const float* __restrict__ bias,
    float* __restrict__ out, int n)
{
    int wave = threadIdx.x >> 6;
    int lane = threadIdx.x & 63;
    int i = blockIdx.x * 4 + wave;
    if (i >= n || lane >= 40) return;
    float d = dis[i];
    float acc = ht[(size_t)i * 40 + lane] * d * d;
    int beg = off[i], num = cnt[i];
    for (int e = 0; e < num; ++e) {
        acc += ht[(size_t)srcs[beg + e] * 40 + lane] * wts[beg + e];
    }
    out[(size_t)i * 40 + lane] = fmaxf(acc + bias[lane], 0.f);
}

// ---------------- log_softmax over 40 classes: one wave per node ----------------
__global__ __launch_bounds__(256) void lsm_kernel(const float* __restrict__ y,
                                                  float* __restrict__ out, int n) {
    int wave = threadIdx.x >> 6;
    int lane = threadIdx.x & 63;
    int i = blockIdx.x * 4 + wave;
    if (i >= n) return;
    float v = (lane < 40) ? y[(size_t)i * 40 + lane] : -INFINITY;
    float m = v;
    for (int o = 32; o; o >>= 1) m = fmaxf(m, __shfl_xor(m, o));
    float ex = (lane < 40) ? expf(v - m) : 0.f;
    float s = ex;
    for (int o = 32; o; o >>= 1) s += __shfl_xor(s, o);
    if (lane < 40) out[(size_t)i * 40 + lane] = (v - m) - logf(s);
}

// ---------------- launch ----------------

extern "C" void kernel_launch(void* const* d_in, const int* in_sizes, int n_in,
                              void* d_out, int out_size, void* d_ws, size_t ws_size,
                              hipStream_t stream)
{
    const float* x  = (const float*)d_in[0];
    const int*   ei = (const int*)d_in[1];
    const float* W1 = (const float*)d_in[2];
    const float* b1 = (const float*)d_in[3];
    const float* W2 = (const float*)d_in[4];
    const float* b2 = (const float*)d_in[5];
    const float* W3 = (const float*)d_in[6];
    const float* b3 = (const float*)d_in[7];
    const float* lw = (const float*)d_in[8];
    const float* lb = (const float*)d_in[9];

    int N = in_sizes[0] / 256;
    int E = in_sizes[1] / 2;
    const int* erow = ei;       // source nodes
    const int* ecol = ei + E;   // target nodes

    char* ws = (char*)d_ws;
    size_t o = 0;
    auto alloc = [&](size_t bytes) -> void* {
        void* p = ws + o;
        o += (bytes + 255) & ~(size_t)255;
        return p;
    };
    int*   cnt  = (int*)alloc((size_t)N * 4);
    int*   off  = (int*)alloc((size_t)(N + 1) * 4);
    int*   fil  = (int*)alloc((size_t)N * 4);
    int*   bsum = (int*)alloc(1024 * 4);
    float* dis  = (float*)alloc((size_t)N * 4);
    int*   srcs = (int*)alloc((size_t)E * 4);
    float* wts  = (float*)alloc((size_t)E * 4);
    float* ht   = (float*)alloc((size_t)N * 256 * 4);
    float* h1   = (float*)alloc((size_t)N * 256 * 4);
    float* h2   = (float*)alloc((size_t)N * 256 * 4);
    float* h3   = (float*)alloc((size_t)N * 40 * 4);
    float* y    = ht;   // ht (N x 256) is dead after layer-3 aggregation; reuse for y (N x 40)

    const int tb = 256;
    init_kernel<<<(N + tb - 1) / tb, tb, 0, stream>>>(cnt, fil, N);
    hist_kernel<<<(E + tb - 1) / tb, tb, 0, stream>>>(ecol, cnt, E);
    dis_kernel<<<(N + tb - 1) / tb, tb, 0, stream>>>(cnt, dis, N);
    int nb = (N + 511) / 512;
    scan1<<<nb, 512, 0, stream>>>(cnt, off, bsum, N);
    scan2<<<1, 256, 0, stream>>>(bsum, nb);
    scan3<<<nb, 512, 0, stream>>>(off, bsum, N);
    fill_kernel<<<(E + tb - 1) / tb, tb, 0, stream>>>(erow, ecol, off, fil, dis, srcs, wts, E);

    dim3 gBig(4, (N + 63) / 64);    // N=256 output cols
    dim3 gSmall(1, (N + 63) / 64);  // 40 output cols

    // layer 1
    gemm_f32<<<gBig, 256, 0, stream>>>(x, W1, nullptr, ht, N, 256, 256, 0);
    agg256_kernel<<<N, 256, 0, stream>>>(ht, off, cnt, srcs, wts, dis, b1, h1, N);
    // layer 2
    gemm_f32<<<gBig, 256, 0, stream>>>(h1, W2, nullptr, ht, N, 256, 256, 0);
    agg256_kernel<<<N, 256, 0, stream>>>(ht, off, cnt, srcs, wts, dis, b2, h2, N);
    // layer 3 (transform to 40 features, then propagate cheap)
    gemm_f32<<<gSmall, 256, 0, stream>>>(h2, W3, nullptr, ht, N, 40, 256, 0);
    agg40_kernel<<<(N + 3) / 4, 256, 0, stream>>>(ht, off, cnt, srcs, wts, dis, b3, h3, N);

    // out = concat(h1,h2,h3) @ lin_w + lin_b  == h1@lw[0:256] + h2@lw[256:512] + h3@lw[512:552] + lb
    gemm_f32<<<gSmall, 256, 0, stream>>>(h1, lw,            lb,      y, N, 40, 256, 0);
    gemm_f32<<<gSmall, 256, 0, stream>>>(h2, lw + 256 * 40, nullptr, y, N, 40, 256, 1);
    gemm_f32<<<gSmall, 256, 0, stream>>>(h3, lw + 512 * 40, nullptr, y, N, 40, 40,  1);

    lsm_kernel<<<(N + 3) / 4, 256, 0, stream>>>(y, (float*)d_out, N);
}

// Round 2
// 863.045 us; speedup vs baseline: 1.9986x; 1.9986x over previous
//
#include <hip/hip_runtime.h>
#include <math.h>

typedef unsigned short u16;
typedef __attribute__((ext_vector_type(8))) short bf16x8;
typedef __attribute__((ext_vector_type(4))) float f32x4;

__device__ __forceinline__ float bf2f(u16 u) {
    union { unsigned u; float f; } v; v.u = (unsigned)u << 16; return v.f;
}
__device__ __forceinline__ u16 f2bf(float f) {
    union { float f; unsigned u; } v; v.f = f;
    unsigned r = v.u + 0x7FFF + ((v.u >> 16) & 1);   // RNE
    return (u16)(r >> 16);
}

// ---------------- CSR build ----------------

__global__ void init_kernel(int* cnt, int* fil, int n) {
    int i = blockIdx.x * blockDim.x + threadIdx.x;
    if (i < n) { cnt[i] = 0; fil[i] = 0; }
}

__global__ void hist_kernel(const int* __restrict__ col, int* __restrict__ cnt, int e) {
    int i = blockIdx.x * blockDim.x + threadIdx.x;
    if (i < e) atomicAdd(&cnt[col[i]], 1);
}

__global__ void dis_kernel(const int* __restrict__ cnt, float* __restrict__ dis, int n) {
    int i = blockIdx.x * blockDim.x + threadIdx.x;
    if (i < n) dis[i] = rsqrtf((float)cnt[i] + 1.0f);  // deg includes self-loop
}

__global__ void scan1(const int* __restrict__ cnt, int* __restrict__ off,
                      int* __restrict__ bsum, int n) {
    __shared__ int s[512];
    int t = threadIdx.x;
    int i = blockIdx.x * 512 + t;
    int v = (i < n) ? cnt[i] : 0;
    s[t] = v; __syncthreads();
    for (int d = 1; d < 512; d <<= 1) {
        int a = (t >= d) ? s[t - d] : 0;
        __syncthreads();
        s[t] += a;
        __syncthreads();
    }
    if (i < n) off[i] = s[t] - v;
    if (t == 511) bsum[blockIdx.x] = s[511];
}

__global__ void scan2(int* bsum, int nb) {
    __shared__ int s[256];
    int t = threadIdx.x;
    int v = (t < nb) ? bsum[t] : 0;
    s[t] = v; __syncthreads();
    for (int d = 1; d < 256; d <<= 1) {
        int a = (t >= d) ? s[t - d] : 0;
        __syncthreads();
        s[t] += a;
        __syncthreads();
    }
    if (t < nb) bsum[t] = s[t] - v;
}

__global__ void scan3(int* off, const int* __restrict__ bsum, int n) {
    int i = blockIdx.x * 512 + threadIdx.x;
    if (i < n) off[i] += bsum[blockIdx.x];
}

__global__ void fill_kernel(const int* __restrict__ erow, const int* __restrict__ ecol,
                            const int* __restrict__ off, int* __restrict__ fil,
                            const float* __restrict__ dis,
                            int* __restrict__ srcs, float* __restrict__ wts, int e) {
    int i = blockIdx.x * blockDim.x + threadIdx.x;
    if (i < e) {
        int r = erow[i], c = ecol[i];
        int slot = off[c] + atomicAdd(&fil[c], 1);
        srcs[slot] = r;
        wts[slot] = dis[r] * dis[c];
    }
}

// ---------------- casts ----------------

__global__ void cast_f2b(const float* __restrict__ in, u16* __restrict__ out, int n4) {
    int i = blockIdx.x * blockDim.x + threadIdx.x;
    if (i < n4) {
        float4 v = ((const float4*)in)[i];
        ushort4 o;
        o.x = f2bf(v.x); o.y = f2bf(v.y); o.z = f2bf(v.z); o.w = f2bf(v.w);
        ((ushort4*)out)[i] = o;
    }
}

// transpose+cast: in fp32 [K][Nin] (col slice starting at col 0 of width ncols)
// -> out bf16 [Npad][Kld], zero-padded outside (ncols x K)
__global__ void tcast(const float* __restrict__ in, u16* __restrict__ out,
                      int K, int Nin, int ncols, int Kld, int Npad) {
    int idx = blockIdx.x * blockDim.x + threadIdx.x;
    if (idx >= Npad * Kld) return;
    int n = idx / Kld, k = idx % Kld;
    float v = (n < ncols && k < K) ? in[(size_t)k * Nin + n] : 0.f;
    out[idx] = f2bf(v);
}

// ---------------- MFMA bf16 GEMM: C[M,Ncols] = A[M,K](bf16) @ Bt[N,K](bf16)^T ----------------
// 128x128 tile, BK=32, 4 waves (2x2), each wave 64x64 out (4x4 frags of 16x16x32).
// flags: 0 = fp32 store (+bias), 1 = fp32 accumulate (+bias if set), 2 = bf16 store (+bias)

#define SWZ(row) ((((row) & 3) ^ (((row) >> 2) & 3)))

__device__ __forceinline__ void gload_lds16(const void* g, void* l) {
    __builtin_amdgcn_global_load_lds(
        (const __attribute__((address_space(1))) unsigned int*)g,
        (__attribute__((address_space(3))) unsigned int*)l, 16, 0, 0);
}

__global__ __launch_bounds__(256) void gemm_mfma(
    const u16* __restrict__ A, int lda,
    const u16* __restrict__ Bt, int ldb,
    const float* __restrict__ bias,
    void* __restrict__ C, int ldc,
    int M, int Ncols, int K, int flags)
{
    __shared__ u16 As[128 * 32];   // [row][32k] bf16, 64B rows, physically swizzled
    __shared__ u16 Bs[128 * 32];
    int tid = threadIdx.x;
    int ln = tid & 63, wv = tid >> 6;
    int wr = wv >> 1, wc = wv & 1;
    int br = blockIdx.y * 128, bc = blockIdx.x * 128;

    f32x4 acc[4][4];
    #pragma unroll
    for (int m = 0; m < 4; ++m)
        #pragma unroll
        for (int n = 0; n < 4; ++n)
            acc[m][n] = (f32x4){0.f, 0.f, 0.f, 0.f};

    for (int k0 = 0; k0 < K; k0 += 32) {
        __syncthreads();   // previous iteration's reads done before overwrite
        #pragma unroll
        for (int r = 0; r < 2; ++r) {
            int l = r * 256 + tid;         // linear 16B-chunk index in tile
            int row = l >> 2;              // 4 chunks per 64B row
            int sp = l & 3;                // physical 16B slot
            int sl = sp ^ SWZ(row);        // logical slot (pre-swizzled source)
            int arow = br + row; if (arow >= M) arow = M - 1;
            const u16* ga = A + (size_t)arow * lda + k0 + sl * 8;
            const u16* gb = Bt + (size_t)(bc + row) * ldb + k0 + sl * 8;
            unsigned lbase = r * 4096 + wv * 1024;   // wave-uniform dest
            gload_lds16(ga, (char*)As + lbase);
            gload_lds16(gb, (char*)Bs + lbase);
        }
        __syncthreads();
        bf16x8 af[4], bf_[4];
        #pragma unroll
        for (int m = 0; m < 4; ++m) {
            int row = wr * 64 + m * 16 + (ln & 15);
            int sl = ((ln >> 4) ^ SWZ(row)) & 3;
            af[m] = *(const bf16x8*)((const char*)As + row * 64 + sl * 16);
        }
        #pragma unroll
        for (int n = 0; n < 4; ++n) {
            int row = wc * 64 + n * 16 + (ln & 15);
            int sl = ((ln >> 4) ^ SWZ(row)) & 3;
            bf_[n] = *(const bf16x8*)((const char*)Bs + row * 64 + sl * 16);
        }
        #pragma unroll
        for (int m = 0; m < 4; ++m)
            #pragma unroll
            for (int n = 0; n < 4; ++n)
                acc[m][n] = __builtin_amdgcn_mfma_f32_16x16x32_bf16(af[m], bf_[n], acc[m][n], 0, 0, 0);
    }

    #pragma unroll
    for (int m = 0; m < 4; ++m) {
        #pragma unroll
        for (int n = 0; n < 4; ++n) {
            #pragma unroll
            for (int j = 0; j < 4; ++j) {
                int r = br + wr * 64 + m * 16 + (ln >> 4) * 4 + j;
                int c = bc + wc * 64 + n * 16 + (ln & 15);
                if (r < M && c < Ncols) {
                    float v = acc[m][n][j];
                    if (bias) v += bias[c];
                    if (flags == 1)      ((float*)C)[(size_t)r * ldc + c] += v;
                    else if (flags == 2) ((u16*)C)[(size_t)r * ldc + c] = f2bf(v);
                    else                 ((float*)C)[(size_t)r * ldc + c] = v;
                }
            }
        }
    }
}

// ---------------- aggregation F=256 bf16: wave per node ----------------
// out[i][f] = relu( bias[f] + dis[i]^2*ht[i][f] + sum_e wts[e]*ht[srcs[e]][f] )

__global__ __launch_bounds__(256) void agg256_bf16(
    const u16* __restrict__ ht,
    const int* __restrict__ off, const int* __restrict__ cnt,
    const int* __restrict__ srcs, const float* __restrict__ wts,
    const float* __restrict__ dis, const float* __restrict__ bias,
    u16* __restrict__ outb, int n)
{
    int wv = threadIdx.x >> 6, ln = threadIdx.x & 63;
    int i = blockIdx.x * 4 + wv;
    if (i >= n) return;
    int c = ln * 4;
    float d = dis[i], dd = d * d;
    ushort4 sv = *(const ushort4*)(ht + (size_t)i * 256 + c);
    float a0 = bf2f(sv.x) * dd, a1 = bf2f(sv.y) * dd, a2 = bf2f(sv.z) * dd, a3 = bf2f(sv.w) * dd;
    int beg = off[i], num = cnt[i];
    int e = 0;
    for (; e + 2 <= num; e += 2) {
        int s0 = srcs[beg + e], s1 = srcs[beg + e + 1];
        float w0 = wts[beg + e], w1 = wts[beg + e + 1];
        ushort4 v0 = *(const ushort4*)(ht + (size_t)s0 * 256 + c);
        ushort4 v1 = *(const ushort4*)(ht + (size_t)s1 * 256 + c);
        a0 += bf2f(v0.x) * w0 + bf2f(v1.x) * w1;
        a1 += bf2f(v0.y) * w0 + bf2f(v1.y) * w1;
        a2 += bf2f(v0.z) * w0 + bf2f(v1.z) * w1;
        a3 += bf2f(v0.w) * w0 + bf2f(v1.w) * w1;
    }
    if (e < num) {
        int s0 = srcs[beg + e];
        float w0 = wts[beg + e];
        ushort4 v0 = *(const ushort4*)(ht + (size_t)s0 * 256 + c);
        a0 += bf2f(v0.x) * w0; a1 += bf2f(v0.y) * w0;
        a2 += bf2f(v0.z) * w0; a3 += bf2f(v0.w) * w0;
    }
    float4 bv = *(const float4*)(bias + c);
    ushort4 o;
    o.x = f2bf(fmaxf(a0 + bv.x, 0.f));
    o.y = f2bf(fmaxf(a1 + bv.y, 0.f));
    o.z = f2bf(fmaxf(a2 + bv.z, 0.f));
    o.w = f2bf(fmaxf(a3 + bv.w, 0.f));
    *(ushort4*)(outb + (size_t)i * 256 + c) = o;
}

// F=40 variant (ht stride 64, out stride 64 zero-padded): wave per node
__global__ __launch_bounds__(256) void agg40_bf16(
    const u16* __restrict__ ht,
    const int* __restrict__ off, const int* __restrict__ cnt,
    const int* __restrict__ srcs, const float* __restrict__ wts,
    const float* __restrict__ dis, const float* __restrict__ bias,
    u16* __restrict__ outb, int n)
{
    int wv = threadIdx.x >> 6, ln = threadIdx.x & 63;
    int i = blockIdx.x * 4 + wv;
    if (i >= n) return;
    float acc = 0.f;
    if (ln < 40) {
        float d = dis[i];
        acc = bf2f(ht[(size_t)i * 64 + ln]) * d * d;
        int beg = off[i], num = cnt[i];
        for (int e = 0; e < num; ++e)
            acc += bf2f(ht[(size_t)srcs[beg + e] * 64 + ln]) * wts[beg + e];
        acc = fmaxf(acc + bias[ln], 0.f);
    }
    outb[(size_t)i * 64 + ln] = (ln < 40) ? f2bf(acc) : (u16)0;
}

// ---------------- log_softmax over 40 classes: one wave per node ----------------
__global__ __launch_bounds__(256) void lsm_kernel(const float* __restrict__ y,
                                                  float* __restrict__ out, int n) {
    int wv = threadIdx.x >> 6, ln = threadIdx.x & 63;
    int i = blockIdx.x * 4 + wv;
    if (i >= n) return;
    float v = (ln < 40) ? y[(size_t)i * 40 + ln] : -INFINITY;
    float m = v;
    for (int o = 32; o; o >>= 1) m = fmaxf(m, __shfl_xor(m, o));
    float ex = (ln < 40) ? expf(v - m) : 0.f;
    float s = ex;
    for (int o = 32; o; o >>= 1) s += __shfl_xor(s, o);
    if (ln < 40) out[(size_t)i * 40 + ln] = (v - m) - logf(s);
}

// ---------------- launch ----------------

extern "C" void kernel_launch(void* const* d_in, const int* in_sizes, int n_in,
                              void* d_out, int out_size, void* d_ws, size_t ws_size,
                              hipStream_t stream)
{
    const float* x  = (const float*)d_in[0];
    const int*   ei = (const int*)d_in[1];
    const float* W1 = (const float*)d_in[2];
    const float* b1 = (const float*)d_in[3];
    const float* W2 = (const float*)d_in[4];
    const float* b2 = (const float*)d_in[5];
    const float* W3 = (const float*)d_in[6];
    const float* b3 = (const float*)d_in[7];
    const float* lw = (const float*)d_in[8];
    const float* lb = (const float*)d_in[9];

    int N = in_sizes[0] / 256;
    int E = in_sizes[1] / 2;
    const int* erow = ei;       // source nodes
    const int* ecol = ei + E;   // target nodes

    char* ws = (char*)d_ws;
    size_t o = 0;
    auto alloc = [&](size_t bytes) -> void* {
        void* p = ws + o;
        o += (bytes + 255) & ~(size_t)255;
        return p;
    };
    int*   cnt  = (int*)alloc((size_t)N * 4);
    int*   off  = (int*)alloc((size_t)(N + 1) * 4);
    int*   fil  = (int*)alloc((size_t)N * 4);
    int*   bsum = (int*)alloc(1024 * 4);
    float* dis  = (float*)alloc((size_t)N * 4);
    int*   srcs = (int*)alloc((size_t)E * 4);
    float* wts  = (float*)alloc((size_t)E * 4);
    u16*   W1t  = (u16*)alloc(256 * 256 * 2);
    u16*   W2t  = (u16*)alloc(256 * 256 * 2);
    u16*   W3t  = (u16*)alloc(128 * 256 * 2);
    u16*   lwAt = (u16*)alloc(128 * 256 * 2);
    u16*   lwBt = (u16*)alloc(128 * 256 * 2);
    u16*   lwCt = (u16*)alloc(128 * 64 * 2);
    u16*   xb   = (u16*)alloc((size_t)N * 256 * 2);
    u16*   htb  = (u16*)alloc((size_t)N * 256 * 2);   // pre-agg transform, reused per layer
    u16*   h1b  = (u16*)alloc((size_t)N * 256 * 2);
    u16*   h2b  = (u16*)alloc((size_t)N * 256 * 2);
    u16*   h3b  = (u16*)alloc((size_t)N * 64 * 2);
    float* y    = (float*)alloc((size_t)N * 40 * 4);
    u16*   ht3b = htb;                                 // [N][64] view, reuse

    const int tb = 256;
    // CSR
    init_kernel<<<(N + tb - 1) / tb, tb, 0, stream>>>(cnt, fil, N);
    hist_kernel<<<(E + tb - 1) / tb, tb, 0, stream>>>(ecol, cnt, E);
    dis_kernel<<<(N + tb - 1) / tb, tb, 0, stream>>>(cnt, dis, N);
    int nb = (N + 511) / 512;
    scan1<<<nb, 512, 0, stream>>>(cnt, off, bsum, N);
    scan2<<<1, 256, 0, stream>>>(bsum, nb);
    scan3<<<nb, 512, 0, stream>>>(off, bsum, N);
    fill_kernel<<<(E + tb - 1) / tb, tb, 0, stream>>>(erow, ecol, off, fil, dis, srcs, wts, E);

    // casts / weight transposes
    cast_f2b<<<(N * 64 + tb - 1) / tb, tb, 0, stream>>>(x, xb, N * 64);
    tcast<<<(256 * 256 + tb - 1) / tb, tb, 0, stream>>>(W1, W1t, 256, 256, 256, 256, 256);
    tcast<<<(256 * 256 + tb - 1) / tb, tb, 0, stream>>>(W2, W2t, 256, 256, 256, 256, 256);
    tcast<<<(128 * 256 + tb - 1) / tb, tb, 0, stream>>>(W3, W3t, 256, 40, 40, 256, 128);
    tcast<<<(128 * 256 + tb - 1) / tb, tb, 0, stream>>>(lw,            lwAt, 256, 40, 40, 256, 128);
    tcast<<<(128 * 256 + tb - 1) / tb, tb, 0, stream>>>(lw + 256 * 40, lwBt, 256, 40, 40, 256, 128);
    tcast<<<(128 * 64  + tb - 1) / tb, tb, 0, stream>>>(lw + 512 * 40, lwCt, 40, 40, 40, 64, 128);

    dim3 gBig(2, (N + 127) / 128);
    dim3 gSm(1, (N + 127) / 128);
    int nAgg = (N + 3) / 4;

    // layer 1
    gemm_mfma<<<gBig, 256, 0, stream>>>(xb, 256, W1t, 256, nullptr, htb, 256, N, 256, 256, 2);
    agg256_bf16<<<nAgg, 256, 0, stream>>>(htb, off, cnt, srcs, wts, dis, b1, h1b, N);
    // layer 2
    gemm_mfma<<<gBig, 256, 0, stream>>>(h1b, 256, W2t, 256, nullptr, htb, 256, N, 256, 256, 2);
    agg256_bf16<<<nAgg, 256, 0, stream>>>(htb, off, cnt, srcs, wts, dis, b2, h2b, N);
    // layer 3 (transform to 40 features first, propagate cheap)
    gemm_mfma<<<gSm, 256, 0, stream>>>(h2b, 256, W3t, 256, nullptr, ht3b, 64, N, 40, 256, 2);
    agg40_bf16<<<nAgg, 256, 0, stream>>>(ht3b, off, cnt, srcs, wts, dis, b3, h3b, N);

    // out = h1@lwA + h2@lwB + h3@lwC + lb
    gemm_mfma<<<gSm, 256, 0, stream>>>(h1b, 256, lwAt, 256, lb,      y, 40, N, 40, 256, 0);
    gemm_mfma<<<gSm, 256, 0, stream>>>(h2b, 256, lwBt, 256, nullptr, y, 40, N, 40, 256, 1);
    gemm_mfma<<<gSm, 256, 0, stream>>>(h3b, 64,  lwCt, 64,  nullptr, y, 40, N, 40, 64,  1);

    lsm_kernel<<<nAgg, 256, 0, stream>>>(y, (float*)d_out, N);
}

// Round 3
// 648.626 us; speedup vs baseline: 2.6593x; 1.3306x over previous
//
#include <hip/hip_runtime.h>
#include <math.h>

typedef unsigned short u16;
typedef unsigned int u32;
typedef __attribute__((ext_vector_type(8))) short bf16x8;
typedef __attribute__((ext_vector_type(4))) float f32x4;

__device__ __forceinline__ float bf2f(u16 u) {
    union { unsigned u; float f; } v; v.u = (unsigned)u << 16; return v.f;
}
__device__ __forceinline__ u16 f2bf(float f) {
    union { float f; unsigned u; } v; v.f = f;
    unsigned r = v.u + 0x7FFF + ((v.u >> 16) & 1);   // RNE
    return (u16)(r >> 16);
}

// ---------------- CSR build ----------------

__global__ void init_kernel(int* cnt, int* fil, int n) {
    int i = blockIdx.x * blockDim.x + threadIdx.x;
    if (i < n) { cnt[i] = 0; fil[i] = 0; }
}

__global__ void hist_kernel(const int* __restrict__ col, int* __restrict__ cnt, int e) {
    int i = blockIdx.x * blockDim.x + threadIdx.x;
    if (i < e) atomicAdd(&cnt[col[i]], 1);
}

__global__ void dis_kernel(const int* __restrict__ cnt, float* __restrict__ dis, int n) {
    int i = blockIdx.x * blockDim.x + threadIdx.x;
    if (i < n) dis[i] = rsqrtf((float)cnt[i] + 1.0f);  // deg includes self-loop
}

__global__ void scan1(const int* __restrict__ cnt, int* __restrict__ off,
                      int* __restrict__ bsum, int n) {
    __shared__ int s[512];
    int t = threadIdx.x;
    int i = blockIdx.x * 512 + t;
    int v = (i < n) ? cnt[i] : 0;
    s[t] = v; __syncthreads();
    for (int d = 1; d < 512; d <<= 1) {
        int a = (t >= d) ? s[t - d] : 0;
        __syncthreads();
        s[t] += a;
        __syncthreads();
    }
    if (i < n) off[i] = s[t] - v;
    if (t == 511) bsum[blockIdx.x] = s[511];
}

__global__ void scan2(int* bsum, int nb) {
    __shared__ int s[256];
    int t = threadIdx.x;
    int v = (t < nb) ? bsum[t] : 0;
    s[t] = v; __syncthreads();
    for (int d = 1; d < 256; d <<= 1) {
        int a = (t >= d) ? s[t - d] : 0;
        __syncthreads();
        s[t] += a;
        __syncthreads();
    }
    if (t < nb) bsum[t] = s[t] - v;
}

__global__ void scan3(int* off, const int* __restrict__ bsum, int n) {
    int i = blockIdx.x * 512 + threadIdx.x;
    if (i < n) off[i] += bsum[blockIdx.x];
}

__global__ void fill_kernel(const int* __restrict__ erow, const int* __restrict__ ecol,
                            const int* __restrict__ off, int* __restrict__ fil,
                            const float* __restrict__ dis,
                            int* __restrict__ srcs, float* __restrict__ wts, int e) {
    int i = blockIdx.x * blockDim.x + threadIdx.x;
    if (i < e) {
        int r = erow[i], c = ecol[i];
        int slot = off[c] + atomicAdd(&fil[c], 1);
        srcs[slot] = r;
        wts[slot] = dis[r] * dis[c];
    }
}

// ---------------- casts ----------------

__global__ void cast_f2b(const float* __restrict__ in, u16* __restrict__ out, int n4) {
    int i = blockIdx.x * blockDim.x + threadIdx.x;
    if (i < n4) {
        float4 v = ((const float4*)in)[i];
        ushort4 o;
        o.x = f2bf(v.x); o.y = f2bf(v.y); o.z = f2bf(v.z); o.w = f2bf(v.w);
        ((ushort4*)out)[i] = o;
    }
}

// transpose+cast: in fp32 [K][Nin] -> out bf16 [Npad][Kld], zero-padded
__global__ void tcast(const float* __restrict__ in, u16* __restrict__ out,
                      int K, int Nin, int ncols, int Kld, int Npad) {
    int idx = blockIdx.x * blockDim.x + threadIdx.x;
    if (idx >= Npad * Kld) return;
    int n = idx / Kld, k = idx % Kld;
    float v = (n < ncols && k < K) ? in[(size_t)k * Nin + n] : 0.f;
    out[idx] = f2bf(v);
}

// ---------------- MFMA bf16 GEMM: C[M,Ncols] = A[M,K](bf16) @ Bt[N,K](bf16)^T ----------------
// 128x128 tile, BK=32, 4 waves (2x2). flags: 2 = bf16 store (+bias if set)

#define SWZ(row) ((((row) & 3) ^ (((row) >> 2) & 3)))

__device__ __forceinline__ void gload_lds16(const void* g, void* l) {
    __builtin_amdgcn_global_load_lds(
        (const __attribute__((address_space(1))) unsigned int*)g,
        (__attribute__((address_space(3))) unsigned int*)l, 16, 0, 0);
}

__global__ __launch_bounds__(256) void gemm_mfma(
    const u16* __restrict__ A, int lda,
    const u16* __restrict__ Bt, int ldb,
    const float* __restrict__ bias,
    void* __restrict__ C, int ldc,
    int M, int Ncols, int K, int flags)
{
    __shared__ u16 As[128 * 32];
    __shared__ u16 Bs[128 * 32];
    int tid = threadIdx.x;
    int ln = tid & 63, wv = tid >> 6;
    int wr = wv >> 1, wc = wv & 1;
    int br = blockIdx.y * 128, bc = blockIdx.x * 128;

    f32x4 acc[4][4];
    #pragma unroll
    for (int m = 0; m < 4; ++m)
        #pragma unroll
        for (int n = 0; n < 4; ++n)
            acc[m][n] = (f32x4){0.f, 0.f, 0.f, 0.f};

    for (int k0 = 0; k0 < K; k0 += 32) {
        __syncthreads();
        #pragma unroll
        for (int r = 0; r < 2; ++r) {
            int l = r * 256 + tid;
            int row = l >> 2;
            int sp = l & 3;
            int sl = sp ^ SWZ(row);
            int arow = br + row; if (arow >= M) arow = M - 1;
            const u16* ga = A + (size_t)arow * lda + k0 + sl * 8;
            const u16* gb = Bt + (size_t)(bc + row) * ldb + k0 + sl * 8;
            unsigned lbase = r * 4096 + wv * 1024;
            gload_lds16(ga, (char*)As + lbase);
            gload_lds16(gb, (char*)Bs + lbase);
        }
        __syncthreads();
        bf16x8 af[4], bf_[4];
        #pragma unroll
        for (int m = 0; m < 4; ++m) {
            int row = wr * 64 + m * 16 + (ln & 15);
            int sl = ((ln >> 4) ^ SWZ(row)) & 3;
            af[m] = *(const bf16x8*)((const char*)As + row * 64 + sl * 16);
        }
        #pragma unroll
        for (int n = 0; n < 4; ++n) {
            int row = wc * 64 + n * 16 + (ln & 15);
            int sl = ((ln >> 4) ^ SWZ(row)) & 3;
            bf_[n] = *(const bf16x8*)((const char*)Bs + row * 64 + sl * 16);
        }
        #pragma unroll
        for (int m = 0; m < 4; ++m)
            #pragma unroll
            for (int n = 0; n < 4; ++n)
                acc[m][n] = __builtin_amdgcn_mfma_f32_16x16x32_bf16(af[m], bf_[n], acc[m][n], 0, 0, 0);
    }

    #pragma unroll
    for (int m = 0; m < 4; ++m) {
        #pragma unroll
        for (int n = 0; n < 4; ++n) {
            #pragma unroll
            for (int j = 0; j < 4; ++j) {
                int r = br + wr * 64 + m * 16 + (ln >> 4) * 4 + j;
                int c = bc + wc * 64 + n * 16 + (ln & 15);
                if (r < M && c < Ncols) {
                    float v = acc[m][n][j];
                    if (bias) v += bias[c];
                    if (flags == 2) ((u16*)C)[(size_t)r * ldc + c] = f2bf(v);
                    else            ((float*)C)[(size_t)r * ldc + c] = v;
                }
            }
        }
    }
}

// ---------------- fused final: out = lsm(h1@B0 + h2@B1 + h3@B2 + lb) ----------------
// 128 rows/block, cols 0..63 (40 valid). 4 waves, wave wv -> rows wv*32..wv*32+31.

__global__ __launch_bounds__(256) void gemm3_lsm(
    const u16* __restrict__ A0, const u16* __restrict__ A1, const u16* __restrict__ A2,
    const u16* __restrict__ B0, const u16* __restrict__ B1, const u16* __restrict__ B2,
    const float* __restrict__ bias,
    float* __restrict__ out, int M)
{
    __shared__ u16 As[128 * 32];
    __shared__ u16 Bs[64 * 32];
    int tid = threadIdx.x;
    int ln = tid & 63, wv = tid >> 6;
    int br = blockIdx.x * 128;

    f32x4 acc[2][4];
    #pragma unroll
    for (int m = 0; m < 2; ++m)
        #pragma unroll
        for (int n = 0; n < 4; ++n)
            acc[m][n] = (f32x4){0.f, 0.f, 0.f, 0.f};

    auto do_seg = [&](const u16* __restrict__ A, const u16* __restrict__ B, int K) {
        for (int k0 = 0; k0 < K; k0 += 32) {
            __syncthreads();
            #pragma unroll
            for (int r = 0; r < 2; ++r) {
                int l = r * 256 + tid;
                int row = l >> 2, sp = l & 3;
                int sl = sp ^ SWZ(row);
                int arow = br + row; if (arow >= M) arow = M - 1;
                gload_lds16(A + (size_t)arow * K + k0 + sl * 8,
                            (char*)As + r * 4096 + wv * 1024);
            }
            {
                int l = tid;
                int row = l >> 2, sp = l & 3;
                int sl = sp ^ SWZ(row);
                gload_lds16(B + (size_t)row * K + k0 + sl * 8,
                            (char*)Bs + wv * 1024);
            }
            __syncthreads();
            bf16x8 af[2], bf_[4];
            #pragma unroll
            for (int m = 0; m < 2; ++m) {
                int row = wv * 32 + m * 16 + (ln & 15);
                int sl = ((ln >> 4) ^ SWZ(row)) & 3;
                af[m] = *(const bf16x8*)((const char*)As + row * 64 + sl * 16);
            }
            #pragma unroll
            for (int nn = 0; nn < 4; ++nn) {
                int row = nn * 16 + (ln & 15);
                int sl = ((ln >> 4) ^ SWZ(row)) & 3;
                bf_[nn] = *(const bf16x8*)((const char*)Bs + row * 64 + sl * 16);
            }
            #pragma unroll
            for (int m = 0; m < 2; ++m)
                #pragma unroll
                for (int nn = 0; nn < 4; ++nn)
                    acc[m][nn] = __builtin_amdgcn_mfma_f32_16x16x32_bf16(af[m], bf_[nn], acc[m][nn], 0, 0, 0);
        }
    };
    do_seg(A0, B0, 256);
    do_seg(A1, B1, 256);
    do_seg(A2, B2, 64);

    // epilogue: bias + log_softmax over cols 0..39
    int l15 = ln & 15;
    #pragma unroll
    for (int m = 0; m < 2; ++m) {
        #pragma unroll
        for (int j = 0; j < 4; ++j) {
            int r = br + wv * 32 + m * 16 + (ln >> 4) * 4 + j;
            float v0 = acc[m][0][j] + bias[l15];
            float v1 = acc[m][1][j] + bias[16 + l15];
            float v2 = (l15 < 8) ? (acc[m][2][j] + bias[32 + l15]) : -INFINITY;
            float mx = fmaxf(fmaxf(v0, v1), v2);
            #pragma unroll
            for (int o = 8; o; o >>= 1) mx = fmaxf(mx, __shfl_xor(mx, o));
            float s = expf(v0 - mx) + expf(v1 - mx) + ((l15 < 8) ? expf(v2 - mx) : 0.f);
            #pragma unroll
            for (int o = 8; o; o >>= 1) s += __shfl_xor(s, o);
            float ls = logf(s);
            if (r < M) {
                out[(size_t)r * 40 + l15]      = v0 - mx - ls;
                out[(size_t)r * 40 + 16 + l15] = v1 - mx - ls;
                if (l15 < 8) out[(size_t)r * 40 + 32 + l15] = v2 - mx - ls;
            }
        }
    }
}

// ---------------- aggregation F=256 bf16: wave per node, shfl-broadcast edges ----------------

__global__ __launch_bounds__(256) void agg256_bf16(
    const u16* __restrict__ ht,
    const int* __restrict__ off, const int* __restrict__ cnt,
    const int* __restrict__ srcs, const float* __restrict__ wts,
    const float* __restrict__ dis, const float* __restrict__ bias,
    u16* __restrict__ outb, int n)
{
    int wv = threadIdx.x >> 6, ln = threadIdx.x & 63;
    int i = blockIdx.x * 4 + wv;
    if (i >= n) return;
    int c = ln * 4;
    float d = dis[i], dd = d * d;
    ushort4 sv = *(const ushort4*)(ht + (size_t)i * 256 + c);
    float a0 = bf2f(sv.x) * dd, a1 = bf2f(sv.y) * dd, a2 = bf2f(sv.z) * dd, a3 = bf2f(sv.w) * dd;
    int beg = off[i], num = cnt[i];
    for (int base = 0; base < num; base += 64) {
        int rem = num - base; if (rem > 64) rem = 64;
        int sl = 0; float wl = 0.f;
        if (ln < rem) { sl = srcs[beg + base + ln]; wl = wts[beg + base + ln]; }
        int j = 0;
        for (; j + 4 <= rem; j += 4) {
            int s0 = __shfl(sl, j),     s1 = __shfl(sl, j + 1);
            int s2 = __shfl(sl, j + 2), s3 = __shfl(sl, j + 3);
            float w0 = __shfl(wl, j),     w1 = __shfl(wl, j + 1);
            float w2 = __shfl(wl, j + 2), w3 = __shfl(wl, j + 3);
            ushort4 v0 = *(const ushort4*)(ht + (size_t)s0 * 256 + c);
            ushort4 v1 = *(const ushort4*)(ht + (size_t)s1 * 256 + c);
            ushort4 v2 = *(const ushort4*)(ht + (size_t)s2 * 256 + c);
            ushort4 v3 = *(const ushort4*)(ht + (size_t)s3 * 256 + c);
            a0 += bf2f(v0.x) * w0 + bf2f(v1.x) * w1 + bf2f(v2.x) * w2 + bf2f(v3.x) * w3;
            a1 += bf2f(v0.y) * w0 + bf2f(v1.y) * w1 + bf2f(v2.y) * w2 + bf2f(v3.y) * w3;
            a2 += bf2f(v0.z) * w0 + bf2f(v1.z) * w1 + bf2f(v2.z) * w2 + bf2f(v3.z) * w3;
            a3 += bf2f(v0.w) * w0 + bf2f(v1.w) * w1 + bf2f(v2.w) * w2 + bf2f(v3.w) * w3;
        }
        for (; j < rem; ++j) {
            int s0 = __shfl(sl, j);
            float w0 = __shfl(wl, j);
            ushort4 v0 = *(const ushort4*)(ht + (size_t)s0 * 256 + c);
            a0 += bf2f(v0.x) * w0; a1 += bf2f(v0.y) * w0;
            a2 += bf2f(v0.z) * w0; a3 += bf2f(v0.w) * w0;
        }
    }
    float4 bv = *(const float4*)(bias + c);
    ushort4 o;
    o.x = f2bf(fmaxf(a0 + bv.x, 0.f));
    o.y = f2bf(fmaxf(a1 + bv.y, 0.f));
    o.z = f2bf(fmaxf(a2 + bv.z, 0.f));
    o.w = f2bf(fmaxf(a3 + bv.w, 0.f));
    *(ushort4*)(outb + (size_t)i * 256 + c) = o;
}

// F=40 (stride 64): HALF-wave per node, uint loads (2 feats/lane), shfl width 32
__global__ __launch_bounds__(256) void agg40_bf16(
    const u16* __restrict__ ht,
    const int* __restrict__ off, const int* __restrict__ cnt,
    const int* __restrict__ srcs, const float* __restrict__ wts,
    const float* __restrict__ dis, const float* __restrict__ bias,
    u16* __restrict__ outb, int n)
{
    int half = threadIdx.x >> 5;     // 0..7
    int l = threadIdx.x & 31;
    int i = blockIdx.x * 8 + half;
    if (i >= n) return;
    int c2 = l * 2;                  // feature pair (cols 40..63 are zero-pad)
    float d = dis[i], dd = d * d;
    u32 sv = *(const u32*)(ht + (size_t)i * 64 + c2);
    float a0 = bf2f((u16)(sv & 0xffff)) * dd;
    float a1 = bf2f((u16)(sv >> 16)) * dd;
    int beg = off[i], num = cnt[i];
    for (int base = 0; base < num; base += 32) {
        int rem = num - base; if (rem > 32) rem = 32;
        int sl = 0; float wl = 0.f;
        if (l < rem) { sl = srcs[beg + base + l]; wl = wts[beg + base + l]; }
        int j = 0;
        for (; j + 4 <= rem; j += 4) {
            int s0 = __shfl(sl, j, 32),     s1 = __shfl(sl, j + 1, 32);
            int s2 = __shfl(sl, j + 2, 32), s3 = __shfl(sl, j + 3, 32);
            float w0 = __shfl(wl, j, 32),     w1 = __shfl(wl, j + 1, 32);
            float w2 = __shfl(wl, j + 2, 32), w3 = __shfl(wl, j + 3, 32);
            u32 v0 = *(const u32*)(ht + (size_t)s0 * 64 + c2);
            u32 v1 = *(const u32*)(ht + (size_t)s1 * 64 + c2);
            u32 v2 = *(const u32*)(ht + (size_t)s2 * 64 + c2);
            u32 v3 = *(const u32*)(ht + (size_t)s3 * 64 + c2);
            a0 += bf2f((u16)(v0 & 0xffff)) * w0 + bf2f((u16)(v1 & 0xffff)) * w1
                + bf2f((u16)(v2 & 0xffff)) * w2 + bf2f((u16)(v3 & 0xffff)) * w3;
            a1 += bf2f((u16)(v0 >> 16)) * w0 + bf2f((u16)(v1 >> 16)) * w1
                + bf2f((u16)(v2 >> 16)) * w2 + bf2f((u16)(v3 >> 16)) * w3;
        }
        for (; j < rem; ++j) {
            int s0 = __shfl(sl, j, 32);
            float w0 = __shfl(wl, j, 32);
            u32 v0 = *(const u32*)(ht + (size_t)s0 * 64 + c2);
            a0 += bf2f((u16)(v0 & 0xffff)) * w0;
            a1 += bf2f((u16)(v0 >> 16)) * w0;
        }
    }
    u32 o;
    if (l < 20) {
        float b0 = bias[c2], b1 = bias[c2 + 1];
        o = (u32)f2bf(fmaxf(a0 + b0, 0.f)) | ((u32)f2bf(fmaxf(a1 + b1, 0.f)) << 16);
    } else {
        o = 0u;   // zero-pad cols 40..63 (consumed as K=64 by gemm3 with zero B rows)
    }
    *(u32*)(outb + (size_t)i * 64 + c2) = o;
}

// ---------------- launch ----------------

extern "C" void kernel_launch(void* const* d_in, const int* in_sizes, int n_in,
                              void* d_out, int out_size, void* d_ws, size_t ws_size,
                              hipStream_t stream)
{
    const float* x  = (const float*)d_in[0];
    const int*   ei = (const int*)d_in[1];
    const float* W1 = (const float*)d_in[2];
    const float* b1 = (const float*)d_in[3];
    const float* W2 = (const float*)d_in[4];
    const float* b2 = (const float*)d_in[5];
    const float* W3 = (const float*)d_in[6];
    const float* b3 = (const float*)d_in[7];
    const float* lw = (const float*)d_in[8];
    const float* lb = (const float*)d_in[9];

    int N = in_sizes[0] / 256;
    int E = in_sizes[1] / 2;
    const int* erow = ei;       // source nodes
    const int* ecol = ei + E;   // target nodes

    char* ws = (char*)d_ws;
    size_t o = 0;
    auto alloc = [&](size_t bytes) -> void* {
        void* p = ws + o;
        o += (bytes + 255) & ~(size_t)255;
        return p;
    };
    int*   cnt  = (int*)alloc((size_t)N * 4);
    int*   off  = (int*)alloc((size_t)(N + 1) * 4);
    int*   fil  = (int*)alloc((size_t)N * 4);
    int*   bsum = (int*)alloc(1024 * 4);
    float* dis  = (float*)alloc((size_t)N * 4);
    int*   srcs = (int*)alloc((size_t)E * 4);
    float* wts  = (float*)alloc((size_t)E * 4);
    u16*   W1t  = (u16*)alloc(256 * 256 * 2);
    u16*   W2t  = (u16*)alloc(256 * 256 * 2);
    u16*   W3t  = (u16*)alloc(128 * 256 * 2);
    u16*   lwAt = (u16*)alloc(128 * 256 * 2);
    u16*   lwBt = (u16*)alloc(128 * 256 * 2);
    u16*   lwCt = (u16*)alloc(128 * 64 * 2);
    u16*   xb   = (u16*)alloc((size_t)N * 256 * 2);
    u16*   htb  = (u16*)alloc((size_t)N * 256 * 2);
    u16*   h1b  = (u16*)alloc((size_t)N * 256 * 2);
    u16*   h2b  = (u16*)alloc((size_t)N * 256 * 2);
    u16*   h3b  = (u16*)alloc((size_t)N * 64 * 2);
    u16*   ht3b = htb;   // [N][64] view, reuse

    const int tb = 256;
    init_kernel<<<(N + tb - 1) / tb, tb, 0, stream>>>(cnt, fil, N);
    hist_kernel<<<(E + tb - 1) / tb, tb, 0, stream>>>(ecol, cnt, E);
    dis_kernel<<<(N + tb - 1) / tb, tb, 0, stream>>>(cnt, dis, N);
    int nb = (N + 511) / 512;
    scan1<<<nb, 512, 0, stream>>>(cnt, off, bsum, N);
    scan2<<<1, 256, 0, stream>>>(bsum, nb);
    scan3<<<nb, 512, 0, stream>>>(off, bsum, N);
    fill_kernel<<<(E + tb - 1) / tb, tb, 0, stream>>>(erow, ecol, off, fil, dis, srcs, wts, E);

    cast_f2b<<<(N * 64 + tb - 1) / tb, tb, 0, stream>>>(x, xb, N * 64);
    tcast<<<(256 * 256 + tb - 1) / tb, tb, 0, stream>>>(W1, W1t, 256, 256, 256, 256, 256);
    tcast<<<(256 * 256 + tb - 1) / tb, tb, 0, stream>>>(W2, W2t, 256, 256, 256, 256, 256);
    tcast<<<(128 * 256 + tb - 1) / tb, tb, 0, stream>>>(W3, W3t, 256, 40, 40, 256, 128);
    tcast<<<(128 * 256 + tb - 1) / tb, tb, 0, stream>>>(lw,            lwAt, 256, 40, 40, 256, 128);
    tcast<<<(128 * 256 + tb - 1) / tb, tb, 0, stream>>>(lw + 256 * 40, lwBt, 256, 40, 40, 256, 128);
    tcast<<<(128 * 64  + tb - 1) / tb, tb, 0, stream>>>(lw + 512 * 40, lwCt, 40, 40, 40, 64, 128);

    dim3 gBig(2, (N + 127) / 128);
    dim3 gSm(1, (N + 127) / 128);
    int nAgg4 = (N + 3) / 4;
    int nAgg8 = (N + 7) / 8;

    // layer 1
    gemm_mfma<<<gBig, 256, 0, stream>>>(xb, 256, W1t, 256, nullptr, htb, 256, N, 256, 256, 2);
    agg256_bf16<<<nAgg4, 256, 0, stream>>>(htb, off, cnt, srcs, wts, dis, b1, h1b, N);
    // layer 2
    gemm_mfma<<<gBig, 256, 0, stream>>>(h1b, 256, W2t, 256, nullptr, htb, 256, N, 256, 256, 2);
    agg256_bf16<<<nAgg4, 256, 0, stream>>>(htb, off, cnt, srcs, wts, dis, b2, h2b, N);
    // layer 3
    gemm_mfma<<<gSm, 256, 0, stream>>>(h2b, 256, W3t, 256, nullptr, ht3b, 64, N, 40, 256, 2);
    agg40_bf16<<<nAgg8, 256, 0, stream>>>(ht3b, off, cnt, srcs, wts, dis, b3, h3b, N);

    // fused final projection + log_softmax
    gemm3_lsm<<<(N + 127) / 128, 256, 0, stream>>>(
        h1b, h2b, h3b, lwAt, lwBt, lwCt, lb, (float*)d_out, N);
}

// Round 4
// 648.444 us; speedup vs baseline: 2.6601x; 1.0003x over previous
//
#include <hip/hip_runtime.h>
#include <math.h>

typedef unsigned short u16;
typedef unsigned int u32;
typedef __attribute__((ext_vector_type(8))) short bf16x8;
typedef __attribute__((ext_vector_type(4))) float f32x4;

__device__ __forceinline__ float bf2f(u16 u) {
    union { unsigned u; float f; } v; v.u = (unsigned)u << 16; return v.f;
}
__device__ __forceinline__ u16 f2bf(float f) {
    union { float f; unsigned u; } v; v.f = f;
    unsigned r = v.u + 0x7FFF + ((v.u >> 16) & 1);   // RNE
    return (u16)(r >> 16);
}

// ---------------- CSR build ----------------

__global__ void init_kernel(int* cnt, int n) {
    int i = blockIdx.x * blockDim.x + threadIdx.x;
    if (i < n) cnt[i] = 0;
}

__global__ void hist_kernel(const int* __restrict__ col, int* __restrict__ cnt, int e) {
    int i = blockIdx.x * blockDim.x + threadIdx.x;
    if (i < e) atomicAdd(&cnt[col[i]], 1);
}

// scan1 also emits dis[i] = rsqrt(deg_with_selfloop)
__global__ void scan1(const int* __restrict__ cnt, int* __restrict__ off,
                      int* __restrict__ bsum, float* __restrict__ dis, int n) {
    __shared__ int s[512];
    int t = threadIdx.x;
    int i = blockIdx.x * 512 + t;
    int v = (i < n) ? cnt[i] : 0;
    if (i < n) dis[i] = rsqrtf((float)v + 1.0f);
    s[t] = v; __syncthreads();
    for (int d = 1; d < 512; d <<= 1) {
        int a = (t >= d) ? s[t - d] : 0;
        __syncthreads();
        s[t] += a;
        __syncthreads();
    }
    if (i < n) off[i] = s[t] - v;
    if (t == 511) bsum[blockIdx.x] = s[511];
}

__global__ void scan2(int* bsum, int nb) {
    __shared__ int s[256];
    int t = threadIdx.x;
    int v = (t < nb) ? bsum[t] : 0;
    s[t] = v; __syncthreads();
    for (int d = 1; d < 256; d <<= 1) {
        int a = (t >= d) ? s[t - d] : 0;
        __syncthreads();
        s[t] += a;
        __syncthreads();
    }
    if (t < nb) bsum[t] = s[t] - v;
}

// scan3 also seeds fil[i] = off[i] (fill's atomic then yields absolute slots)
__global__ void scan3(int* off, int* fil, const int* __restrict__ bsum, int n) {
    int i = blockIdx.x * 512 + threadIdx.x;
    if (i < n) {
        int v = off[i] + bsum[blockIdx.x];
        off[i] = v;
        fil[i] = v;
    }
}

__global__ void fill_kernel(const int* __restrict__ erow, const int* __restrict__ ecol,
                            int* __restrict__ fil, int* __restrict__ srcs, int e) {
    int i = blockIdx.x * blockDim.x + threadIdx.x;
    if (i < e) {
        int slot = atomicAdd(&fil[ecol[i]], 1);
        srcs[slot] = erow[i];
    }
}

// ---------------- casts ----------------

__global__ void cast_f2b(const float* __restrict__ in, u16* __restrict__ out, int n4) {
    int i = blockIdx.x * blockDim.x + threadIdx.x;
    if (i < n4) {
        float4 v = ((const float4*)in)[i];
        ushort4 o;
        o.x = f2bf(v.x); o.y = f2bf(v.y); o.z = f2bf(v.z); o.w = f2bf(v.w);
        ((ushort4*)out)[i] = o;
    }
}

// transpose+cast: in fp32 [K][Nin] -> out bf16 [Npad][Kld], zero-padded
__global__ void tcast(const float* __restrict__ in, u16* __restrict__ out,
                      int K, int Nin, int ncols, int Kld, int Npad) {
    int idx = blockIdx.x * blockDim.x + threadIdx.x;
    if (idx >= Npad * Kld) return;
    int n = idx / Kld, k = idx % Kld;
    float v = (n < ncols && k < K) ? in[(size_t)k * Nin + n] : 0.f;
    out[idx] = f2bf(v);
}

// ---------------- MFMA bf16 GEMM: C[M,Ncols] = A[M,K](bf16) @ Bt[N,K](bf16)^T ----------------

#define SWZ(row) ((((row) & 3) ^ (((row) >> 2) & 3)))

__device__ __forceinline__ void gload_lds16(const void* g, void* l) {
    __builtin_amdgcn_global_load_lds(
        (const __attribute__((address_space(1))) unsigned int*)g,
        (__attribute__((address_space(3))) unsigned int*)l, 16, 0, 0);
}

__global__ __launch_bounds__(256) void gemm_mfma(
    const u16* __restrict__ A, int lda,
    const u16* __restrict__ Bt, int ldb,
    const float* __restrict__ bias,
    void* __restrict__ C, int ldc,
    int M, int Ncols, int K, int flags)
{
    __shared__ u16 As[128 * 32];
    __shared__ u16 Bs[128 * 32];
    int tid = threadIdx.x;
    int ln = tid & 63, wv = tid >> 6;
    int wr = wv >> 1, wc = wv & 1;
    int br = blockIdx.y * 128, bc = blockIdx.x * 128;

    f32x4 acc[4][4];
    #pragma unroll
    for (int m = 0; m < 4; ++m)
        #pragma unroll
        for (int n = 0; n < 4; ++n)
            acc[m][n] = (f32x4){0.f, 0.f, 0.f, 0.f};

    for (int k0 = 0; k0 < K; k0 += 32) {
        __syncthreads();
        #pragma unroll
        for (int r = 0; r < 2; ++r) {
            int l = r * 256 + tid;
            int row = l >> 2;
            int sp = l & 3;
            int sl = sp ^ SWZ(row);
            int arow = br + row; if (arow >= M) arow = M - 1;
            const u16* ga = A + (size_t)arow * lda + k0 + sl * 8;
            const u16* gb = Bt + (size_t)(bc + row) * ldb + k0 + sl * 8;
            unsigned lbase = r * 4096 + wv * 1024;
            gload_lds16(ga, (char*)As + lbase);
            gload_lds16(gb, (char*)Bs + lbase);
        }
        __syncthreads();
        bf16x8 af[4], bf_[4];
        #pragma unroll
        for (int m = 0; m < 4; ++m) {
            int row = wr * 64 + m * 16 + (ln & 15);
            int sl = ((ln >> 4) ^ SWZ(row)) & 3;
            af[m] = *(const bf16x8*)((const char*)As + row * 64 + sl * 16);
        }
        #pragma unroll
        for (int n = 0; n < 4; ++n) {
            int row = wc * 64 + n * 16 + (ln & 15);
            int sl = ((ln >> 4) ^ SWZ(row)) & 3;
            bf_[n] = *(const bf16x8*)((const char*)Bs + row * 64 + sl * 16);
        }
        #pragma unroll
        for (int m = 0; m < 4; ++m)
            #pragma unroll
            for (int n = 0; n < 4; ++n)
                acc[m][n] = __builtin_amdgcn_mfma_f32_16x16x32_bf16(af[m], bf_[n], acc[m][n], 0, 0, 0);
    }

    #pragma unroll
    for (int m = 0; m < 4; ++m) {
        #pragma unroll
        for (int n = 0; n < 4; ++n) {
            #pragma unroll
            for (int j = 0; j < 4; ++j) {
                int r = br + wr * 64 + m * 16 + (ln >> 4) * 4 + j;
                int c = bc + wc * 64 + n * 16 + (ln & 15);
                if (r < M && c < Ncols) {
                    float v = acc[m][n][j];
                    if (bias) v += bias[c];
                    if (flags == 2) ((u16*)C)[(size_t)r * ldc + c] = f2bf(v);
                    else            ((float*)C)[(size_t)r * ldc + c] = v;
                }
            }
        }
    }
}

// ---------------- fused final: out = lsm(h1@B0 + h2@B1 + h3@B2 + lb) ----------------

__global__ __launch_bounds__(256) void gemm3_lsm(
    const u16* __restrict__ A0, const u16* __restrict__ A1, const u16* __restrict__ A2,
    const u16* __restrict__ B0, const u16* __restrict__ B1, const u16* __restrict__ B2,
    const float* __restrict__ bias,
    float* __restrict__ out, int M)
{
    __shared__ u16 As[128 * 32];
    __shared__ u16 Bs[64 * 32];
    int tid = threadIdx.x;
    int ln = tid & 63, wv = tid >> 6;
    int br = blockIdx.x * 128;

    f32x4 acc[2][4];
    #pragma unroll
    for (int m = 0; m < 2; ++m)
        #pragma unroll
        for (int n = 0; n < 4; ++n)
            acc[m][n] = (f32x4){0.f, 0.f, 0.f, 0.f};

    auto do_seg = [&](const u16* __restrict__ A, const u16* __restrict__ B, int K) {
        for (int k0 = 0; k0 < K; k0 += 32) {
            __syncthreads();
            #pragma unroll
            for (int r = 0; r < 2; ++r) {
                int l = r * 256 + tid;
                int row = l >> 2, sp = l & 3;
                int sl = sp ^ SWZ(row);
                int arow = br + row; if (arow >= M) arow = M - 1;
                gload_lds16(A + (size_t)arow * K + k0 + sl * 8,
                            (char*)As + r * 4096 + wv * 1024);
            }
            {
                int l = tid;
                int row = l >> 2, sp = l & 3;
                int sl = sp ^ SWZ(row);
                gload_lds16(B + (size_t)row * K + k0 + sl * 8,
                            (char*)Bs + wv * 1024);
            }
            __syncthreads();
            bf16x8 af[2], bf_[4];
            #pragma unroll
            for (int m = 0; m < 2; ++m) {
                int row = wv * 32 + m * 16 + (ln & 15);
                int sl = ((ln >> 4) ^ SWZ(row)) & 3;
                af[m] = *(const bf16x8*)((const char*)As + row * 64 + sl * 16);
            }
            #pragma unroll
            for (int nn = 0; nn < 4; ++nn) {
                int row = nn * 16 + (ln & 15);
                int sl = ((ln >> 4) ^ SWZ(row)) & 3;
                bf_[nn] = *(const bf16x8*)((const char*)Bs + row * 64 + sl * 16);
            }
            #pragma unroll
            for (int m = 0; m < 2; ++m)
                #pragma unroll
                for (int nn = 0; nn < 4; ++nn)
                    acc[m][nn] = __builtin_amdgcn_mfma_f32_16x16x32_bf16(af[m], bf_[nn], acc[m][nn], 0, 0, 0);
        }
    };
    do_seg(A0, B0, 256);
    do_seg(A1, B1, 256);
    do_seg(A2, B2, 64);

    int l15 = ln & 15;
    #pragma unroll
    for (int m = 0; m < 2; ++m) {
        #pragma unroll
        for (int j = 0; j < 4; ++j) {
            int r = br + wv * 32 + m * 16 + (ln >> 4) * 4 + j;
            float v0 = acc[m][0][j] + bias[l15];
            float v1 = acc[m][1][j] + bias[16 + l15];
            float v2 = (l15 < 8) ? (acc[m][2][j] + bias[32 + l15]) : -INFINITY;
            float mx = fmaxf(fmaxf(v0, v1), v2);
            #pragma unroll
            for (int o = 8; o; o >>= 1) mx = fmaxf(mx, __shfl_xor(mx, o));
            float s = expf(v0 - mx) + expf(v1 - mx) + ((l15 < 8) ? expf(v2 - mx) : 0.f);
            #pragma unroll
            for (int o = 8; o; o >>= 1) s += __shfl_xor(s, o);
            float ls = logf(s);
            if (r < M) {
                out[(size_t)r * 40 + l15]      = v0 - mx - ls;
                out[(size_t)r * 40 + 16 + l15] = v1 - mx - ls;
                if (l15 < 8) out[(size_t)r * 40 + 32 + l15] = v2 - mx - ls;
            }
        }
    }
}

// ---------------- aggregation F=256 bf16: wave per node, on-the-fly weights ----------------

__global__ __launch_bounds__(256) void agg256_bf16(
    const u16* __restrict__ ht,
    const int* __restrict__ off, const int* __restrict__ cnt,
    const int* __restrict__ srcs, const float* __restrict__ dis,
    const float* __restrict__ bias,
    u16* __restrict__ outb, int n)
{
    int wv = threadIdx.x >> 6, ln = threadIdx.x & 63;
    int i = blockIdx.x * 4 + wv;
    if (i >= n) return;
    int c = ln * 4;
    float di = dis[i], dd = di * di;
    ushort4 sv = *(const ushort4*)(ht + (size_t)i * 256 + c);
    float a0 = bf2f(sv.x) * dd, a1 = bf2f(sv.y) * dd, a2 = bf2f(sv.z) * dd, a3 = bf2f(sv.w) * dd;
    int beg = off[i], num = cnt[i];
    for (int base = 0; base < num; base += 64) {
        int rem = num - base; if (rem > 64) rem = 64;
        int sl = 0; float dsl = 0.f;
        if (ln < rem) { sl = srcs[beg + base + ln]; dsl = dis[sl]; }
        int j = 0;
        for (; j + 8 <= rem; j += 8) {
            int s[8]; float w[8]; ushort4 v[8];
            #pragma unroll
            for (int q = 0; q < 8; ++q) {
                s[q] = __shfl(sl, j + q);
                w[q] = __shfl(dsl, j + q) * di;
            }
            #pragma unroll
            for (int q = 0; q < 8; ++q)
                v[q] = *(const ushort4*)(ht + (size_t)s[q] * 256 + c);
            #pragma unroll
            for (int q = 0; q < 8; ++q) {
                a0 += bf2f(v[q].x) * w[q];
                a1 += bf2f(v[q].y) * w[q];
                a2 += bf2f(v[q].z) * w[q];
                a3 += bf2f(v[q].w) * w[q];
            }
        }
        for (; j + 4 <= rem; j += 4) {
            int s[4]; float w[4]; ushort4 v[4];
            #pragma unroll
            for (int q = 0; q < 4; ++q) {
                s[q] = __shfl(sl, j + q);
                w[q] = __shfl(dsl, j + q) * di;
            }
            #pragma unroll
            for (int q = 0; q < 4; ++q)
                v[q] = *(const ushort4*)(ht + (size_t)s[q] * 256 + c);
            #pragma unroll
            for (int q = 0; q < 4; ++q) {
                a0 += bf2f(v[q].x) * w[q];
                a1 += bf2f(v[q].y) * w[q];
                a2 += bf2f(v[q].z) * w[q];
                a3 += bf2f(v[q].w) * w[q];
            }
        }
        for (; j < rem; ++j) {
            int s0 = __shfl(sl, j);
            float w0 = __shfl(dsl, j) * di;
            ushort4 v0 = *(const ushort4*)(ht + (size_t)s0 * 256 + c);
            a0 += bf2f(v0.x) * w0; a1 += bf2f(v0.y) * w0;
            a2 += bf2f(v0.z) * w0; a3 += bf2f(v0.w) * w0;
        }
    }
    float4 bv = *(const float4*)(bias + c);
    ushort4 o;
    o.x = f2bf(fmaxf(a0 + bv.x, 0.f));
    o.y = f2bf(fmaxf(a1 + bv.y, 0.f));
    o.z = f2bf(fmaxf(a2 + bv.z, 0.f));
    o.w = f2bf(fmaxf(a3 + bv.w, 0.f));
    *(ushort4*)(outb + (size_t)i * 256 + c) = o;
}

// F=40 (stride 64): HALF-wave per node, uint loads (2 feats/lane)
__global__ __launch_bounds__(256) void agg40_bf16(
    const u16* __restrict__ ht,
    const int* __restrict__ off, const int* __restrict__ cnt,
    const int* __restrict__ srcs, const float* __restrict__ dis,
    const float* __restrict__ bias,
    u16* __restrict__ outb, int n)
{
    int half = threadIdx.x >> 5;
    int l = threadIdx.x & 31;
    int i = blockIdx.x * 8 + half;
    if (i >= n) return;
    int c2 = l * 2;
    float di = dis[i], dd = di * di;
    u32 sv = *(const u32*)(ht + (size_t)i * 64 + c2);
    float a0 = bf2f((u16)(sv & 0xffff)) * dd;
    float a1 = bf2f((u16)(sv >> 16)) * dd;
    int beg = off[i], num = cnt[i];
    for (int base = 0; base < num; base += 32) {
        int rem = num - base; if (rem > 32) rem = 32;
        int sl = 0; float dsl = 0.f;
        if (l < rem) { sl = srcs[beg + base + l]; dsl = dis[sl]; }
        int j = 0;
        for (; j + 8 <= rem; j += 8) {
            int s[8]; float w[8]; u32 v[8];
            #pragma unroll
            for (int q = 0; q < 8; ++q) {
                s[q] = __shfl(sl, j + q, 32);
                w[q] = __shfl(dsl, j + q, 32) * di;
            }
            #pragma unroll
            for (int q = 0; q < 8; ++q)
                v[q] = *(const u32*)(ht + (size_t)s[q] * 64 + c2);
            #pragma unroll
            for (int q = 0; q < 8; ++q) {
                a0 += bf2f((u16)(v[q] & 0xffff)) * w[q];
                a1 += bf2f((u16)(v[q] >> 16)) * w[q];
            }
        }
        for (; j + 4 <= rem; j += 4) {
            int s[4]; float w[4]; u32 v[4];
            #pragma unroll
            for (int q = 0; q < 4; ++q) {
                s[q] = __shfl(sl, j + q, 32);
                w[q] = __shfl(dsl, j + q, 32) * di;
            }
            #pragma unroll
            for (int q = 0; q < 4; ++q)
                v[q] = *(const u32*)(ht + (size_t)s[q] * 64 + c2);
            #pragma unroll
            for (int q = 0; q < 4; ++q) {
                a0 += bf2f((u16)(v[q] & 0xffff)) * w[q];
                a1 += bf2f((u16)(v[q] >> 16)) * w[q];
            }
        }
        for (; j < rem; ++j) {
            int s0 = __shfl(sl, j, 32);
            float w0 = __shfl(dsl, j, 32) * di;
            u32 v0 = *(const u32*)(ht + (size_t)s0 * 64 + c2);
            a0 += bf2f((u16)(v0 & 0xffff)) * w0;
            a1 += bf2f((u16)(v0 >> 16)) * w0;
        }
    }
    u32 o;
    if (l < 20) {
        float b0 = bias[c2], b1 = bias[c2 + 1];
        o = (u32)f2bf(fmaxf(a0 + b0, 0.f)) | ((u32)f2bf(fmaxf(a1 + b1, 0.f)) << 16);
    } else {
        o = 0u;
    }
    *(u32*)(outb + (size_t)i * 64 + c2) = o;
}

// ---------------- launch ----------------

extern "C" void kernel_launch(void* const* d_in, const int* in_sizes, int n_in,
                              void* d_out, int out_size, void* d_ws, size_t ws_size,
                              hipStream_t stream)
{
    const float* x  = (const float*)d_in[0];
    const int*   ei = (const int*)d_in[1];
    const float* W1 = (const float*)d_in[2];
    const float* b1 = (const float*)d_in[3];
    const float* W2 = (const float*)d_in[4];
    const float* b2 = (const float*)d_in[5];
    const float* W3 = (const float*)d_in[6];
    const float* b3 = (const float*)d_in[7];
    const float* lw = (const float*)d_in[8];
    const float* lb = (const float*)d_in[9];

    int N = in_sizes[0] / 256;
    int E = in_sizes[1] / 2;
    const int* erow = ei;       // source nodes
    const int* ecol = ei + E;   // target nodes

    char* ws = (char*)d_ws;
    size_t o = 0;
    auto alloc = [&](size_t bytes) -> void* {
        void* p = ws + o;
        o += (bytes + 255) & ~(size_t)255;
        return p;
    };
    int*   cnt  = (int*)alloc((size_t)N * 4);
    int*   off  = (int*)alloc((size_t)(N + 1) * 4);
    int*   fil  = (int*)alloc((size_t)N * 4);
    int*   bsum = (int*)alloc(1024 * 4);
    float* dis  = (float*)alloc((size_t)N * 4);
    int*   srcs = (int*)alloc((size_t)E * 4);
    u16*   W1t  = (u16*)alloc(256 * 256 * 2);
    u16*   W2t  = (u16*)alloc(256 * 256 * 2);
    u16*   W3t  = (u16*)alloc(128 * 256 * 2);
    u16*   lwAt = (u16*)alloc(128 * 256 * 2);
    u16*   lwBt = (u16*)alloc(128 * 256 * 2);
    u16*   lwCt = (u16*)alloc(128 * 64 * 2);
    u16*   xb   = (u16*)alloc((size_t)N * 256 * 2);
    u16*   htb  = (u16*)alloc((size_t)N * 256 * 2);
    u16*   h1b  = (u16*)alloc((size_t)N * 256 * 2);
    u16*   h2b  = (u16*)alloc((size_t)N * 256 * 2);
    u16*   h3b  = (u16*)alloc((size_t)N * 64 * 2);
    u16*   ht3b = htb;   // [N][64] view, reuse

    const int tb = 256;
    init_kernel<<<(N + tb - 1) / tb, tb, 0, stream>>>(cnt, N);
    hist_kernel<<<(E + tb - 1) / tb, tb, 0, stream>>>(ecol, cnt, E);
    int nb = (N + 511) / 512;
    scan1<<<nb, 512, 0, stream>>>(cnt, off, bsum, dis, N);
    scan2<<<1, 256, 0, stream>>>(bsum, nb);
    scan3<<<nb, 512, 0, stream>>>(off, fil, bsum, N);
    fill_kernel<<<(E + tb - 1) / tb, tb, 0, stream>>>(erow, ecol, fil, srcs, E);

    cast_f2b<<<(N * 64 + tb - 1) / tb, tb, 0, stream>>>(x, xb, N * 64);
    tcast<<<(256 * 256 + tb - 1) / tb, tb, 0, stream>>>(W1, W1t, 256, 256, 256, 256, 256);
    tcast<<<(256 * 256 + tb - 1) / tb, tb, 0, stream>>>(W2, W2t, 256, 256, 256, 256, 256);
    tcast<<<(128 * 256 + tb - 1) / tb, tb, 0, stream>>>(W3, W3t, 256, 40, 40, 256, 128);
    tcast<<<(128 * 256 + tb - 1) / tb, tb, 0, stream>>>(lw,            lwAt, 256, 40, 40, 256, 128);
    tcast<<<(128 * 256 + tb - 1) / tb, tb, 0, stream>>>(lw + 256 * 40, lwBt, 256, 40, 40, 256, 128);
    tcast<<<(128 * 64  + tb - 1) / tb, tb, 0, stream>>>(lw + 512 * 40, lwCt, 40, 40, 40, 64, 128);

    dim3 gBig(2, (N + 127) / 128);
    dim3 gSm(1, (N + 127) / 128);
    int nAgg4 = (N + 3) / 4;
    int nAgg8 = (N + 7) / 8;

    // layer 1
    gemm_mfma<<<gBig, 256, 0, stream>>>(xb, 256, W1t, 256, nullptr, htb, 256, N, 256, 256, 2);
    agg256_bf16<<<nAgg4, 256, 0, stream>>>(htb, off, cnt, srcs, dis, b1, h1b, N);
    // layer 2
    gemm_mfma<<<gBig, 256, 0, stream>>>(h1b, 256, W2t, 256, nullptr, htb, 256, N, 256, 256, 2);
    agg256_bf16<<<nAgg4, 256, 0, stream>>>(htb, off, cnt, srcs, dis, b2, h2b, N);
    // layer 3
    gemm_mfma<<<gSm, 256, 0, stream>>>(h2b, 256, W3t, 256, nullptr, ht3b, 64, N, 40, 256, 2);
    agg40_bf16<<<nAgg8, 256, 0, stream>>>(ht3b, off, cnt, srcs, dis, b3, h3b, N);

    // fused final projection + log_softmax
    gemm3_lsm<<<(N + 127) / 128, 256, 0, stream>>>(
        h1b, h2b, h3b, lwAt, lwBt, lwCt, lb, (float*)d_out, N);
}

// Round 5
// 625.518 us; speedup vs baseline: 2.7576x; 1.0367x over previous
//
#include <hip/hip_runtime.h>
#include <math.h>

typedef unsigned short u16;
typedef unsigned int u32;
typedef __attribute__((ext_vector_type(8))) short bf16x8;
typedef __attribute__((ext_vector_type(4))) float f32x4;

__device__ __forceinline__ float bf2f(u16 u) {
    union { unsigned u; float f; } v; v.u = (unsigned)u << 16; return v.f;
}
__device__ __forceinline__ u16 f2bf(float f) {
    union { float f; unsigned u; } v; v.f = f;
    unsigned r = v.u + 0x7FFF + ((v.u >> 16) & 1);   // RNE
    return (u16)(r >> 16);
}

// ---------------- CSR build ----------------

__global__ void init_kernel(int* cnt, int n) {
    int i = blockIdx.x * blockDim.x + threadIdx.x;
    if (i < n) cnt[i] = 0;
}

__global__ void hist_kernel(const int* __restrict__ col, int* __restrict__ cnt, int e) {
    int i = blockIdx.x * blockDim.x + threadIdx.x;
    if (i < e) atomicAdd(&cnt[col[i]], 1);
}

// scan1 also emits dis[i] = rsqrt(deg_with_selfloop)
__global__ void scan1(const int* __restrict__ cnt, int* __restrict__ off,
                      int* __restrict__ bsum, float* __restrict__ dis, int n) {
    __shared__ int s[512];
    int t = threadIdx.x;
    int i = blockIdx.x * 512 + t;
    int v = (i < n) ? cnt[i] : 0;
    if (i < n) dis[i] = rsqrtf((float)v + 1.0f);
    s[t] = v; __syncthreads();
    for (int d = 1; d < 512; d <<= 1) {
        int a = (t >= d) ? s[t - d] : 0;
        __syncthreads();
        s[t] += a;
        __syncthreads();
    }
    if (i < n) off[i] = s[t] - v;
    if (t == 511) bsum[blockIdx.x] = s[511];
}

__global__ void scan2(int* bsum, int nb) {
    __shared__ int s[256];
    int t = threadIdx.x;
    int v = (t < nb) ? bsum[t] : 0;
    s[t] = v; __syncthreads();
    for (int d = 1; d < 256; d <<= 1) {
        int a = (t >= d) ? s[t - d] : 0;
        __syncthreads();
        s[t] += a;
        __syncthreads();
    }
    if (t < nb) bsum[t] = s[t] - v;
}

// scan3 also seeds fil[i] = off[i]
__global__ void scan3(int* off, int* fil, const int* __restrict__ bsum, int n) {
    int i = blockIdx.x * 512 + threadIdx.x;
    if (i < n) {
        int v = off[i] + bsum[blockIdx.x];
        off[i] = v;
        fil[i] = v;
    }
}

// Multi-pass predicated fill: pass p handles dst in [p*chunk, (p+1)*chunk).
// Concurrent scatter writes land in an L2-resident window -> partial lines
// merge in cache instead of write-allocate thrashing to HBM.
__global__ void fill_kernel(const int* __restrict__ erow, const int* __restrict__ ecol,
                            int* __restrict__ fil, int* __restrict__ srcs,
                            int e, int chunk, int npass) {
    int stride = gridDim.x * blockDim.x;
    int t0 = blockIdx.x * blockDim.x + threadIdx.x;
    for (int p = 0; p < npass; ++p) {
        int lo = p * chunk, hi = lo + chunk;
        for (int i = t0; i < e; i += stride) {
            int c = ecol[i];
            if (c >= lo && c < hi) {
                int slot = atomicAdd(&fil[c], 1);
                srcs[slot] = erow[i];
            }
        }
    }
}

// ---------------- casts ----------------

__global__ void cast_f2b(const float* __restrict__ in, u16* __restrict__ out, int n4) {
    int i = blockIdx.x * blockDim.x + threadIdx.x;
    if (i < n4) {
        float4 v = ((const float4*)in)[i];
        ushort4 o;
        o.x = f2bf(v.x); o.y = f2bf(v.y); o.z = f2bf(v.z); o.w = f2bf(v.w);
        ((ushort4*)out)[i] = o;
    }
}

// transpose+cast: in fp32 [K][Nin] -> out bf16 [Npad][Kld], zero-padded
__global__ void tcast(const float* __restrict__ in, u16* __restrict__ out,
                      int K, int Nin, int ncols, int Kld, int Npad) {
    int idx = blockIdx.x * blockDim.x + threadIdx.x;
    if (idx >= Npad * Kld) return;
    int n = idx / Kld, k = idx % Kld;
    float v = (n < ncols && k < K) ? in[(size_t)k * Nin + n] : 0.f;
    out[idx] = f2bf(v);
}

// ---------------- MFMA bf16 GEMM: C[M,Ncols] = A[M,K](bf16) @ Bt[N,K](bf16)^T ----------------

#define SWZ(row) ((((row) & 3) ^ (((row) >> 2) & 3)))

__device__ __forceinline__ void gload_lds16(const void* g, void* l) {
    __builtin_amdgcn_global_load_lds(
        (const __attribute__((address_space(1))) unsigned int*)g,
        (__attribute__((address_space(3))) unsigned int*)l, 16, 0, 0);
}

__global__ __launch_bounds__(256) void gemm_mfma(
    const u16* __restrict__ A, int lda,
    const u16* __restrict__ Bt, int ldb,
    const float* __restrict__ bias,
    void* __restrict__ C, int ldc,
    int M, int Ncols, int K, int flags)
{
    __shared__ u16 As[128 * 32];
    __shared__ u16 Bs[128 * 32];
    int tid = threadIdx.x;
    int ln = tid & 63, wv = tid >> 6;
    int wr = wv >> 1, wc = wv & 1;
    int br = blockIdx.y * 128, bc = blockIdx.x * 128;

    f32x4 acc[4][4];
    #pragma unroll
    for (int m = 0; m < 4; ++m)
        #pragma unroll
        for (int n = 0; n < 4; ++n)
            acc[m][n] = (f32x4){0.f, 0.f, 0.f, 0.f};

    for (int k0 = 0; k0 < K; k0 += 32) {
        __syncthreads();
        #pragma unroll
        for (int r = 0; r < 2; ++r) {
            int l = r * 256 + tid;
            int row = l >> 2;
            int sp = l & 3;
            int sl = sp ^ SWZ(row);
            int arow = br + row; if (arow >= M) arow = M - 1;
            const u16* ga = A + (size_t)arow * lda + k0 + sl * 8;
            const u16* gb = Bt + (size_t)(bc + row) * ldb + k0 + sl * 8;
            unsigned lbase = r * 4096 + wv * 1024;
            gload_lds16(ga, (char*)As + lbase);
            gload_lds16(gb, (char*)Bs + lbase);
        }
        __syncthreads();
        bf16x8 af[4], bf_[4];
        #pragma unroll
        for (int m = 0; m < 4; ++m) {
            int row = wr * 64 + m * 16 + (ln & 15);
            int sl = ((ln >> 4) ^ SWZ(row)) & 3;
            af[m] = *(const bf16x8*)((const char*)As + row * 64 + sl * 16);
        }
        #pragma unroll
        for (int n = 0; n < 4; ++n) {
            int row = wc * 64 + n * 16 + (ln & 15);
            int sl = ((ln >> 4) ^ SWZ(row)) & 3;
            bf_[n] = *(const bf16x8*)((const char*)Bs + row * 64 + sl * 16);
        }
        #pragma unroll
        for (int m = 0; m < 4; ++m)
            #pragma unroll
            for (int n = 0; n < 4; ++n)
                acc[m][n] = __builtin_amdgcn_mfma_f32_16x16x32_bf16(af[m], bf_[n], acc[m][n], 0, 0, 0);
    }

    #pragma unroll
    for (int m = 0; m < 4; ++m) {
        #pragma unroll
        for (int n = 0; n < 4; ++n) {
            #pragma unroll
            for (int j = 0; j < 4; ++j) {
                int r = br + wr * 64 + m * 16 + (ln >> 4) * 4 + j;
                int c = bc + wc * 64 + n * 16 + (ln & 15);
                if (r < M && c < Ncols) {
                    float v = acc[m][n][j];
                    if (bias) v += bias[c];
                    if (flags == 2) ((u16*)C)[(size_t)r * ldc + c] = f2bf(v);
                    else            ((float*)C)[(size_t)r * ldc + c] = v;
                }
            }
        }
    }
}

// ---------------- fused final: out = lsm(h1@B0 + h2@B1 + h3@B2 + lb) ----------------

__global__ __launch_bounds__(256) void gemm3_lsm(
    const u16* __restrict__ A0, const u16* __restrict__ A1, const u16* __restrict__ A2,
    const u16* __restrict__ B0, const u16* __restrict__ B1, const u16* __restrict__ B2,
    const float* __restrict__ bias,
    float* __restrict__ out, int M)
{
    __shared__ u16 As[128 * 32];
    __shared__ u16 Bs[64 * 32];
    int tid = threadIdx.x;
    int ln = tid & 63, wv = tid >> 6;
    int br = blockIdx.x * 128;

    f32x4 acc[2][4];
    #pragma unroll
    for (int m = 0; m < 2; ++m)
        #pragma unroll
        for (int n = 0; n < 4; ++n)
            acc[m][n] = (f32x4){0.f, 0.f, 0.f, 0.f};

    auto do_seg = [&](const u16* __restrict__ A, const u16* __restrict__ B, int K) {
        for (int k0 = 0; k0 < K; k0 += 32) {
            __syncthreads();
            #pragma unroll
            for (int r = 0; r < 2; ++r) {
                int l = r * 256 + tid;
                int row = l >> 2, sp = l & 3;
                int sl = sp ^ SWZ(row);
                int arow = br + row; if (arow >= M) arow = M - 1;
                gload_lds16(A + (size_t)arow * K + k0 + sl * 8,
                            (char*)As + r * 4096 + wv * 1024);
            }
            {
                int l = tid;
                int row = l >> 2, sp = l & 3;
                int sl = sp ^ SWZ(row);
                gload_lds16(B + (size_t)row * K + k0 + sl * 8,
                            (char*)Bs + wv * 1024);
            }
            __syncthreads();
            bf16x8 af[2], bf_[4];
            #pragma unroll
            for (int m = 0; m < 2; ++m) {
                int row = wv * 32 + m * 16 + (ln & 15);
                int sl = ((ln >> 4) ^ SWZ(row)) & 3;
                af[m] = *(const bf16x8*)((const char*)As + row * 64 + sl * 16);
            }
            #pragma unroll
            for (int nn = 0; nn < 4; ++nn) {
                int row = nn * 16 + (ln & 15);
                int sl = ((ln >> 4) ^ SWZ(row)) & 3;
                bf_[nn] = *(const bf16x8*)((const char*)Bs + row * 64 + sl * 16);
            }
            #pragma unroll
            for (int m = 0; m < 2; ++m)
                #pragma unroll
                for (int nn = 0; nn < 4; ++nn)
                    acc[m][nn] = __builtin_amdgcn_mfma_f32_16x16x32_bf16(af[m], bf_[nn], acc[m][nn], 0, 0, 0);
        }
    };
    do_seg(A0, B0, 256);
    do_seg(A1, B1, 256);
    do_seg(A2, B2, 64);

    int l15 = ln & 15;
    #pragma unroll
    for (int m = 0; m < 2; ++m) {
        #pragma unroll
        for (int j = 0; j < 4; ++j) {
            int r = br + wv * 32 + m * 16 + (ln >> 4) * 4 + j;
            float v0 = acc[m][0][j] + bias[l15];
            float v1 = acc[m][1][j] + bias[16 + l15];
            float v2 = (l15 < 8) ? (acc[m][2][j] + bias[32 + l15]) : -INFINITY;
            float mx = fmaxf(fmaxf(v0, v1), v2);
            #pragma unroll
            for (int o = 8; o; o >>= 1) mx = fmaxf(mx, __shfl_xor(mx, o));
            float s = expf(v0 - mx) + expf(v1 - mx) + ((l15 < 8) ? expf(v2 - mx) : 0.f);
            #pragma unroll
            for (int o = 8; o; o >>= 1) s += __shfl_xor(s, o);
            float ls = logf(s);
            if (r < M) {
                out[(size_t)r * 40 + l15]      = v0 - mx - ls;
                out[(size_t)r * 40 + 16 + l15] = v1 - mx - ls;
                if (l15 < 8) out[(size_t)r * 40 + 32 + l15] = v2 - mx - ls;
            }
        }
    }
}

// ---------------- aggregation F=256 bf16: wave per node, 16-deep gather ----------------

__global__ __launch_bounds__(256) void agg256_bf16(
    const u16* __restrict__ ht,
    const int* __restrict__ off, const int* __restrict__ cnt,
    const int* __restrict__ srcs, const float* __restrict__ dis,
    const float* __restrict__ bias,
    u16* __restrict__ outb, int n)
{
    int wv = threadIdx.x >> 6, ln = threadIdx.x & 63;
    int i = blockIdx.x * 4 + wv;
    if (i >= n) return;
    int c = ln * 4;
    float di = dis[i], dd = di * di;
    ushort4 sv = *(const ushort4*)(ht + (size_t)i * 256 + c);
    float a0 = bf2f(sv.x) * dd, a1 = bf2f(sv.y) * dd, a2 = bf2f(sv.z) * dd, a3 = bf2f(sv.w) * dd;
    int beg = off[i], num = cnt[i];
    for (int base = 0; base < num; base += 64) {
        int rem = num - base; if (rem > 64) rem = 64;
        int sl = 0; float dsl = 0.f;
        if (ln < rem) { sl = srcs[beg + base + ln]; dsl = dis[sl]; }
        int j = 0;
        for (; j + 16 <= rem; j += 16) {
            int s[16]; float w[16]; ushort4 v[16];
            #pragma unroll
            for (int q = 0; q < 16; ++q) {
                s[q] = __shfl(sl, j + q);
                w[q] = __shfl(dsl, j + q) * di;
            }
            #pragma unroll
            for (int q = 0; q < 16; ++q)
                v[q] = *(const ushort4*)(ht + (size_t)s[q] * 256 + c);
            #pragma unroll
            for (int q = 0; q < 16; ++q) {
                a0 += bf2f(v[q].x) * w[q];
                a1 += bf2f(v[q].y) * w[q];
                a2 += bf2f(v[q].z) * w[q];
                a3 += bf2f(v[q].w) * w[q];
            }
        }
        for (; j + 8 <= rem; j += 8) {
            int s[8]; float w[8]; ushort4 v[8];
            #pragma unroll
            for (int q = 0; q < 8; ++q) {
                s[q] = __shfl(sl, j + q);
                w[q] = __shfl(dsl, j + q) * di;
            }
            #pragma unroll
            for (int q = 0; q < 8; ++q)
                v[q] = *(const ushort4*)(ht + (size_t)s[q] * 256 + c);
            #pragma unroll
            for (int q = 0; q < 8; ++q) {
                a0 += bf2f(v[q].x) * w[q];
                a1 += bf2f(v[q].y) * w[q];
                a2 += bf2f(v[q].z) * w[q];
                a3 += bf2f(v[q].w) * w[q];
            }
        }
        for (; j + 4 <= rem; j += 4) {
            int s[4]; float w[4]; ushort4 v[4];
            #pragma unroll
            for (int q = 0; q < 4; ++q) {
                s[q] = __shfl(sl, j + q);
                w[q] = __shfl(dsl, j + q) * di;
            }
            #pragma unroll
            for (int q = 0; q < 4; ++q)
                v[q] = *(const ushort4*)(ht + (size_t)s[q] * 256 + c);
            #pragma unroll
            for (int q = 0; q < 4; ++q) {
                a0 += bf2f(v[q].x) * w[q];
                a1 += bf2f(v[q].y) * w[q];
                a2 += bf2f(v[q].z) * w[q];
                a3 += bf2f(v[q].w) * w[q];
            }
        }
        for (; j < rem; ++j) {
            int s0 = __shfl(sl, j);
            float w0 = __shfl(dsl, j) * di;
            ushort4 v0 = *(const ushort4*)(ht + (size_t)s0 * 256 + c);
            a0 += bf2f(v0.x) * w0; a1 += bf2f(v0.y) * w0;
            a2 += bf2f(v0.z) * w0; a3 += bf2f(v0.w) * w0;
        }
    }
    float4 bv = *(const float4*)(bias + c);
    ushort4 o;
    o.x = f2bf(fmaxf(a0 + bv.x, 0.f));
    o.y = f2bf(fmaxf(a1 + bv.y, 0.f));
    o.z = f2bf(fmaxf(a2 + bv.z, 0.f));
    o.w = f2bf(fmaxf(a3 + bv.w, 0.f));
    *(ushort4*)(outb + (size_t)i * 256 + c) = o;
}

// F=40 (stride 64): HALF-wave per node, uint loads (2 feats/lane)
__global__ __launch_bounds__(256) void agg40_bf16(
    const u16* __restrict__ ht,
    const int* __restrict__ off, const int* __restrict__ cnt,
    const int* __restrict__ srcs, const float* __restrict__ dis,
    const float* __restrict__ bias,
    u16* __restrict__ outb, int n)
{
    int half = threadIdx.x >> 5;
    int l = threadIdx.x & 31;
    int i = blockIdx.x * 8 + half;
    if (i >= n) return;
    int c2 = l * 2;
    float di = dis[i], dd = di * di;
    u32 sv = *(const u32*)(ht + (size_t)i * 64 + c2);
    float a0 = bf2f((u16)(sv & 0xffff)) * dd;
    float a1 = bf2f((u16)(sv >> 16)) * dd;
    int beg = off[i], num = cnt[i];
    for (int base = 0; base < num; base += 32) {
        int rem = num - base; if (rem > 32) rem = 32;
        int sl = 0; float dsl = 0.f;
        if (l < rem) { sl = srcs[beg + base + l]; dsl = dis[sl]; }
        int j = 0;
        for (; j + 8 <= rem; j += 8) {
            int s[8]; float w[8]; u32 v[8];
            #pragma unroll
            for (int q = 0; q < 8; ++q) {
                s[q] = __shfl(sl, j + q, 32);
                w[q] = __shfl(dsl, j + q, 32) * di;
            }
            #pragma unroll
            for (int q = 0; q < 8; ++q)
                v[q] = *(const u32*)(ht + (size_t)s[q] * 64 + c2);
            #pragma unroll
            for (int q = 0; q < 8; ++q) {
                a0 += bf2f((u16)(v[q] & 0xffff)) * w[q];
                a1 += bf2f((u16)(v[q] >> 16)) * w[q];
            }
        }
        for (; j + 4 <= rem; j += 4) {
            int s[4]; float w[4]; u32 v[4];
            #pragma unroll
            for (int q = 0; q < 4; ++q) {
                s[q] = __shfl(sl, j + q, 32);
                w[q] = __shfl(dsl, j + q, 32) * di;
            }
            #pragma unroll
            for (int q = 0; q < 4; ++q)
                v[q] = *(const u32*)(ht + (size_t)s[q] * 64 + c2);
            #pragma unroll
            for (int q = 0; q < 4; ++q) {
                a0 += bf2f((u16)(v[q] & 0xffff)) * w[q];
                a1 += bf2f((u16)(v[q] >> 16)) * w[q];
            }
        }
        for (; j < rem; ++j) {
            int s0 = __shfl(sl, j, 32);
            float w0 = __shfl(dsl, j, 32) * di;
            u32 v0 = *(const u32*)(ht + (size_t)s0 * 64 + c2);
            a0 += bf2f((u16)(v0 & 0xffff)) * w0;
            a1 += bf2f((u16)(v0 >> 16)) * w0;
        }
    }
    u32 o;
    if (l < 20) {
        float b0 = bias[c2], b1 = bias[c2 + 1];
        o = (u32)f2bf(fmaxf(a0 + b0, 0.f)) | ((u32)f2bf(fmaxf(a1 + b1, 0.f)) << 16);
    } else {
        o = 0u;
    }
    *(u32*)(outb + (size_t)i * 64 + c2) = o;
}

// ---------------- launch ----------------

extern "C" void kernel_launch(void* const* d_in, const int* in_sizes, int n_in,
                              void* d_out, int out_size, void* d_ws, size_t ws_size,
                              hipStream_t stream)
{
    const float* x  = (const float*)d_in[0];
    const int*   ei = (const int*)d_in[1];
    const float* W1 = (const float*)d_in[2];
    const float* b1 = (const float*)d_in[3];
    const float* W2 = (const float*)d_in[4];
    const float* b2 = (const float*)d_in[5];
    const float* W3 = (const float*)d_in[6];
    const float* b3 = (const float*)d_in[7];
    const float* lw = (const float*)d_in[8];
    const float* lb = (const float*)d_in[9];

    int N = in_sizes[0] / 256;
    int E = in_sizes[1] / 2;
    const int* erow = ei;       // source nodes
    const int* ecol = ei + E;   // target nodes

    char* ws = (char*)d_ws;
    size_t o = 0;
    auto alloc = [&](size_t bytes) -> void* {
        void* p = ws + o;
        o += (bytes + 255) & ~(size_t)255;
        return p;
    };
    int*   cnt  = (int*)alloc((size_t)N * 4);
    int*   off  = (int*)alloc((size_t)(N + 1) * 4);
    int*   fil  = (int*)alloc((size_t)N * 4);
    int*   bsum = (int*)alloc(1024 * 4);
    float* dis  = (float*)alloc((size_t)N * 4);
    int*   srcs = (int*)alloc((size_t)E * 4);
    u16*   W1t  = (u16*)alloc(256 * 256 * 2);
    u16*   W2t  = (u16*)alloc(256 * 256 * 2);
    u16*   W3t  = (u16*)alloc(128 * 256 * 2);
    u16*   lwAt = (u16*)alloc(128 * 256 * 2);
    u16*   lwBt = (u16*)alloc(128 * 256 * 2);
    u16*   lwCt = (u16*)alloc(128 * 64 * 2);
    u16*   xb   = (u16*)alloc((size_t)N * 256 * 2);
    u16*   htb  = (u16*)alloc((size_t)N * 256 * 2);
    u16*   h1b  = (u16*)alloc((size_t)N * 256 * 2);
    u16*   h2b  = (u16*)alloc((size_t)N * 256 * 2);
    u16*   h3b  = (u16*)alloc((size_t)N * 64 * 2);
    u16*   ht3b = htb;   // [N][64] view, reuse

    const int tb = 256;
    init_kernel<<<(N + tb - 1) / tb, tb, 0, stream>>>(cnt, N);
    hist_kernel<<<(E + tb - 1) / tb, tb, 0, stream>>>(ecol, cnt, E);
    int nb = (N + 511) / 512;
    scan1<<<nb, 512, 0, stream>>>(cnt, off, bsum, dis, N);
    scan2<<<1, 256, 0, stream>>>(bsum, nb);
    scan3<<<nb, 512, 0, stream>>>(off, fil, bsum, N);
    {
        const int npass = 8;
        int chunk = (N + npass - 1) / npass;
        fill_kernel<<<2048, 256, 0, stream>>>(erow, ecol, fil, srcs, E, chunk, npass);
    }

    cast_f2b<<<(N * 64 + tb - 1) / tb, tb, 0, stream>>>(x, xb, N * 64);
    tcast<<<(256 * 256 + tb - 1) / tb, tb, 0, stream>>>(W1, W1t, 256, 256, 256, 256, 256);
    tcast<<<(256 * 256 + tb - 1) / tb, tb, 0, stream>>>(W2, W2t, 256, 256, 256, 256, 256);
    tcast<<<(128 * 256 + tb - 1) / tb, tb, 0, stream>>>(W3, W3t, 256, 40, 40, 256, 128);
    tcast<<<(128 * 256 + tb - 1) / tb, tb, 0, stream>>>(lw,            lwAt, 256, 40, 40, 256, 128);
    tcast<<<(128 * 256 + tb - 1) / tb, tb, 0, stream>>>(lw + 256 * 40, lwBt, 256, 40, 40, 256, 128);
    tcast<<<(128 * 64  + tb - 1) / tb, tb, 0, stream>>>(lw + 512 * 40, lwCt, 40, 40, 40, 64, 128);

    dim3 gBig(2, (N + 127) / 128);
    dim3 gSm(1, (N + 127) / 128);
    int nAgg4 = (N + 3) / 4;
    int nAgg8 = (N + 7) / 8;

    // layer 1
    gemm_mfma<<<gBig, 256, 0, stream>>>(xb, 256, W1t, 256, nullptr, htb, 256, N, 256, 256, 2);
    agg256_bf16<<<nAgg4, 256, 0, stream>>>(htb, off, cnt, srcs, dis, b1, h1b, N);
    // layer 2
    gemm_mfma<<<gBig, 256, 0, stream>>>(h1b, 256, W2t, 256, nullptr, htb, 256, N, 256, 256, 2);
    agg256_bf16<<<nAgg4, 256, 0, stream>>>(htb, off, cnt, srcs, dis, b2, h2b, N);
    // layer 3
    gemm_mfma<<<gSm, 256, 0, stream>>>(h2b, 256, W3t, 256, nullptr, ht3b, 64, N, 40, 256, 2);
    agg40_bf16<<<nAgg8, 256, 0, stream>>>(ht3b, off, cnt, srcs, dis, b3, h3b, N);

    // fused final projection + log_softmax
    gemm3_lsm<<<(N + 127) / 128, 256, 0, stream>>>(
        h1b, h2b, h3b, lwAt, lwBt, lwCt, lb, (float*)d_out, N);
}

// Round 6
// 583.066 us; speedup vs baseline: 2.9584x; 1.0728x over previous
//
#include <hip/hip_runtime.h>
#include <math.h>

typedef unsigned short u16;
typedef unsigned int u32;
typedef __attribute__((ext_vector_type(8))) short bf16x8;
typedef __attribute__((ext_vector_type(4))) float f32x4;

__device__ __forceinline__ float bf2f(u16 u) {
    union { unsigned u; float f; } v; v.u = (unsigned)u << 16; return v.f;
}
__device__ __forceinline__ u16 f2bf(float f) {
    union { float f; unsigned u; } v; v.f = f;
    unsigned r = v.u + 0x7FFF + ((v.u >> 16) & 1);   // RNE
    return (u16)(r >> 16);
}

// ---------------- CSR build ----------------

__global__ void init_kernel(int* cnt, int n) {
    int i = blockIdx.x * blockDim.x + threadIdx.x;
    if (i < n) cnt[i] = 0;
}

__global__ void hist_kernel(const int* __restrict__ col, int* __restrict__ cnt, int e) {
    int i = blockIdx.x * blockDim.x + threadIdx.x;
    if (i < e) atomicAdd(&cnt[col[i]], 1);
}

// scan1 also emits dis[i] = rsqrt(deg_with_selfloop)
__global__ void scan1(const int* __restrict__ cnt, int* __restrict__ off,
                      int* __restrict__ bsum, float* __restrict__ dis, int n) {
    __shared__ int s[512];
    int t = threadIdx.x;
    int i = blockIdx.x * 512 + t;
    int v = (i < n) ? cnt[i] : 0;
    if (i < n) dis[i] = rsqrtf((float)v + 1.0f);
    s[t] = v; __syncthreads();
    for (int d = 1; d < 512; d <<= 1) {
        int a = (t >= d) ? s[t - d] : 0;
        __syncthreads();
        s[t] += a;
        __syncthreads();
    }
    if (i < n) off[i] = s[t] - v;
    if (t == 511) bsum[blockIdx.x] = s[511];
}

__global__ void scan2(int* bsum, int nb) {
    __shared__ int s[256];
    int t = threadIdx.x;
    int v = (t < nb) ? bsum[t] : 0;
    s[t] = v; __syncthreads();
    for (int d = 1; d < 256; d <<= 1) {
        int a = (t >= d) ? s[t - d] : 0;
        __syncthreads();
        s[t] += a;
        __syncthreads();
    }
    if (t < nb) bsum[t] = s[t] - v;
}

// scan3 also seeds fil[i] = off[i]
__global__ void scan3(int* off, int* fil, const int* __restrict__ bsum, int n) {
    int i = blockIdx.x * 512 + threadIdx.x;
    if (i < n) {
        int v = off[i] + bsum[blockIdx.x];
        off[i] = v;
        fil[i] = v;
    }
}

// Multi-pass predicated fill: pass p handles dst in [p*chunk, (p+1)*chunk).
// Scatter writes stay in an L2-resident window -> partial lines merge in cache.
__global__ void fill_kernel(const int* __restrict__ erow, const int* __restrict__ ecol,
                            int* __restrict__ fil, int* __restrict__ srcs,
                            int e, int chunk, int npass) {
    int stride = gridDim.x * blockDim.x;
    int t0 = blockIdx.x * blockDim.x + threadIdx.x;
    for (int p = 0; p < npass; ++p) {
        int lo = p * chunk, hi = lo + chunk;
        for (int i = t0; i < e; i += stride) {
            int c = ecol[i];
            if (c >= lo && c < hi) {
                int slot = atomicAdd(&fil[c], 1);
                srcs[slot] = erow[i];
            }
        }
    }
}

// ---------------- casts ----------------

__global__ void cast_f2b(const float* __restrict__ in, u16* __restrict__ out, int n4) {
    int i = blockIdx.x * blockDim.x + threadIdx.x;
    if (i < n4) {
        float4 v = ((const float4*)in)[i];
        ushort4 o;
        o.x = f2bf(v.x); o.y = f2bf(v.y); o.z = f2bf(v.z); o.w = f2bf(v.w);
        ((ushort4*)out)[i] = o;
    }
}

// transpose+cast: in fp32 [K][Nin] -> out bf16 [Npad][Kld], zero-padded
__global__ void tcast(const float* __restrict__ in, u16* __restrict__ out,
                      int K, int Nin, int ncols, int Kld, int Npad) {
    int idx = blockIdx.x * blockDim.x + threadIdx.x;
    if (idx >= Npad * Kld) return;
    int n = idx / Kld, k = idx % Kld;
    float v = (n < ncols && k < K) ? in[(size_t)k * Nin + n] : 0.f;
    out[idx] = f2bf(v);
}

// ---------------- MFMA helpers ----------------

#define SWZ(row) ((((row) & 3) ^ (((row) >> 2) & 3)))

__device__ __forceinline__ void gload_lds16(const void* g, void* l) {
    __builtin_amdgcn_global_load_lds(
        (const __attribute__((address_space(1))) unsigned int*)g,
        (__attribute__((address_space(3))) unsigned int*)l, 16, 0, 0);
}

// ---------------- big GEMM: C[M,256] = A[M,K] @ Bt[256,K]^T, bf16 out ----------------
// tile 128x256, BK=32, 8 waves (2 row-groups x 4 col-groups), each wave 64x64.

__global__ __launch_bounds__(512) void gemm256(
    const u16* __restrict__ A, int lda,
    const u16* __restrict__ Bt, int ldb,
    u16* __restrict__ C, int ldc,
    int M, int K)
{
    __shared__ u16 As[128 * 32];   // 8 KB
    __shared__ u16 Bs[256 * 32];   // 16 KB
    int tid = threadIdx.x;
    int ln = tid & 63, wv = tid >> 6;
    int wr = wv >> 2, wc = wv & 3;
    int br = blockIdx.y * 128;

    f32x4 acc[4][4];
    #pragma unroll
    for (int m = 0; m < 4; ++m)
        #pragma unroll
        for (int n = 0; n < 4; ++n)
            acc[m][n] = (f32x4){0.f, 0.f, 0.f, 0.f};

    for (int k0 = 0; k0 < K; k0 += 32) {
        __syncthreads();
        {   // A: 512 chunks, 1/thread
            int l = tid;
            int row = l >> 2, sp = l & 3;
            int sl = sp ^ SWZ(row);
            int arow = br + row; if (arow >= M) arow = M - 1;
            gload_lds16(A + (size_t)arow * lda + k0 + sl * 8,
                        (char*)As + wv * 1024);
        }
        #pragma unroll
        for (int r = 0; r < 2; ++r) {   // B: 1024 chunks, 2/thread
            int l = r * 512 + tid;
            int row = l >> 2, sp = l & 3;
            int sl = sp ^ SWZ(row);
            gload_lds16(Bt + (size_t)row * ldb + k0 + sl * 8,
                        (char*)Bs + r * 8192 + wv * 1024);
        }
        __syncthreads();
        bf16x8 af[4], bf_[4];
        #pragma unroll
        for (int m = 0; m < 4; ++m) {
            int row = wr * 64 + m * 16 + (ln & 15);
            int sl = ((ln >> 4) ^ SWZ(row)) & 3;
            af[m] = *(const bf16x8*)((const char*)As + row * 64 + sl * 16);
        }
        #pragma unroll
        for (int n = 0; n < 4; ++n) {
            int row = wc * 64 + n * 16 + (ln & 15);
            int sl = ((ln >> 4) ^ SWZ(row)) & 3;
            bf_[n] = *(const bf16x8*)((const char*)Bs + row * 64 + sl * 16);
        }
        #pragma unroll
        for (int m = 0; m < 4; ++m)
            #pragma unroll
            for (int n = 0; n < 4; ++n)
                acc[m][n] = __builtin_amdgcn_mfma_f32_16x16x32_bf16(af[m], bf_[n], acc[m][n], 0, 0, 0);
    }

    #pragma unroll
    for (int m = 0; m < 4; ++m) {
        #pragma unroll
        for (int n = 0; n < 4; ++n) {
            #pragma unroll
            for (int j = 0; j < 4; ++j) {
                int r = br + wr * 64 + m * 16 + (ln >> 4) * 4 + j;
                int c = wc * 64 + n * 16 + (ln & 15);
                if (r < M)
                    C[(size_t)r * ldc + c] = f2bf(acc[m][n][j]);
            }
        }
    }
}

// ---------------- W3 GEMM: C[M,Ncols<=64] = A[M,K] @ Bt[64+,K]^T, bf16 out ----------------
// tile 128x64, BK=32, 4 waves, each wave 32x64 (2x4 frags).

__global__ __launch_bounds__(256) void gemm_w3(
    const u16* __restrict__ A, int lda,
    const u16* __restrict__ Bt, int ldb,
    u16* __restrict__ C, int ldc,
    int M, int Ncols, int K)
{
    __shared__ u16 As[128 * 32];   // 8 KB
    __shared__ u16 Bs[64 * 32];    // 4 KB
    int tid = threadIdx.x;
    int ln = tid & 63, wv = tid >> 6;
    int br = blockIdx.y * 128;

    f32x4 acc[2][4];
    #pragma unroll
    for (int m = 0; m < 2; ++m)
        #pragma unroll
        for (int n = 0; n < 4; ++n)
            acc[m][n] = (f32x4){0.f, 0.f, 0.f, 0.f};

    for (int k0 = 0; k0 < K; k0 += 32) {
        __syncthreads();
        #pragma unroll
        for (int r = 0; r < 2; ++r) {   // A: 512 chunks, 2/thread
            int l = r * 256 + tid;
            int row = l >> 2, sp = l & 3;
            int sl = sp ^ SWZ(row);
            int arow = br + row; if (arow >= M) arow = M - 1;
            gload_lds16(A + (size_t)arow * lda + k0 + sl * 8,
                        (char*)As + r * 4096 + wv * 1024);
        }
        {   // B: 256 chunks, 1/thread
            int l = tid;
            int row = l >> 2, sp = l & 3;
            int sl = sp ^ SWZ(row);
            gload_lds16(Bt + (size_t)row * ldb + k0 + sl * 8,
                        (char*)Bs + wv * 1024);
        }
        __syncthreads();
        bf16x8 af[2], bf_[4];
        #pragma unroll
        for (int m = 0; m < 2; ++m) {
            int row = wv * 32 + m * 16 + (ln & 15);
            int sl = ((ln >> 4) ^ SWZ(row)) & 3;
            af[m] = *(const bf16x8*)((const char*)As + row * 64 + sl * 16);
        }
        #pragma unroll
        for (int n = 0; n < 4; ++n) {
            int row = n * 16 + (ln & 15);
            int sl = ((ln >> 4) ^ SWZ(row)) & 3;
            bf_[n] = *(const bf16x8*)((const char*)Bs + row * 64 + sl * 16);
        }
        #pragma unroll
        for (int m = 0; m < 2; ++m)
            #pragma unroll
            for (int n = 0; n < 4; ++n)
                acc[m][n] = __builtin_amdgcn_mfma_f32_16x16x32_bf16(af[m], bf_[n], acc[m][n], 0, 0, 0);
    }

    #pragma unroll
    for (int m = 0; m < 2; ++m) {
        #pragma unroll
        for (int n = 0; n < 4; ++n) {
            #pragma unroll
            for (int j = 0; j < 4; ++j) {
                int r = br + wv * 32 + m * 16 + (ln >> 4) * 4 + j;
                int c = n * 16 + (ln & 15);
                if (r < M && c < Ncols)
                    C[(size_t)r * ldc + c] = f2bf(acc[m][n][j]);
            }
        }
    }
}

// ---------------- fused final: out = lsm(h1@B0 + h2@B1 + h3@B2 + lb) ----------------

__global__ __launch_bounds__(256) void gemm3_lsm(
    const u16* __restrict__ A0, const u16* __restrict__ A1, const u16* __restrict__ A2,
    const u16* __restrict__ B0, const u16* __restrict__ B1, const u16* __restrict__ B2,
    const float* __restrict__ bias,
    float* __restrict__ out, int M)
{
    __shared__ u16 As[128 * 32];
    __shared__ u16 Bs[64 * 32];
    int tid = threadIdx.x;
    int ln = tid & 63, wv = tid >> 6;
    int br = blockIdx.x * 128;

    f32x4 acc[2][4];
    #pragma unroll
    for (int m = 0; m < 2; ++m)
        #pragma unroll
        for (int n = 0; n < 4; ++n)
            acc[m][n] = (f32x4){0.f, 0.f, 0.f, 0.f};

    auto do_seg = [&](const u16* __restrict__ A, const u16* __restrict__ B, int K) {
        for (int k0 = 0; k0 < K; k0 += 32) {
            __syncthreads();
            #pragma unroll
            for (int r = 0; r < 2; ++r) {
                int l = r * 256 + tid;
                int row = l >> 2, sp = l & 3;
                int sl = sp ^ SWZ(row);
                int arow = br + row; if (arow >= M) arow = M - 1;
                gload_lds16(A + (size_t)arow * K + k0 + sl * 8,
                            (char*)As + r * 4096 + wv * 1024);
            }
            {
                int l = tid;
                int row = l >> 2, sp = l & 3;
                int sl = sp ^ SWZ(row);
                gload_lds16(B + (size_t)row * K + k0 + sl * 8,
                            (char*)Bs + wv * 1024);
            }
            __syncthreads();
            bf16x8 af[2], bf_[4];
            #pragma unroll
            for (int m = 0; m < 2; ++m) {
                int row = wv * 32 + m * 16 + (ln & 15);
                int sl = ((ln >> 4) ^ SWZ(row)) & 3;
                af[m] = *(const bf16x8*)((const char*)As + row * 64 + sl * 16);
            }
            #pragma unroll
            for (int nn = 0; nn < 4; ++nn) {
                int row = nn * 16 + (ln & 15);
                int sl = ((ln >> 4) ^ SWZ(row)) & 3;
                bf_[nn] = *(const bf16x8*)((const char*)Bs + row * 64 + sl * 16);
            }
            #pragma unroll
            for (int m = 0; m < 2; ++m)
                #pragma unroll
                for (int nn = 0; nn < 4; ++nn)
                    acc[m][nn] = __builtin_amdgcn_mfma_f32_16x16x32_bf16(af[m], bf_[nn], acc[m][nn], 0, 0, 0);
        }
    };
    do_seg(A0, B0, 256);
    do_seg(A1, B1, 256);
    do_seg(A2, B2, 64);

    int l15 = ln & 15;
    #pragma unroll
    for (int m = 0; m < 2; ++m) {
        #pragma unroll
        for (int j = 0; j < 4; ++j) {
            int r = br + wv * 32 + m * 16 + (ln >> 4) * 4 + j;
            float v0 = acc[m][0][j] + bias[l15];
            float v1 = acc[m][1][j] + bias[16 + l15];
            float v2 = (l15 < 8) ? (acc[m][2][j] + bias[32 + l15]) : -INFINITY;
            float mx = fmaxf(fmaxf(v0, v1), v2);
            #pragma unroll
            for (int o = 8; o; o >>= 1) mx = fmaxf(mx, __shfl_xor(mx, o));
            float s = expf(v0 - mx) + expf(v1 - mx) + ((l15 < 8) ? expf(v2 - mx) : 0.f);
            #pragma unroll
            for (int o = 8; o; o >>= 1) s += __shfl_xor(s, o);
            float ls = logf(s);
            if (r < M) {
                out[(size_t)r * 40 + l15]      = v0 - mx - ls;
                out[(size_t)r * 40 + 16 + l15] = v1 - mx - ls;
                if (l15 < 8) out[(size_t)r * 40 + 32 + l15] = v2 - mx - ls;
            }
        }
    }
}

// ---------------- aggregation F=256 bf16: wave per node, 8-deep gather ----------------

__global__ __launch_bounds__(256) void agg256_bf16(
    const u16* __restrict__ ht,
    const int* __restrict__ off, const int* __restrict__ cnt,
    const int* __restrict__ srcs, const float* __restrict__ dis,
    const float* __restrict__ bias,
    u16* __restrict__ outb, int n)
{
    int wv = threadIdx.x >> 6, ln = threadIdx.x & 63;
    int i = blockIdx.x * 4 + wv;
    if (i >= n) return;
    int c = ln * 4;
    float di = dis[i], dd = di * di;
    ushort4 sv = *(const ushort4*)(ht + (size_t)i * 256 + c);
    float a0 = bf2f(sv.x) * dd, a1 = bf2f(sv.y) * dd, a2 = bf2f(sv.z) * dd, a3 = bf2f(sv.w) * dd;
    int beg = off[i], num = cnt[i];
    for (int base = 0; base < num; base += 64) {
        int rem = num - base; if (rem > 64) rem = 64;
        int sl = 0; float dsl = 0.f;
        if (ln < rem) { sl = srcs[beg + base + ln]; dsl = dis[sl]; }
        int j = 0;
        for (; j + 8 <= rem; j += 8) {
            int s[8]; float w[8]; ushort4 v[8];
            #pragma unroll
            for (int q = 0; q < 8; ++q) {
                s[q] = __shfl(sl, j + q);
                w[q] = __shfl(dsl, j + q) * di;
            }
            #pragma unroll
            for (int q = 0; q < 8; ++q)
                v[q] = *(const ushort4*)(ht + (size_t)s[q] * 256 + c);
            #pragma unroll
            for (int q = 0; q < 8; ++q) {
                a0 += bf2f(v[q].x) * w[q];
                a1 += bf2f(v[q].y) * w[q];
                a2 += bf2f(v[q].z) * w[q];
                a3 += bf2f(v[q].w) * w[q];
            }
        }
        for (; j + 4 <= rem; j += 4) {
            int s[4]; float w[4]; ushort4 v[4];
            #pragma unroll
            for (int q = 0; q < 4; ++q) {
                s[q] = __shfl(sl, j + q);
                w[q] = __shfl(dsl, j + q) * di;
            }
            #pragma unroll
            for (int q = 0; q < 4; ++q)
                v[q] = *(const ushort4*)(ht + (size_t)s[q] * 256 + c);
            #pragma unroll
            for (int q = 0; q < 4; ++q) {
                a0 += bf2f(v[q].x) * w[q];
                a1 += bf2f(v[q].y) * w[q];
                a2 += bf2f(v[q].z) * w[q];
                a3 += bf2f(v[q].w) * w[q];
            }
        }
        for (; j < rem; ++j) {
            int s0 = __shfl(sl, j);
            float w0 = __shfl(dsl, j) * di;
            ushort4 v0 = *(const ushort4*)(ht + (size_t)s0 * 256 + c);
            a0 += bf2f(v0.x) * w0; a1 += bf2f(v0.y) * w0;
            a2 += bf2f(v0.z) * w0; a3 += bf2f(v0.w) * w0;
        }
    }
    float4 bv = *(const float4*)(bias + c);
    ushort4 o;
    o.x = f2bf(fmaxf(a0 + bv.x, 0.f));
    o.y = f2bf(fmaxf(a1 + bv.y, 0.f));
    o.z = f2bf(fmaxf(a2 + bv.z, 0.f));
    o.w = f2bf(fmaxf(a3 + bv.w, 0.f));
    *(ushort4*)(outb + (size_t)i * 256 + c) = o;
}

// F=40 (stride 64): HALF-wave per node, uint loads (2 feats/lane)
__global__ __launch_bounds__(256) void agg40_bf16(
    const u16* __restrict__ ht,
    const int* __restrict__ off, const int* __restrict__ cnt,
    const int* __restrict__ srcs, const float* __restrict__ dis,
    const float* __restrict__ bias,
    u16* __restrict__ outb, int n)
{
    int half = threadIdx.x >> 5;
    int l = threadIdx.x & 31;
    int i = blockIdx.x * 8 + half;
    if (i >= n) return;
    int c2 = l * 2;
    float di = dis[i], dd = di * di;
    u32 sv = *(const u32*)(ht + (size_t)i * 64 + c2);
    float a0 = bf2f((u16)(sv & 0xffff)) * dd;
    float a1 = bf2f((u16)(sv >> 16)) * dd;
    int beg = off[i], num = cnt[i];
    for (int base = 0; base < num; base += 32) {
        int rem = num - base; if (rem > 32) rem = 32;
        int sl = 0; float dsl = 0.f;
        if (l < rem) { sl = srcs[beg + base + l]; dsl = dis[sl]; }
        int j = 0;
        for (; j + 8 <= rem; j += 8) {
            int s[8]; float w[8]; u32 v[8];
            #pragma unroll
            for (int q = 0; q < 8; ++q) {
                s[q] = __shfl(sl, j + q, 32);
                w[q] = __shfl(dsl, j + q, 32) * di;
            }
            #pragma unroll
            for (int q = 0; q < 8; ++q)
                v[q] = *(const u32*)(ht + (size_t)s[q] * 64 + c2);
            #pragma unroll
            for (int q = 0; q < 8; ++q) {
                a0 += bf2f((u16)(v[q] & 0xffff)) * w[q];
                a1 += bf2f((u16)(v[q] >> 16)) * w[q];
            }
        }
        for (; j + 4 <= rem; j += 4) {
            int s[4]; float w[4]; u32 v[4];
            #pragma unroll
            for (int q = 0; q < 4; ++q) {
                s[q] = __shfl(sl, j + q, 32);
                w[q] = __shfl(dsl, j + q, 32) * di;
            }
            #pragma unroll
            for (int q = 0; q < 4; ++q)
                v[q] = *(const u32*)(ht + (size_t)s[q] * 64 + c2);
            #pragma unroll
            for (int q = 0; q < 4; ++q) {
                a0 += bf2f((u16)(v[q] & 0xffff)) * w[q];
                a1 += bf2f((u16)(v[q] >> 16)) * w[q];
            }
        }
        for (; j < rem; ++j) {
            int s0 = __shfl(sl, j, 32);
            float w0 = __shfl(dsl, j, 32) * di;
            u32 v0 = *(const u32*)(ht + (size_t)s0 * 64 + c2);
            a0 += bf2f((u16)(v0 & 0xffff)) * w0;
            a1 += bf2f((u16)(v0 >> 16)) * w0;
        }
    }
    u32 o;
    if (l < 20) {
        float b0 = bias[c2], b1 = bias[c2 + 1];
        o = (u32)f2bf(fmaxf(a0 + b0, 0.f)) | ((u32)f2bf(fmaxf(a1 + b1, 0.f)) << 16);
    } else {
        o = 0u;
    }
    *(u32*)(outb + (size_t)i * 64 + c2) = o;
}

// ---------------- launch ----------------

extern "C" void kernel_launch(void* const* d_in, const int* in_sizes, int n_in,
                              void* d_out, int out_size, void* d_ws, size_t ws_size,
                              hipStream_t stream)
{
    const float* x  = (const float*)d_in[0];
    const int*   ei = (const int*)d_in[1];
    const float* W1 = (const float*)d_in[2];
    const float* b1 = (const float*)d_in[3];
    const float* W2 = (const float*)d_in[4];
    const float* b2 = (const float*)d_in[5];
    const float* W3 = (const float*)d_in[6];
    const float* b3 = (const float*)d_in[7];
    const float* lw = (const float*)d_in[8];
    const float* lb = (const float*)d_in[9];

    int N = in_sizes[0] / 256;
    int E = in_sizes[1] / 2;
    const int* erow = ei;       // source nodes
    const int* ecol = ei + E;   // target nodes

    char* ws = (char*)d_ws;
    size_t o = 0;
    auto alloc = [&](size_t bytes) -> void* {
        void* p = ws + o;
        o += (bytes + 255) & ~(size_t)255;
        return p;
    };
    int*   cnt  = (int*)alloc((size_t)N * 4);
    int*   off  = (int*)alloc((size_t)(N + 1) * 4);
    int*   fil  = (int*)alloc((size_t)N * 4);
    int*   bsum = (int*)alloc(1024 * 4);
    float* dis  = (float*)alloc((size_t)N * 4);
    int*   srcs = (int*)alloc((size_t)E * 4);
    u16*   W1t  = (u16*)alloc(256 * 256 * 2);
    u16*   W2t  = (u16*)alloc(256 * 256 * 2);
    u16*   W3t  = (u16*)alloc(128 * 256 * 2);
    u16*   lwAt = (u16*)alloc(128 * 256 * 2);
    u16*   lwBt = (u16*)alloc(128 * 256 * 2);
    u16*   lwCt = (u16*)alloc(128 * 64 * 2);
    u16*   xb   = (u16*)alloc((size_t)N * 256 * 2);
    u16*   htb  = (u16*)alloc((size_t)N * 256 * 2);
    u16*   h1b  = (u16*)alloc((size_t)N * 256 * 2);
    u16*   h2b  = (u16*)alloc((size_t)N * 256 * 2);
    u16*   h3b  = (u16*)alloc((size_t)N * 64 * 2);
    u16*   ht3b = htb;   // [N][64] view, reuse

    const int tb = 256;
    init_kernel<<<(N + tb - 1) / tb, tb, 0, stream>>>(cnt, N);
    hist_kernel<<<(E + tb - 1) / tb, tb, 0, stream>>>(ecol, cnt, E);
    int nb = (N + 511) / 512;
    scan1<<<nb, 512, 0, stream>>>(cnt, off, bsum, dis, N);
    scan2<<<1, 256, 0, stream>>>(bsum, nb);
    scan3<<<nb, 512, 0, stream>>>(off, fil, bsum, N);
    {
        const int npass = 8;
        int chunk = (N + npass - 1) / npass;
        fill_kernel<<<2048, 256, 0, stream>>>(erow, ecol, fil, srcs, E, chunk, npass);
    }

    cast_f2b<<<(N * 64 + tb - 1) / tb, tb, 0, stream>>>(x, xb, N * 64);
    tcast<<<(256 * 256 + tb - 1) / tb, tb, 0, stream>>>(W1, W1t, 256, 256, 256, 256, 256);
    tcast<<<(256 * 256 + tb - 1) / tb, tb, 0, stream>>>(W2, W2t, 256, 256, 256, 256, 256);
    tcast<<<(128 * 256 + tb - 1) / tb, tb, 0, stream>>>(W3, W3t, 256, 40, 40, 256, 128);
    tcast<<<(128 * 256 + tb - 1) / tb, tb, 0, stream>>>(lw,            lwAt, 256, 40, 40, 256, 128);
    tcast<<<(128 * 256 + tb - 1) / tb, tb, 0, stream>>>(lw + 256 * 40, lwBt, 256, 40, 40, 256, 128);
    tcast<<<(128 * 64  + tb - 1) / tb, tb, 0, stream>>>(lw + 512 * 40, lwCt, 40, 40, 40, 64, 128);

    dim3 gBig(1, (N + 127) / 128);
    int nAgg4 = (N + 3) / 4;
    int nAgg8 = (N + 7) / 8;

    // layer 1
    gemm256<<<gBig, 512, 0, stream>>>(xb, 256, W1t, 256, htb, 256, N, 256);
    agg256_bf16<<<nAgg4, 256, 0, stream>>>(htb, off, cnt, srcs, dis, b1, h1b, N);
    // layer 2
    gemm256<<<gBig, 512, 0, stream>>>(h1b, 256, W2t, 256, htb, 256, N, 256);
    agg256_bf16<<<nAgg4, 256, 0, stream>>>(htb, off, cnt, srcs, dis, b2, h2b, N);
    // layer 3
    gemm_w3<<<gBig, 256, 0, stream>>>(h2b, 256, W3t, 256, ht3b, 64, N, 40, 256);
    agg40_bf16<<<nAgg8, 256, 0, stream>>>(ht3b, off, cnt, srcs, dis, b3, h3b, N);

    // fused final projection + log_softmax
    gemm3_lsm<<<(N + 127) / 128, 256, 0, stream>>>(
        h1b, h2b, h3b, lwAt, lwBt, lwCt, lb, (float*)d_out, N);
}

// Round 7
// 468.413 us; speedup vs baseline: 3.6825x; 1.2448x over previous
//
#include <hip/hip_runtime.h>
#include <math.h>

typedef unsigned short u16;
typedef unsigned int u32;
typedef unsigned char u8;
typedef __attribute__((ext_vector_type(8))) short bf16x8;
typedef __attribute__((ext_vector_type(4))) float f32x4;
typedef __attribute__((ext_vector_type(2))) float f32x2;

__device__ __forceinline__ float bf2f(u16 u) {
    union { unsigned u; float f; } v; v.u = (unsigned)u << 16; return v.f;
}
__device__ __forceinline__ u16 f2bf(float f) {
    union { float f; unsigned u; } v; v.f = f;
    unsigned r = v.u + 0x7FFF + ((v.u >> 16) & 1);   // RNE
    return (u16)(r >> 16);
}

// ---------------- CSR build ----------------

__global__ void init_kernel(int* cnt, int n) {
    int i = blockIdx.x * blockDim.x + threadIdx.x;
    if (i < n) cnt[i] = 0;
}

__global__ void hist_kernel(const int* __restrict__ col, int* __restrict__ cnt, int e) {
    int i = blockIdx.x * blockDim.x + threadIdx.x;
    if (i < e) atomicAdd(&cnt[col[i]], 1);
}

// scan1 also emits dis[i] = rsqrt(deg_with_selfloop)
__global__ void scan1(const int* __restrict__ cnt, int* __restrict__ off,
                      int* __restrict__ bsum, float* __restrict__ dis, int n) {
    __shared__ int s[512];
    int t = threadIdx.x;
    int i = blockIdx.x * 512 + t;
    int v = (i < n) ? cnt[i] : 0;
    if (i < n) dis[i] = rsqrtf((float)v + 1.0f);
    s[t] = v; __syncthreads();
    for (int d = 1; d < 512; d <<= 1) {
        int a = (t >= d) ? s[t - d] : 0;
        __syncthreads();
        s[t] += a;
        __syncthreads();
    }
    if (i < n) off[i] = s[t] - v;
    if (t == 511) bsum[blockIdx.x] = s[511];
}

__global__ void scan2(int* bsum, int nb) {
    __shared__ int s[256];
    int t = threadIdx.x;
    int v = (t < nb) ? bsum[t] : 0;
    s[t] = v; __syncthreads();
    for (int d = 1; d < 256; d <<= 1) {
        int a = (t >= d) ? s[t - d] : 0;
        __syncthreads();
        s[t] += a;
        __syncthreads();
    }
    if (t < nb) bsum[t] = s[t] - v;
}

// scan3 also seeds fil[i] = off[i]
__global__ void scan3(int* off, int* fil, const int* __restrict__ bsum, int n) {
    int i = blockIdx.x * 512 + threadIdx.x;
    if (i < n) {
        int v = off[i] + bsum[blockIdx.x];
        off[i] = v;
        fil[i] = v;
    }
}

// Multi-pass predicated fill: scatter writes stay in an L2-resident window.
__global__ void fill_kernel(const int* __restrict__ erow, const int* __restrict__ ecol,
                            int* __restrict__ fil, int* __restrict__ srcs,
                            int e, int chunk, int npass) {
    int stride = gridDim.x * blockDim.x;
    int t0 = blockIdx.x * blockDim.x + threadIdx.x;
    for (int p = 0; p < npass; ++p) {
        int lo = p * chunk, hi = lo + chunk;
        for (int i = t0; i < e; i += stride) {
            int c = ecol[i];
            if (c >= lo && c < hi) {
                int slot = atomicAdd(&fil[c], 1);
                srcs[slot] = erow[i];
            }
        }
    }
}

// ---------------- casts ----------------

__global__ void cast_f2b(const float* __restrict__ in, u16* __restrict__ out, int n4) {
    int i = blockIdx.x * blockDim.x + threadIdx.x;
    if (i < n4) {
        float4 v = ((const float4*)in)[i];
        ushort4 o;
        o.x = f2bf(v.x); o.y = f2bf(v.y); o.z = f2bf(v.z); o.w = f2bf(v.w);
        ((ushort4*)out)[i] = o;
    }
}

// One kernel for all 6 weight transposes+casts.
__global__ void prep_weights(const float* __restrict__ W1, const float* __restrict__ W2,
                             const float* __restrict__ W3, const float* __restrict__ lw,
                             u16* __restrict__ W1t, u16* __restrict__ W2t,
                             u16* __restrict__ W3t, u16* __restrict__ lwAt,
                             u16* __restrict__ lwBt, u16* __restrict__ lwCt) {
    int idx = blockIdx.x * blockDim.x + threadIdx.x;
    if (idx < 65536) {                       // W1t [256][256] <- W1[k][n]
        int n = idx >> 8, k = idx & 255;
        W1t[idx] = f2bf(W1[k * 256 + n]);
    } else if (idx < 131072) {               // W2t
        int i = idx - 65536; int n = i >> 8, k = i & 255;
        W2t[i] = f2bf(W2[k * 256 + n]);
    } else if (idx < 163840) {               // W3t [128][256] <- W3[k][n], n<40
        int i = idx - 131072; int n = i >> 8, k = i & 255;
        W3t[i] = (n < 40) ? f2bf(W3[k * 40 + n]) : (u16)0;
    } else if (idx < 196608) {               // lwAt <- lw[k][n], k=0..255
        int i = idx - 163840; int n = i >> 8, k = i & 255;
        lwAt[i] = (n < 40) ? f2bf(lw[k * 40 + n]) : (u16)0;
    } else if (idx < 229376) {               // lwBt <- lw[256+k][n]
        int i = idx - 196608; int n = i >> 8, k = i & 255;
        lwBt[i] = (n < 40) ? f2bf(lw[(256 + k) * 40 + n]) : (u16)0;
    } else if (idx < 237568) {               // lwCt [128][64] <- lw[512+k][n], k<40
        int i = idx - 229376; int n = i >> 6, k = i & 63;
        lwCt[i] = (n < 40 && k < 40) ? f2bf(lw[(512 + k) * 40 + n]) : (u16)0;
    }
}

// ---------------- MFMA helpers ----------------

#define SWZ(row) ((((row) & 3) ^ (((row) >> 2) & 3)))

__device__ __forceinline__ void gload_lds16(const void* g, void* l) {
    __builtin_amdgcn_global_load_lds(
        (const __attribute__((address_space(1))) unsigned int*)g,
        (__attribute__((address_space(3))) unsigned int*)l, 16, 0, 0);
}

// ---------------- big GEMM: C[M,256] = A[M,K] @ Bt[256,K]^T, fp8(e4m3) out ----------------
// tile 128x256, BK=32, 8 waves (2x4), each wave 64x64.

__global__ __launch_bounds__(512) void gemm256(
    const u16* __restrict__ A, int lda,
    const u16* __restrict__ Bt, int ldb,
    u8* __restrict__ C,                 // [M][256] fp8
    int M, int K)
{
    __shared__ u16 As[128 * 32];   // 8 KB
    __shared__ u16 Bs[256 * 32];   // 16 KB
    int tid = threadIdx.x;
    int ln = tid & 63, wv = tid >> 6;
    int wr = wv >> 2, wc = wv & 3;
    int br = blockIdx.y * 128;

    f32x4 acc[4][4];
    #pragma unroll
    for (int m = 0; m < 4; ++m)
        #pragma unroll
        for (int n = 0; n < 4; ++n)
            acc[m][n] = (f32x4){0.f, 0.f, 0.f, 0.f};

    for (int k0 = 0; k0 < K; k0 += 32) {
        __syncthreads();
        {   // A: 512 chunks, 1/thread
            int l = tid;
            int row = l >> 2, sp = l & 3;
            int sl = sp ^ SWZ(row);
            int arow = br + row; if (arow >= M) arow = M - 1;
            gload_lds16(A + (size_t)arow * lda + k0 + sl * 8,
                        (char*)As + wv * 1024);
        }
        #pragma unroll
        for (int r = 0; r < 2; ++r) {   // B: 1024 chunks, 2/thread
            int l = r * 512 + tid;
            int row = l >> 2, sp = l & 3;
            int sl = sp ^ SWZ(row);
            gload_lds16(Bt + (size_t)row * ldb + k0 + sl * 8,
                        (char*)Bs + r * 8192 + wv * 1024);
        }
        __syncthreads();
        bf16x8 af[4], bf_[4];
        #pragma unroll
        for (int m = 0; m < 4; ++m) {
            int row = wr * 64 + m * 16 + (ln & 15);
            int sl = ((ln >> 4) ^ SWZ(row)) & 3;
            af[m] = *(const bf16x8*)((const char*)As + row * 64 + sl * 16);
        }
        #pragma unroll
        for (int n = 0; n < 4; ++n) {
            int row = wc * 64 + n * 16 + (ln & 15);
            int sl = ((ln >> 4) ^ SWZ(row)) & 3;
            bf_[n] = *(const bf16x8*)((const char*)Bs + row * 64 + sl * 16);
        }
        #pragma unroll
        for (int m = 0; m < 4; ++m)
            #pragma unroll
            for (int n = 0; n < 4; ++n)
                acc[m][n] = __builtin_amdgcn_mfma_f32_16x16x32_bf16(af[m], bf_[n], acc[m][n], 0, 0, 0);
    }

    #pragma unroll
    for (int m = 0; m < 4; ++m) {
        #pragma unroll
        for (int n = 0; n < 4; ++n) {
            #pragma unroll
            for (int j = 0; j < 4; ++j) {
                int r = br + wr * 64 + m * 16 + (ln >> 4) * 4 + j;
                int c = wc * 64 + n * 16 + (ln & 15);
                if (r < M) {
                    float v = acc[m][n][j];
                    u32 pk = __builtin_amdgcn_cvt_pk_fp8_f32(v, v, 0, false);
                    C[(size_t)r * 256 + c] = (u8)(pk & 0xff);
                }
            }
        }
    }
}

// ---------------- W3 GEMM: C[M,Ncols<=64] = A[M,K] @ Bt[64+,K]^T, bf16 out ----------------
// tile 128x64, BK=32, 4 waves, each wave 32x64.

__global__ __launch_bounds__(256) void gemm_w3(
    const u16* __restrict__ A, int lda,
    const u16* __restrict__ Bt, int ldb,
    u16* __restrict__ C, int ldc,
    int M, int Ncols, int K)
{
    __shared__ u16 As[128 * 32];
    __shared__ u16 Bs[64 * 32];
    int tid = threadIdx.x;
    int ln = tid & 63, wv = tid >> 6;
    int br = blockIdx.y * 128;

    f32x4 acc[2][4];
    #pragma unroll
    for (int m = 0; m < 2; ++m)
        #pragma unroll
        for (int n = 0; n < 4; ++n)
            acc[m][n] = (f32x4){0.f, 0.f, 0.f, 0.f};

    for (int k0 = 0; k0 < K; k0 += 32) {
        __syncthreads();
        #pragma unroll
        for (int r = 0; r < 2; ++r) {
            int l = r * 256 + tid;
            int row = l >> 2, sp = l & 3;
            int sl = sp ^ SWZ(row);
            int arow = br + row; if (arow >= M) arow = M - 1;
            gload_lds16(A + (size_t)arow * lda + k0 + sl * 8,
                        (char*)As + r * 4096 + wv * 1024);
        }
        {
            int l = tid;
            int row = l >> 2, sp = l & 3;
            int sl = sp ^ SWZ(row);
            gload_lds16(Bt + (size_t)row * ldb + k0 + sl * 8,
                        (char*)Bs + wv * 1024);
        }
        __syncthreads();
        bf16x8 af[2], bf_[4];
        #pragma unroll
        for (int m = 0; m < 2; ++m) {
            int row = wv * 32 + m * 16 + (ln & 15);
            int sl = ((ln >> 4) ^ SWZ(row)) & 3;
            af[m] = *(const bf16x8*)((const char*)As + row * 64 + sl * 16);
        }
        #pragma unroll
        for (int n = 0; n < 4; ++n) {
            int row = n * 16 + (ln & 15);
            int sl = ((ln >> 4) ^ SWZ(row)) & 3;
            bf_[n] = *(const bf16x8*)((const char*)Bs + row * 64 + sl * 16);
        }
        #pragma unroll
        for (int m = 0; m < 2; ++m)
            #pragma unroll
            for (int n = 0; n < 4; ++n)
                acc[m][n] = __builtin_amdgcn_mfma_f32_16x16x32_bf16(af[m], bf_[n], acc[m][n], 0, 0, 0);
    }

    #pragma unroll
    for (int m = 0; m < 2; ++m) {
        #pragma unroll
        for (int n = 0; n < 4; ++n) {
            #pragma unroll
            for (int j = 0; j < 4; ++j) {
                int r = br + wv * 32 + m * 16 + (ln >> 4) * 4 + j;
                int c = n * 16 + (ln & 15);
                if (r < M && c < Ncols)
                    C[(size_t)r * ldc + c] = f2bf(acc[m][n][j]);
            }
        }
    }
}

// ---------------- fused final: out = lsm(h1@B0 + h2@B1 + h3@B2 + lb) ----------------

__global__ __launch_bounds__(256) void gemm3_lsm(
    const u16* __restrict__ A0, const u16* __restrict__ A1, const u16* __restrict__ A2,
    const u16* __restrict__ B0, const u16* __restrict__ B1, const u16* __restrict__ B2,
    const float* __restrict__ bias,
    float* __restrict__ out, int M)
{
    __shared__ u16 As[128 * 32];
    __shared__ u16 Bs[64 * 32];
    int tid = threadIdx.x;
    int ln = tid & 63, wv = tid >> 6;
    int br = blockIdx.x * 128;

    f32x4 acc[2][4];
    #pragma unroll
    for (int m = 0; m < 2; ++m)
        #pragma unroll
        for (int n = 0; n < 4; ++n)
            acc[m][n] = (f32x4){0.f, 0.f, 0.f, 0.f};

    auto do_seg = [&](const u16* __restrict__ A, const u16* __restrict__ B, int K) {
        for (int k0 = 0; k0 < K; k0 += 32) {
            __syncthreads();
            #pragma unroll
            for (int r = 0; r < 2; ++r) {
                int l = r * 256 + tid;
                int row = l >> 2, sp = l & 3;
                int sl = sp ^ SWZ(row);
                int arow = br + row; if (arow >= M) arow = M - 1;
                gload_lds16(A + (size_t)arow * K + k0 + sl * 8,
                            (char*)As + r * 4096 + wv * 1024);
            }
            {
                int l = tid;
                int row = l >> 2, sp = l & 3;
                int sl = sp ^ SWZ(row);
                gload_lds16(B + (size_t)row * K + k0 + sl * 8,
                            (char*)Bs + wv * 1024);
            }
            __syncthreads();
            bf16x8 af[2], bf_[4];
            #pragma unroll
            for (int m = 0; m < 2; ++m) {
                int row = wv * 32 + m * 16 + (ln & 15);
                int sl = ((ln >> 4) ^ SWZ(row)) & 3;
                af[m] = *(const bf16x8*)((const char*)As + row * 64 + sl * 16);
            }
            #pragma unroll
            for (int nn = 0; nn < 4; ++nn) {
                int row = nn * 16 + (ln & 15);
                int sl = ((ln >> 4) ^ SWZ(row)) & 3;
                bf_[nn] = *(const bf16x8*)((const char*)Bs + row * 64 + sl * 16);
            }
            #pragma unroll
            for (int m = 0; m < 2; ++m)
                #pragma unroll
                for (int nn = 0; nn < 4; ++nn)
                    acc[m][nn] = __builtin_amdgcn_mfma_f32_16x16x32_bf16(af[m], bf_[nn], acc[m][nn], 0, 0, 0);
        }
    };
    do_seg(A0, B0, 256);
    do_seg(A1, B1, 256);
    do_seg(A2, B2, 64);

    int l15 = ln & 15;
    #pragma unroll
    for (int m = 0; m < 2; ++m) {
        #pragma unroll
        for (int j = 0; j < 4; ++j) {
            int r = br + wv * 32 + m * 16 + (ln >> 4) * 4 + j;
            float v0 = acc[m][0][j] + bias[l15];
            float v1 = acc[m][1][j] + bias[16 + l15];
            float v2 = (l15 < 8) ? (acc[m][2][j] + bias[32 + l15]) : -INFINITY;
            float mx = fmaxf(fmaxf(v0, v1), v2);
            #pragma unroll
            for (int o = 8; o; o >>= 1) mx = fmaxf(mx, __shfl_xor(mx, o));
            float s = expf(v0 - mx) + expf(v1 - mx) + ((l15 < 8) ? expf(v2 - mx) : 0.f);
            #pragma unroll
            for (int o = 8; o; o >>= 1) s += __shfl_xor(s, o);
            float ls = logf(s);
            if (r < M) {
                out[(size_t)r * 40 + l15]      = v0 - mx - ls;
                out[(size_t)r * 40 + 16 + l15] = v1 - mx - ls;
                if (l15 < 8) out[(size_t)r * 40 + 32 + l15] = v2 - mx - ls;
            }
        }
    }
}

// ---------------- aggregation F=256 fp8: wave per node, 8-deep gather ----------------
// ht is [N][256] fp8 e4m3; lane ln covers feats 4ln..4ln+3 (u32 load).

__global__ __launch_bounds__(256) void agg256_fp8(
    const u8* __restrict__ ht,
    const int* __restrict__ off, const int* __restrict__ cnt,
    const int* __restrict__ srcs, const float* __restrict__ dis,
    const float* __restrict__ bias,
    u16* __restrict__ outb, int n)
{
    int wv = threadIdx.x >> 6, ln = threadIdx.x & 63;
    int i = blockIdx.x * 4 + wv;
    if (i >= n) return;
    int c = ln * 4;
    float di = dis[i], dd = di * di;
    u32 sv = *(const u32*)(ht + (size_t)i * 256 + c);
    f32x2 slo = __builtin_amdgcn_cvt_pk_f32_fp8(sv, false);
    f32x2 shi = __builtin_amdgcn_cvt_pk_f32_fp8(sv, true);
    float a0 = slo[0] * dd, a1 = slo[1] * dd, a2 = shi[0] * dd, a3 = shi[1] * dd;
    int beg = off[i], num = cnt[i];
    for (int base = 0; base < num; base += 64) {
        int rem = num - base; if (rem > 64) rem = 64;
        int sl = 0; float dsl = 0.f;
        if (ln < rem) { sl = srcs[beg + base + ln]; dsl = dis[sl]; }
        int j = 0;
        for (; j + 8 <= rem; j += 8) {
            int s[8]; float w[8]; u32 v[8];
            #pragma unroll
            for (int q = 0; q < 8; ++q) {
                s[q] = __shfl(sl, j + q);
                w[q] = __shfl(dsl, j + q) * di;
            }
            #pragma unroll
            for (int q = 0; q < 8; ++q)
                v[q] = *(const u32*)(ht + (size_t)s[q] * 256 + c);
            #pragma unroll
            for (int q = 0; q < 8; ++q) {
                f32x2 lo = __builtin_amdgcn_cvt_pk_f32_fp8(v[q], false);
                f32x2 hi = __builtin_amdgcn_cvt_pk_f32_fp8(v[q], true);
                a0 += lo[0] * w[q]; a1 += lo[1] * w[q];
                a2 += hi[0] * w[q]; a3 += hi[1] * w[q];
            }
        }
        for (; j + 4 <= rem; j += 4) {
            int s[4]; float w[4]; u32 v[4];
            #pragma unroll
            for (int q = 0; q < 4; ++q) {
                s[q] = __shfl(sl, j + q);
                w[q] = __shfl(dsl, j + q) * di;
            }
            #pragma unroll
            for (int q = 0; q < 4; ++q)
                v[q] = *(const u32*)(ht + (size_t)s[q] * 256 + c);
            #pragma unroll
            for (int q = 0; q < 4; ++q) {
                f32x2 lo = __builtin_amdgcn_cvt_pk_f32_fp8(v[q], false);
                f32x2 hi = __builtin_amdgcn_cvt_pk_f32_fp8(v[q], true);
                a0 += lo[0] * w[q]; a1 += lo[1] * w[q];
                a2 += hi[0] * w[q]; a3 += hi[1] * w[q];
            }
        }
        for (; j < rem; ++j) {
            int s0 = __shfl(sl, j);
            float w0 = __shfl(dsl, j) * di;
            u32 v0 = *(const u32*)(ht + (size_t)s0 * 256 + c);
            f32x2 lo = __builtin_amdgcn_cvt_pk_f32_fp8(v0, false);
            f32x2 hi = __builtin_amdgcn_cvt_pk_f32_fp8(v0, true);
            a0 += lo[0] * w0; a1 += lo[1] * w0;
            a2 += hi[0] * w0; a3 += hi[1] * w0;
        }
    }
    float4 bv = *(const float4*)(bias + c);
    ushort4 o;
    o.x = f2bf(fmaxf(a0 + bv.x, 0.f));
    o.y = f2bf(fmaxf(a1 + bv.y, 0.f));
    o.z = f2bf(fmaxf(a2 + bv.z, 0.f));
    o.w = f2bf(fmaxf(a3 + bv.w, 0.f));
    *(ushort4*)(outb + (size_t)i * 256 + c) = o;
}

// F=40 (stride 64 bf16): HALF-wave per node, uint loads (2 feats/lane)
__global__ __launch_bounds__(256) void agg40_bf16(
    const u16* __restrict__ ht,
    const int* __restrict__ off, const int* __restrict__ cnt,
    const int* __restrict__ srcs, const float* __restrict__ dis,
    const float* __restrict__ bias,
    u16* __restrict__ outb, int n)
{
    int half = threadIdx.x >> 5;
    int l = threadIdx.x & 31;
    int i = blockIdx.x * 8 + half;
    if (i >= n) return;
    int c2 = l * 2;
    float di = dis[i], dd = di * di;
    u32 sv = *(const u32*)(ht + (size_t)i * 64 + c2);
    float a0 = bf2f((u16)(sv & 0xffff)) * dd;
    float a1 = bf2f((u16)(sv >> 16)) * dd;
    int beg = off[i], num = cnt[i];
    for (int base = 0; base < num; base += 32) {
        int rem = num - base; if (rem > 32) rem = 32;
        int sl = 0; float dsl = 0.f;
        if (l < rem) { sl = srcs[beg + base + l]; dsl = dis[sl]; }
        int j = 0;
        for (; j + 8 <= rem; j += 8) {
            int s[8]; float w[8]; u32 v[8];
            #pragma unroll
            for (int q = 0; q < 8; ++q) {
                s[q] = __shfl(sl, j + q, 32);
                w[q] = __shfl(dsl, j + q, 32) * di;
            }
            #pragma unroll
            for (int q = 0; q < 8; ++q)
                v[q] = *(const u32*)(ht + (size_t)s[q] * 64 + c2);
            #pragma unroll
            for (int q = 0; q < 8; ++q) {
                a0 += bf2f((u16)(v[q] & 0xffff)) * w[q];
                a1 += bf2f((u16)(v[q] >> 16)) * w[q];
            }
        }
        for (; j + 4 <= rem; j += 4) {
            int s[4]; float w[4]; u32 v[4];
            #pragma unroll
            for (int q = 0; q < 4; ++q) {
                s[q] = __shfl(sl, j + q, 32);
                w[q] = __shfl(dsl, j + q, 32) * di;
            }
            #pragma unroll
            for (int q = 0; q < 4; ++q)
                v[q] = *(const u32*)(ht + (size_t)s[q] * 64 + c2);
            #pragma unroll
            for (int q = 0; q < 4; ++q) {
                a0 += bf2f((u16)(v[q] & 0xffff)) * w[q];
                a1 += bf2f((u16)(v[q] >> 16)) * w[q];
            }
        }
        for (; j < rem; ++j) {
            int s0 = __shfl(sl, j, 32);
            float w0 = __shfl(dsl, j, 32) * di;
            u32 v0 = *(const u32*)(ht + (size_t)s0 * 64 + c2);
            a0 += bf2f((u16)(v0 & 0xffff)) * w0;
            a1 += bf2f((u16)(v0 >> 16)) * w0;
        }
    }
    u32 o;
    if (l < 20) {
        float b0 = bias[c2], b1 = bias[c2 + 1];
        o = (u32)f2bf(fmaxf(a0 + b0, 0.f)) | ((u32)f2bf(fmaxf(a1 + b1, 0.f)) << 16);
    } else {
        o = 0u;
    }
    *(u32*)(outb + (size_t)i * 64 + c2) = o;
}

// ---------------- launch ----------------

extern "C" void kernel_launch(void* const* d_in, const int* in_sizes, int n_in,
                              void* d_out, int out_size, void* d_ws, size_t ws_size,
                              hipStream_t stream)
{
    const float* x  = (const float*)d_in[0];
    const int*   ei = (const int*)d_in[1];
    const float* W1 = (const float*)d_in[2];
    const float* b1 = (const float*)d_in[3];
    const float* W2 = (const float*)d_in[4];
    const float* b2 = (const float*)d_in[5];
    const float* W3 = (const float*)d_in[6];
    const float* b3 = (const float*)d_in[7];
    const float* lw = (const float*)d_in[8];
    const float* lb = (const float*)d_in[9];

    int N = in_sizes[0] / 256;
    int E = in_sizes[1] / 2;
    const int* erow = ei;       // source nodes
    const int* ecol = ei + E;   // target nodes

    char* ws = (char*)d_ws;
    size_t o = 0;
    auto alloc = [&](size_t bytes) -> void* {
        void* p = ws + o;
        o += (bytes + 255) & ~(size_t)255;
        return p;
    };
    int*   cnt  = (int*)alloc((size_t)N * 4);
    int*   off  = (int*)alloc((size_t)(N + 1) * 4);
    int*   fil  = (int*)alloc((size_t)N * 4);
    int*   bsum = (int*)alloc(1024 * 4);
    float* dis  = (float*)alloc((size_t)N * 4);
    int*   srcs = (int*)alloc((size_t)E * 4);
    u16*   W1t  = (u16*)alloc(256 * 256 * 2);
    u16*   W2t  = (u16*)alloc(256 * 256 * 2);
    u16*   W3t  = (u16*)alloc(128 * 256 * 2);
    u16*   lwAt = (u16*)alloc(128 * 256 * 2);
    u16*   lwBt = (u16*)alloc(128 * 256 * 2);
    u16*   lwCt = (u16*)alloc(128 * 64 * 2);
    u16*   xb   = (u16*)alloc((size_t)N * 256 * 2);
    u8*    htb  = (u8*)alloc((size_t)N * 256 * 2);   // fp8 [N][256] (alloc keeps bf16 size; tail reused as ht3b)
    u16*   h1b  = (u16*)alloc((size_t)N * 256 * 2);
    u16*   h2b  = (u16*)alloc((size_t)N * 256 * 2);
    u16*   h3b  = (u16*)alloc((size_t)N * 64 * 2);
    u16*   ht3b = (u16*)htb;                          // [N][64] bf16 view, reuse

    const int tb = 256;
    init_kernel<<<(N + tb - 1) / tb, tb, 0, stream>>>(cnt, N);
    hist_kernel<<<(E + tb - 1) / tb, tb, 0, stream>>>(ecol, cnt, E);
    int nb = (N + 511) / 512;
    scan1<<<nb, 512, 0, stream>>>(cnt, off, bsum, dis, N);
    scan2<<<1, 256, 0, stream>>>(bsum, nb);
    scan3<<<nb, 512, 0, stream>>>(off, fil, bsum, N);
    {
        const int npass = 8;
        int chunk = (N + npass - 1) / npass;
        fill_kernel<<<2048, 256, 0, stream>>>(erow, ecol, fil, srcs, E, chunk, npass);
    }

    cast_f2b<<<(N * 64 + tb - 1) / tb, tb, 0, stream>>>(x, xb, N * 64);
    prep_weights<<<(237568 + tb - 1) / tb, tb, 0, stream>>>(
        W1, W2, W3, lw, W1t, W2t, W3t, lwAt, lwBt, lwCt);

    dim3 gBig(1, (N + 127) / 128);
    int nAgg4 = (N + 3) / 4;
    int nAgg8 = (N + 7) / 8;

    // layer 1
    gemm256<<<gBig, 512, 0, stream>>>(xb, 256, W1t, 256, htb, N, 256);
    agg256_fp8<<<nAgg4, 256, 0, stream>>>(htb, off, cnt, srcs, dis, b1, h1b, N);
    // layer 2
    gemm256<<<gBig, 512, 0, stream>>>(h1b, 256, W2t, 256, htb, N, 256);
    agg256_fp8<<<nAgg4, 256, 0, stream>>>(htb, off, cnt, srcs, dis, b2, h2b, N);
    // layer 3
    gemm_w3<<<gBig, 256, 0, stream>>>(h2b, 256, W3t, 256, ht3b, 64, N, 40, 256);
    agg40_bf16<<<nAgg8, 256, 0, stream>>>(ht3b, off, cnt, srcs, dis, b3, h3b, N);

    // fused final projection + log_softmax
    gemm3_lsm<<<(N + 127) / 128, 256, 0, stream>>>(
        h1b, h2b, h3b, lwAt, lwBt, lwCt, lb, (float*)d_out, N);
}

// Round 8
// 466.235 us; speedup vs baseline: 3.6997x; 1.0047x over previous
//
#include <hip/hip_runtime.h>
#include <math.h>

typedef unsigned short u16;
typedef unsigned int u32;
typedef unsigned char u8;
typedef __attribute__((ext_vector_type(8))) short bf16x8;
typedef __attribute__((ext_vector_type(4))) float f32x4;
typedef __attribute__((ext_vector_type(2))) float f32x2;

__device__ __forceinline__ float bf2f(u16 u) {
    union { unsigned u; float f; } v; v.u = (unsigned)u << 16; return v.f;
}
__device__ __forceinline__ u16 f2bf(float f) {
    union { float f; unsigned u; } v; v.f = f;
    unsigned r = v.u + 0x7FFF + ((v.u >> 16) & 1);   // RNE
    return (u16)(r >> 16);
}

// ---------------- CSR build ----------------

__global__ void init_kernel(int* cnt, int n) {
    int i = blockIdx.x * blockDim.x + threadIdx.x;
    if (i < n) cnt[i] = 0;
}

__global__ void hist_kernel(const int* __restrict__ col, int* __restrict__ cnt, int e) {
    int i = blockIdx.x * blockDim.x + threadIdx.x;
    if (i < e) atomicAdd(&cnt[__builtin_nontemporal_load(&col[i])], 1);
}

// scan1 also emits dis[i] = rsqrt(deg_with_selfloop)
__global__ void scan1(const int* __restrict__ cnt, int* __restrict__ off,
                      int* __restrict__ bsum, float* __restrict__ dis, int n) {
    __shared__ int s[512];
    int t = threadIdx.x;
    int i = blockIdx.x * 512 + t;
    int v = (i < n) ? cnt[i] : 0;
    if (i < n) dis[i] = rsqrtf((float)v + 1.0f);
    s[t] = v; __syncthreads();
    for (int d = 1; d < 512; d <<= 1) {
        int a = (t >= d) ? s[t - d] : 0;
        __syncthreads();
        s[t] += a;
        __syncthreads();
    }
    if (i < n) off[i] = s[t] - v;
    if (t == 511) bsum[blockIdx.x] = s[511];
}

__global__ void scan2(int* bsum, int nb) {
    __shared__ int s[256];
    int t = threadIdx.x;
    int v = (t < nb) ? bsum[t] : 0;
    s[t] = v; __syncthreads();
    for (int d = 1; d < 256; d <<= 1) {
        int a = (t >= d) ? s[t - d] : 0;
        __syncthreads();
        s[t] += a;
        __syncthreads();
    }
    if (t < nb) bsum[t] = s[t] - v;
}

// scan3 also seeds fil[i] = off[i]
__global__ void scan3(int* off, int* fil, const int* __restrict__ bsum, int n) {
    int i = blockIdx.x * 512 + threadIdx.x;
    if (i < n) {
        int v = off[i] + bsum[blockIdx.x];
        off[i] = v;
        fil[i] = v;
    }
}

// Multi-pass predicated fill: pass p handles dst in [p*chunk,(p+1)*chunk).
// Scatter writes stay in an L2-resident window; edge-list reads are
// NON-TEMPORAL so they don't evict the partially-filled scatter lines.
__global__ void fill_kernel(const int* __restrict__ erow, const int* __restrict__ ecol,
                            int* __restrict__ fil, int* __restrict__ srcs,
                            int e, int chunk, int npass) {
    int stride = gridDim.x * blockDim.x;
    int t0 = blockIdx.x * blockDim.x + threadIdx.x;
    for (int p = 0; p < npass; ++p) {
        int lo = p * chunk, hi = lo + chunk;
        for (int i = t0; i < e; i += stride) {
            int c = __builtin_nontemporal_load(&ecol[i]);
            if (c >= lo && c < hi) {
                int r = __builtin_nontemporal_load(&erow[i]);
                int slot = atomicAdd(&fil[c], 1);
                srcs[slot] = r;
            }
        }
    }
}

// ---------------- casts ----------------

__global__ void cast_f2b(const float* __restrict__ in, u16* __restrict__ out, int n4) {
    int i = blockIdx.x * blockDim.x + threadIdx.x;
    if (i < n4) {
        float4 v = ((const float4*)in)[i];
        ushort4 o;
        o.x = f2bf(v.x); o.y = f2bf(v.y); o.z = f2bf(v.z); o.w = f2bf(v.w);
        ((ushort4*)out)[i] = o;
    }
}

// One kernel for all 6 weight transposes+casts.
__global__ void prep_weights(const float* __restrict__ W1, const float* __restrict__ W2,
                             const float* __restrict__ W3, const float* __restrict__ lw,
                             u16* __restrict__ W1t, u16* __restrict__ W2t,
                             u16* __restrict__ W3t, u16* __restrict__ lwAt,
                             u16* __restrict__ lwBt, u16* __restrict__ lwCt) {
    int idx = blockIdx.x * blockDim.x + threadIdx.x;
    if (idx < 65536) {                       // W1t [256][256] <- W1[k][n]
        int n = idx >> 8, k = idx & 255;
        W1t[idx] = f2bf(W1[k * 256 + n]);
    } else if (idx < 131072) {               // W2t
        int i = idx - 65536; int n = i >> 8, k = i & 255;
        W2t[i] = f2bf(W2[k * 256 + n]);
    } else if (idx < 163840) {               // W3t [128][256] <- W3[k][n], n<40
        int i = idx - 131072; int n = i >> 8, k = i & 255;
        W3t[i] = (n < 40) ? f2bf(W3[k * 40 + n]) : (u16)0;
    } else if (idx < 196608) {               // lwAt <- lw[k][n], k=0..255
        int i = idx - 163840; int n = i >> 8, k = i & 255;
        lwAt[i] = (n < 40) ? f2bf(lw[k * 40 + n]) : (u16)0;
    } else if (idx < 229376) {               // lwBt <- lw[256+k][n]
        int i = idx - 196608; int n = i >> 8, k = i & 255;
        lwBt[i] = (n < 40) ? f2bf(lw[(256 + k) * 40 + n]) : (u16)0;
    } else if (idx < 237568) {               // lwCt [128][64] <- lw[512+k][n], k<40
        int i = idx - 229376; int n = i >> 6, k = i & 63;
        lwCt[i] = (n < 40 && k < 40) ? f2bf(lw[(512 + k) * 40 + n]) : (u16)0;
    }
}

// ---------------- MFMA helpers ----------------

#define SWZ(row) ((((row) & 3) ^ (((row) >> 2) & 3)))

__device__ __forceinline__ void gload_lds16(const void* g, void* l) {
    __builtin_amdgcn_global_load_lds(
        (const __attribute__((address_space(1))) unsigned int*)g,
        (__attribute__((address_space(3))) unsigned int*)l, 16, 0, 0);
}

// ---------------- big GEMM: C[M,256] = A[M,K] @ Bt[256,K]^T, fp8(e4m3) out ----------------
// tile 128x256, BK=32, 8 waves (2x4), each wave 64x64.

__global__ __launch_bounds__(512) void gemm256(
    const u16* __restrict__ A, int lda,
    const u16* __restrict__ Bt, int ldb,
    u8* __restrict__ C,                 // [M][256] fp8
    int M, int K)
{
    __shared__ u16 As[128 * 32];   // 8 KB
    __shared__ u16 Bs[256 * 32];   // 16 KB
    int tid = threadIdx.x;
    int ln = tid & 63, wv = tid >> 6;
    int wr = wv >> 2, wc = wv & 3;
    int br = blockIdx.y * 128;

    f32x4 acc[4][4];
    #pragma unroll
    for (int m = 0; m < 4; ++m)
        #pragma unroll
        for (int n = 0; n < 4; ++n)
            acc[m][n] = (f32x4){0.f, 0.f, 0.f, 0.f};

    for (int k0 = 0; k0 < K; k0 += 32) {
        __syncthreads();
        {   // A: 512 chunks, 1/thread
            int l = tid;
            int row = l >> 2, sp = l & 3;
            int sl = sp ^ SWZ(row);
            int arow = br + row; if (arow >= M) arow = M - 1;
            gload_lds16(A + (size_t)arow * lda + k0 + sl * 8,
                        (char*)As + wv * 1024);
        }
        #pragma unroll
        for (int r = 0; r < 2; ++r) {   // B: 1024 chunks, 2/thread
            int l = r * 512 + tid;
            int row = l >> 2, sp = l & 3;
            int sl = sp ^ SWZ(row);
            gload_lds16(Bt + (size_t)row * ldb + k0 + sl * 8,
                        (char*)Bs + r * 8192 + wv * 1024);
        }
        __syncthreads();
        bf16x8 af[4], bf_[4];
        #pragma unroll
        for (int m = 0; m < 4; ++m) {
            int row = wr * 64 + m * 16 + (ln & 15);
            int sl = ((ln >> 4) ^ SWZ(row)) & 3;
            af[m] = *(const bf16x8*)((const char*)As + row * 64 + sl * 16);
        }
        #pragma unroll
        for (int n = 0; n < 4; ++n) {
            int row = wc * 64 + n * 16 + (ln & 15);
            int sl = ((ln >> 4) ^ SWZ(row)) & 3;
            bf_[n] = *(const bf16x8*)((const char*)Bs + row * 64 + sl * 16);
        }
        #pragma unroll
        for (int m = 0; m < 4; ++m)
            #pragma unroll
            for (int n = 0; n < 4; ++n)
                acc[m][n] = __builtin_amdgcn_mfma_f32_16x16x32_bf16(af[m], bf_[n], acc[m][n], 0, 0, 0);
    }

    #pragma unroll
    for (int m = 0; m < 4; ++m) {
        #pragma unroll
        for (int n = 0; n < 4; ++n) {
            #pragma unroll
            for (int j = 0; j < 4; ++j) {
                int r = br + wr * 64 + m * 16 + (ln >> 4) * 4 + j;
                int c = wc * 64 + n * 16 + (ln & 15);
                if (r < M) {
                    float v = acc[m][n][j];
                    u32 pk = __builtin_amdgcn_cvt_pk_fp8_f32(v, v, 0, false);
                    C[(size_t)r * 256 + c] = (u8)(pk & 0xff);
                }
            }
        }
    }
}

// ---------------- W3 GEMM: C[M,64] = A[M,K] @ Bt[64,K]^T, fp8 out ----------------
// tile 128x64, BK=32, 4 waves, each wave 32x64.

__global__ __launch_bounds__(256) void gemm_w3(
    const u16* __restrict__ A, int lda,
    const u16* __restrict__ Bt, int ldb,
    u8* __restrict__ C,                 // [M][64] fp8 (cols >=40 garbage-but-finite: B rows zeroed)
    int M, int K)
{
    __shared__ u16 As[128 * 32];
    __shared__ u16 Bs[64 * 32];
    int tid = threadIdx.x;
    int ln = tid & 63, wv = tid >> 6;
    int br = blockIdx.y * 128;

    f32x4 acc[2][4];
    #pragma unroll
    for (int m = 0; m < 2; ++m)
        #pragma unroll
        for (int n = 0; n < 4; ++n)
            acc[m][n] = (f32x4){0.f, 0.f, 0.f, 0.f};

    for (int k0 = 0; k0 < K; k0 += 32) {
        __syncthreads();
        #pragma unroll
        for (int r = 0; r < 2; ++r) {
            int l = r * 256 + tid;
            int row = l >> 2, sp = l & 3;
            int sl = sp ^ SWZ(row);
            int arow = br + row; if (arow >= M) arow = M - 1;
            gload_lds16(A + (size_t)arow * lda + k0 + sl * 8,
                        (char*)As + r * 4096 + wv * 1024);
        }
        {
            int l = tid;
            int row = l >> 2, sp = l & 3;
            int sl = sp ^ SWZ(row);
            gload_lds16(Bt + (size_t)row * ldb + k0 + sl * 8,
                        (char*)Bs + wv * 1024);
        }
        __syncthreads();
        bf16x8 af[2], bf_[4];
        #pragma unroll
        for (int m = 0; m < 2; ++m) {
            int row = wv * 32 + m * 16 + (ln & 15);
            int sl = ((ln >> 4) ^ SWZ(row)) & 3;
            af[m] = *(const bf16x8*)((const char*)As + row * 64 + sl * 16);
        }
        #pragma unroll
        for (int n = 0; n < 4; ++n) {
            int row = n * 16 + (ln & 15);
            int sl = ((ln >> 4) ^ SWZ(row)) & 3;
            bf_[n] = *(const bf16x8*)((const char*)Bs + row * 64 + sl * 16);
        }
        #pragma unroll
        for (int m = 0; m < 2; ++m)
            #pragma unroll
            for (int n = 0; n < 4; ++n)
                acc[m][n] = __builtin_amdgcn_mfma_f32_16x16x32_bf16(af[m], bf_[n], acc[m][n], 0, 0, 0);
    }

    #pragma unroll
    for (int m = 0; m < 2; ++m) {
        #pragma unroll
        for (int n = 0; n < 4; ++n) {
            #pragma unroll
            for (int j = 0; j < 4; ++j) {
                int r = br + wv * 32 + m * 16 + (ln >> 4) * 4 + j;
                int c = n * 16 + (ln & 15);
                if (r < M) {
                    float v = acc[m][n][j];
                    u32 pk = __builtin_amdgcn_cvt_pk_fp8_f32(v, v, 0, false);
                    C[(size_t)r * 64 + c] = (u8)(pk & 0xff);
                }
            }
        }
    }
}

// ---------------- fused final: out = lsm(h1@B0 + h2@B1 + h3@B2 + lb) ----------------

__global__ __launch_bounds__(256) void gemm3_lsm(
    const u16* __restrict__ A0, const u16* __restrict__ A1, const u16* __restrict__ A2,
    const u16* __restrict__ B0, const u16* __restrict__ B1, const u16* __restrict__ B2,
    const float* __restrict__ bias,
    float* __restrict__ out, int M)
{
    __shared__ u16 As[128 * 32];
    __shared__ u16 Bs[64 * 32];
    int tid = threadIdx.x;
    int ln = tid & 63, wv = tid >> 6;
    int br = blockIdx.x * 128;

    f32x4 acc[2][4];
    #pragma unroll
    for (int m = 0; m < 2; ++m)
        #pragma unroll
        for (int n = 0; n < 4; ++n)
            acc[m][n] = (f32x4){0.f, 0.f, 0.f, 0.f};

    auto do_seg = [&](const u16* __restrict__ A, const u16* __restrict__ B, int K) {
        for (int k0 = 0; k0 < K; k0 += 32) {
            __syncthreads();
            #pragma unroll
            for (int r = 0; r < 2; ++r) {
                int l = r * 256 + tid;
                int row = l >> 2, sp = l & 3;
                int sl = sp ^ SWZ(row);
                int arow = br + row; if (arow >= M) arow = M - 1;
                gload_lds16(A + (size_t)arow * K + k0 + sl * 8,
                            (char*)As + r * 4096 + wv * 1024);
            }
            {
                int l = tid;
                int row = l >> 2, sp = l & 3;
                int sl = sp ^ SWZ(row);
                gload_lds16(B + (size_t)row * K + k0 + sl * 8,
                            (char*)Bs + wv * 1024);
            }
            __syncthreads();
            bf16x8 af[2], bf_[4];
            #pragma unroll
            for (int m = 0; m < 2; ++m) {
                int row = wv * 32 + m * 16 + (ln & 15);
                int sl = ((ln >> 4) ^ SWZ(row)) & 3;
                af[m] = *(const bf16x8*)((const char*)As + row * 64 + sl * 16);
            }
            #pragma unroll
            for (int nn = 0; nn < 4; ++nn) {
                int row = nn * 16 + (ln & 15);
                int sl = ((ln >> 4) ^ SWZ(row)) & 3;
                bf_[nn] = *(const bf16x8*)((const char*)Bs + row * 64 + sl * 16);
            }
            #pragma unroll
            for (int m = 0; m < 2; ++m)
                #pragma unroll
                for (int nn = 0; nn < 4; ++nn)
                    acc[m][nn] = __builtin_amdgcn_mfma_f32_16x16x32_bf16(af[m], bf_[nn], acc[m][nn], 0, 0, 0);
        }
    };
    do_seg(A0, B0, 256);
    do_seg(A1, B1, 256);
    do_seg(A2, B2, 64);

    int l15 = ln & 15;
    #pragma unroll
    for (int m = 0; m < 2; ++m) {
        #pragma unroll
        for (int j = 0; j < 4; ++j) {
            int r = br + wv * 32 + m * 16 + (ln >> 4) * 4 + j;
            float v0 = acc[m][0][j] + bias[l15];
            float v1 = acc[m][1][j] + bias[16 + l15];
            float v2 = (l15 < 8) ? (acc[m][2][j] + bias[32 + l15]) : -INFINITY;
            float mx = fmaxf(fmaxf(v0, v1), v2);
            #pragma unroll
            for (int o = 8; o; o >>= 1) mx = fmaxf(mx, __shfl_xor(mx, o));
            float s = expf(v0 - mx) + expf(v1 - mx) + ((l15 < 8) ? expf(v2 - mx) : 0.f);
            #pragma unroll
            for (int o = 8; o; o >>= 1) s += __shfl_xor(s, o);
            float ls = logf(s);
            if (r < M) {
                out[(size_t)r * 40 + l15]      = v0 - mx - ls;
                out[(size_t)r * 40 + 16 + l15] = v1 - mx - ls;
                if (l15 < 8) out[(size_t)r * 40 + 32 + l15] = v2 - mx - ls;
            }
        }
    }
}

// ---------------- aggregation F=256 fp8: wave per node, 8-deep gather ----------------

__global__ __launch_bounds__(256) void agg256_fp8(
    const u8* __restrict__ ht,
    const int* __restrict__ off, const int* __restrict__ cnt,
    const int* __restrict__ srcs, const float* __restrict__ dis,
    const float* __restrict__ bias,
    u16* __restrict__ outb, int n)
{
    int wv = threadIdx.x >> 6, ln = threadIdx.x & 63;
    int i = blockIdx.x * 4 + wv;
    if (i >= n) return;
    int c = ln * 4;
    float di = dis[i], dd = di * di;
    u32 sv = *(const u32*)(ht + (size_t)i * 256 + c);
    f32x2 slo = __builtin_amdgcn_cvt_pk_f32_fp8(sv, false);
    f32x2 shi = __builtin_amdgcn_cvt_pk_f32_fp8(sv, true);
    float a0 = slo[0] * dd, a1 = slo[1] * dd, a2 = shi[0] * dd, a3 = shi[1] * dd;
    int beg = off[i], num = cnt[i];
    for (int base = 0; base < num; base += 64) {
        int rem = num - base; if (rem > 64) rem = 64;
        int sl = 0; float dsl = 0.f;
        if (ln < rem) { sl = srcs[beg + base + ln]; dsl = dis[sl]; }
        int j = 0;
        for (; j + 8 <= rem; j += 8) {
            int s[8]; float w[8]; u32 v[8];
            #pragma unroll
            for (int q = 0; q < 8; ++q) {
                s[q] = __shfl(sl, j + q);
                w[q] = __shfl(dsl, j + q) * di;
            }
            #pragma unroll
            for (int q = 0; q < 8; ++q)
                v[q] = *(const u32*)(ht + (size_t)s[q] * 256 + c);
            #pragma unroll
            for (int q = 0; q < 8; ++q) {
                f32x2 lo = __builtin_amdgcn_cvt_pk_f32_fp8(v[q], false);
                f32x2 hi = __builtin_amdgcn_cvt_pk_f32_fp8(v[q], true);
                a0 += lo[0] * w[q]; a1 += lo[1] * w[q];
                a2 += hi[0] * w[q]; a3 += hi[1] * w[q];
            }
        }
        for (; j + 4 <= rem; j += 4) {
            int s[4]; float w[4]; u32 v[4];
            #pragma unroll
            for (int q = 0; q < 4; ++q) {
                s[q] = __shfl(sl, j + q);
                w[q] = __shfl(dsl, j + q) * di;
            }
            #pragma unroll
            for (int q = 0; q < 4; ++q)
                v[q] = *(const u32*)(ht + (size_t)s[q] * 256 + c);
            #pragma unroll
            for (int q = 0; q < 4; ++q) {
                f32x2 lo = __builtin_amdgcn_cvt_pk_f32_fp8(v[q], false);
                f32x2 hi = __builtin_amdgcn_cvt_pk_f32_fp8(v[q], true);
                a0 += lo[0] * w[q]; a1 += lo[1] * w[q];
                a2 += hi[0] * w[q]; a3 += hi[1] * w[q];
            }
        }
        for (; j < rem; ++j) {
            int s0 = __shfl(sl, j);
            float w0 = __shfl(dsl, j) * di;
            u32 v0 = *(const u32*)(ht + (size_t)s0 * 256 + c);
            f32x2 lo = __builtin_amdgcn_cvt_pk_f32_fp8(v0, false);
            f32x2 hi = __builtin_amdgcn_cvt_pk_f32_fp8(v0, true);
            a0 += lo[0] * w0; a1 += lo[1] * w0;
            a2 += hi[0] * w0; a3 += hi[1] * w0;
        }
    }
    float4 bv = *(const float4*)(bias + c);
    ushort4 o;
    o.x = f2bf(fmaxf(a0 + bv.x, 0.f));
    o.y = f2bf(fmaxf(a1 + bv.y, 0.f));
    o.z = f2bf(fmaxf(a2 + bv.z, 0.f));
    o.w = f2bf(fmaxf(a3 + bv.w, 0.f));
    *(ushort4*)(outb + (size_t)i * 256 + c) = o;
}

// F=40 fp8 (stride 64 = one cache line/row): HALF-wave per node, u16 loads (2 feats/lane)
__global__ __launch_bounds__(256) void agg40_fp8(
    const u8* __restrict__ ht,
    const int* __restrict__ off, const int* __restrict__ cnt,
    const int* __restrict__ srcs, const float* __restrict__ dis,
    const float* __restrict__ bias,
    u16* __restrict__ outb, int n)
{
    int half = threadIdx.x >> 5;
    int l = threadIdx.x & 31;
    int i = blockIdx.x * 8 + half;
    if (i >= n) return;
    int c2 = l * 2;
    float di = dis[i], dd = di * di;
    u32 sv = (u32)*(const u16*)(ht + (size_t)i * 64 + c2);
    f32x2 sf = __builtin_amdgcn_cvt_pk_f32_fp8(sv, false);
    float a0 = sf[0] * dd, a1 = sf[1] * dd;
    int beg = off[i], num = cnt[i];
    for (int base = 0; base < num; base += 32) {
        int rem = num - base; if (rem > 32) rem = 32;
        int sl = 0; float dsl = 0.f;
        if (l < rem) { sl = srcs[beg + base + l]; dsl = dis[sl]; }
        int j = 0;
        for (; j + 8 <= rem; j += 8) {
            int s[8]; float w[8]; u32 v[8];
            #pragma unroll
            for (int q = 0; q < 8; ++q) {
                s[q] = __shfl(sl, j + q, 32);
                w[q] = __shfl(dsl, j + q, 32) * di;
            }
            #pragma unroll
            for (int q = 0; q < 8; ++q)
                v[q] = (u32)*(const u16*)(ht + (size_t)s[q] * 64 + c2);
            #pragma unroll
            for (int q = 0; q < 8; ++q) {
                f32x2 f = __builtin_amdgcn_cvt_pk_f32_fp8(v[q], false);
                a0 += f[0] * w[q]; a1 += f[1] * w[q];
            }
        }
        for (; j + 4 <= rem; j += 4) {
            int s[4]; float w[4]; u32 v[4];
            #pragma unroll
            for (int q = 0; q < 4; ++q) {
                s[q] = __shfl(sl, j + q, 32);
                w[q] = __shfl(dsl, j + q, 32) * di;
            }
            #pragma unroll
            for (int q = 0; q < 4; ++q)
                v[q] = (u32)*(const u16*)(ht + (size_t)s[q] * 64 + c2);
            #pragma unroll
            for (int q = 0; q < 4; ++q) {
                f32x2 f = __builtin_amdgcn_cvt_pk_f32_fp8(v[q], false);
                a0 += f[0] * w[q]; a1 += f[1] * w[q];
            }
        }
        for (; j < rem; ++j) {
            int s0 = __shfl(sl, j, 32);
            float w0 = __shfl(dsl, j, 32) * di;
            u32 v0 = (u32)*(const u16*)(ht + (size_t)s0 * 64 + c2);
            f32x2 f = __builtin_amdgcn_cvt_pk_f32_fp8(v0, false);
            a0 += f[0] * w0; a1 += f[1] * w0;
        }
    }
    u32 o;
    if (l < 20) {
        float b0 = bias[c2], b1 = bias[c2 + 1];
        o = (u32)f2bf(fmaxf(a0 + b0, 0.f)) | ((u32)f2bf(fmaxf(a1 + b1, 0.f)) << 16);
    } else {
        o = 0u;
    }
    *(u32*)(outb + (size_t)i * 64 + c2) = o;
}

// ---------------- launch ----------------

extern "C" void kernel_launch(void* const* d_in, const int* in_sizes, int n_in,
                              void* d_out, int out_size, void* d_ws, size_t ws_size,
                              hipStream_t stream)
{
    const float* x  = (const float*)d_in[0];
    const int*   ei = (const int*)d_in[1];
    const float* W1 = (const float*)d_in[2];
    const float* b1 = (const float*)d_in[3];
    const float* W2 = (const float*)d_in[4];
    const float* b2 = (const float*)d_in[5];
    const float* W3 = (const float*)d_in[6];
    const float* b3 = (const float*)d_in[7];
    const float* lw = (const float*)d_in[8];
    const float* lb = (const float*)d_in[9];

    int N = in_sizes[0] / 256;
    int E = in_sizes[1] / 2;
    const int* erow = ei;       // source nodes
    const int* ecol = ei + E;   // target nodes

    char* ws = (char*)d_ws;
    size_t o = 0;
    auto alloc = [&](size_t bytes) -> void* {
        void* p = ws + o;
        o += (bytes + 255) & ~(size_t)255;
        return p;
    };
    int*   cnt  = (int*)alloc((size_t)N * 4);
    int*   off  = (int*)alloc((size_t)(N + 1) * 4);
    int*   fil  = (int*)alloc((size_t)N * 4);
    int*   bsum = (int*)alloc(1024 * 4);
    float* dis  = (float*)alloc((size_t)N * 4);
    int*   srcs = (int*)alloc((size_t)E * 4);
    u16*   W1t  = (u16*)alloc(256 * 256 * 2);
    u16*   W2t  = (u16*)alloc(256 * 256 * 2);
    u16*   W3t  = (u16*)alloc(128 * 256 * 2);
    u16*   lwAt = (u16*)alloc(128 * 256 * 2);
    u16*   lwBt = (u16*)alloc(128 * 256 * 2);
    u16*   lwCt = (u16*)alloc(128 * 64 * 2);
    u16*   xb   = (u16*)alloc((size_t)N * 256 * 2);
    u8*    htb  = (u8*)alloc((size_t)N * 256 * 2);   // fp8 [N][256]; also reused as fp8 [N][64] ht3
    u16*   h1b  = (u16*)alloc((size_t)N * 256 * 2);
    u16*   h2b  = (u16*)alloc((size_t)N * 256 * 2);
    u16*   h3b  = (u16*)alloc((size_t)N * 64 * 2);
    u8*    ht3b = htb;                                // [N][64] fp8 view, reuse

    const int tb = 256;
    init_kernel<<<(N + tb - 1) / tb, tb, 0, stream>>>(cnt, N);
    hist_kernel<<<(E + tb - 1) / tb, tb, 0, stream>>>(ecol, cnt, E);
    int nb = (N + 511) / 512;
    scan1<<<nb, 512, 0, stream>>>(cnt, off, bsum, dis, N);
    scan2<<<1, 256, 0, stream>>>(bsum, nb);
    scan3<<<nb, 512, 0, stream>>>(off, fil, bsum, N);
    {
        const int npass = 8;
        int chunk = (N + npass - 1) / npass;
        fill_kernel<<<2048, 256, 0, stream>>>(erow, ecol, fil, srcs, E, chunk, npass);
    }

    cast_f2b<<<(N * 64 + tb - 1) / tb, tb, 0, stream>>>(x, xb, N * 64);
    prep_weights<<<(237568 + tb - 1) / tb, tb, 0, stream>>>(
        W1, W2, W3, lw, W1t, W2t, W3t, lwAt, lwBt, lwCt);

    dim3 gBig(1, (N + 127) / 128);
    int nAgg4 = (N + 3) / 4;
    int nAgg8 = (N + 7) / 8;

    // layer 1
    gemm256<<<gBig, 512, 0, stream>>>(xb, 256, W1t, 256, htb, N, 256);
    agg256_fp8<<<nAgg4, 256, 0, stream>>>(htb, off, cnt, srcs, dis, b1, h1b, N);
    // layer 2
    gemm256<<<gBig, 512, 0, stream>>>(h1b, 256, W2t, 256, htb, N, 256);
    agg256_fp8<<<nAgg4, 256, 0, stream>>>(htb, off, cnt, srcs, dis, b2, h2b, N);
    // layer 3 (fp8 path)
    gemm_w3<<<gBig, 256, 0, stream>>>(h2b, 256, W3t, 256, ht3b, N, 256);
    agg40_fp8<<<nAgg8, 256, 0, stream>>>(ht3b, off, cnt, srcs, dis, b3, h3b, N);

    // fused final projection + log_softmax
    gemm3_lsm<<<(N + 127) / 128, 256, 0, stream>>>(
        h1b, h2b, h3b, lwAt, lwBt, lwCt, lb, (float*)d_out, N);
}

// Round 9
// 451.900 us; speedup vs baseline: 3.8170x; 1.0317x over previous
//
#include <hip/hip_runtime.h>
#include <math.h>

typedef unsigned short u16;
typedef unsigned int u32;
typedef unsigned char u8;
typedef __attribute__((ext_vector_type(8))) short bf16x8;
typedef __attribute__((ext_vector_type(4))) float f32x4;
typedef __attribute__((ext_vector_type(2))) float f32x2;

__device__ __forceinline__ float bf2f(u16 u) {
    union { unsigned u; float f; } v; v.u = (unsigned)u << 16; return v.f;
}
__device__ __forceinline__ u16 f2bf(float f) {
    union { float f; unsigned u; } v; v.f = f;
    unsigned r = v.u + 0x7FFF + ((v.u >> 16) & 1);   // RNE
    return (u16)(r >> 16);
}

// ---------------- CSR build ----------------

__global__ void init_kernel(int* cnt, int n) {
    int i = blockIdx.x * blockDim.x + threadIdx.x;
    if (i < n) cnt[i] = 0;
}

__global__ void hist_kernel(const int* __restrict__ col, int* __restrict__ cnt, int e) {
    int i = blockIdx.x * blockDim.x + threadIdx.x;
    if (i < e) atomicAdd(&cnt[__builtin_nontemporal_load(&col[i])], 1);
}

// scan1 also emits dis[i] = rsqrt(deg_with_selfloop)
__global__ void scan1(const int* __restrict__ cnt, int* __restrict__ off,
                      int* __restrict__ bsum, float* __restrict__ dis, int n) {
    __shared__ int s[512];
    int t = threadIdx.x;
    int i = blockIdx.x * 512 + t;
    int v = (i < n) ? cnt[i] : 0;
    if (i < n) dis[i] = rsqrtf((float)v + 1.0f);
    s[t] = v; __syncthreads();
    for (int d = 1; d < 512; d <<= 1) {
        int a = (t >= d) ? s[t - d] : 0;
        __syncthreads();
        s[t] += a;
        __syncthreads();
    }
    if (i < n) off[i] = s[t] - v;
    if (t == 511) bsum[blockIdx.x] = s[511];
}

__global__ void scan2(int* bsum, int nb) {
    __shared__ int s[256];
    int t = threadIdx.x;
    int v = (t < nb) ? bsum[t] : 0;
    s[t] = v; __syncthreads();
    for (int d = 1; d < 256; d <<= 1) {
        int a = (t >= d) ? s[t - d] : 0;
        __syncthreads();
        s[t] += a;
        __syncthreads();
    }
    if (t < nb) bsum[t] = s[t] - v;
}

// scan3 also seeds fil[i] = off[i]
__global__ void scan3(int* off, int* fil, const int* __restrict__ bsum, int n) {
    int i = blockIdx.x * 512 + threadIdx.x;
    if (i < n) {
        int v = off[i] + bsum[blockIdx.x];
        off[i] = v;
        fil[i] = v;
    }
}

// XCD-cohort fill: cohort w = blockIdx.x & 7 (== XCD id under round-robin
// dispatch) handles only dst in window w. All scatter writes to a given
// srcs window then come from ONE XCD's L2 -> partial 64B lines merge in
// that L2 instead of being written back partially by 8 incoherent L2s.
// Correctness does not depend on the block->XCD mapping (slot uniqueness
// is from atomicAdd); the mapping only affects write locality.
__global__ void fill_kernel(const int* __restrict__ erow, const int* __restrict__ ecol,
                            int* __restrict__ fil, int* __restrict__ srcs,
                            int e, int chunk) {
    int w = blockIdx.x & 7;
    int rank = blockIdx.x >> 3;
    int cohortThreads = (gridDim.x >> 3) * blockDim.x;
    int t0 = rank * blockDim.x + threadIdx.x;
    int lo = w * chunk, hi = lo + chunk;
    for (int i = t0; i < e; i += cohortThreads) {
        int c = __builtin_nontemporal_load(&ecol[i]);
        if (c >= lo && c < hi) {
            int r = __builtin_nontemporal_load(&erow[i]);
            int slot = atomicAdd(&fil[c], 1);
            srcs[slot] = r;
        }
    }
}

// ---------------- casts ----------------

__global__ void cast_f2b(const float* __restrict__ in, u16* __restrict__ out, int n4) {
    int i = blockIdx.x * blockDim.x + threadIdx.x;
    if (i < n4) {
        float4 v = ((const float4*)in)[i];
        ushort4 o;
        o.x = f2bf(v.x); o.y = f2bf(v.y); o.z = f2bf(v.z); o.w = f2bf(v.w);
        ((ushort4*)out)[i] = o;
    }
}

// One kernel for all 6 weight transposes+casts.
__global__ void prep_weights(const float* __restrict__ W1, const float* __restrict__ W2,
                             const float* __restrict__ W3, const float* __restrict__ lw,
                             u16* __restrict__ W1t, u16* __restrict__ W2t,
                             u16* __restrict__ W3t, u16* __restrict__ lwAt,
                             u16* __restrict__ lwBt, u16* __restrict__ lwCt) {
    int idx = blockIdx.x * blockDim.x + threadIdx.x;
    if (idx < 65536) {                       // W1t [256][256] <- W1[k][n]
        int n = idx >> 8, k = idx & 255;
        W1t[idx] = f2bf(W1[k * 256 + n]);
    } else if (idx < 131072) {               // W2t
        int i = idx - 65536; int n = i >> 8, k = i & 255;
        W2t[i] = f2bf(W2[k * 256 + n]);
    } else if (idx < 163840) {               // W3t [128][256] <- W3[k][n], n<40
        int i = idx - 131072; int n = i >> 8, k = i & 255;
        W3t[i] = (n < 40) ? f2bf(W3[k * 40 + n]) : (u16)0;
    } else if (idx < 196608) {               // lwAt <- lw[k][n], k=0..255
        int i = idx - 163840; int n = i >> 8, k = i & 255;
        lwAt[i] = (n < 40) ? f2bf(lw[k * 40 + n]) : (u16)0;
    } else if (idx < 229376) {               // lwBt <- lw[256+k][n]
        int i = idx - 196608; int n = i >> 8, k = i & 255;
        lwBt[i] = (n < 40) ? f2bf(lw[(256 + k) * 40 + n]) : (u16)0;
    } else if (idx < 237568) {               // lwCt [128][64] <- lw[512+k][n], k<40
        int i = idx - 229376; int n = i >> 6, k = i & 63;
        lwCt[i] = (n < 40 && k < 40) ? f2bf(lw[(512 + k) * 40 + n]) : (u16)0;
    }
}

// ---------------- MFMA helpers ----------------

#define SWZ(row) ((((row) & 3) ^ (((row) >> 2) & 3)))

__device__ __forceinline__ void gload_lds16(const void* g, void* l) {
    __builtin_amdgcn_global_load_lds(
        (const __attribute__((address_space(1))) unsigned int*)g,
        (__attribute__((address_space(3))) unsigned int*)l, 16, 0, 0);
}

// ---------------- big GEMM: C[M,256] = A[M,K] @ Bt[256,K]^T, fp8(e4m3) out ----------------
// tile 128x256, BK=32, 8 waves (2x4), each wave 64x64.

__global__ __launch_bounds__(512) void gemm256(
    const u16* __restrict__ A, int lda,
    const u16* __restrict__ Bt, int ldb,
    u8* __restrict__ C,                 // [M][256] fp8
    int M, int K)
{
    __shared__ u16 As[128 * 32];   // 8 KB
    __shared__ u16 Bs[256 * 32];   // 16 KB
    int tid = threadIdx.x;
    int ln = tid & 63, wv = tid >> 6;
    int wr = wv >> 2, wc = wv & 3;
    int br = blockIdx.y * 128;

    f32x4 acc[4][4];
    #pragma unroll
    for (int m = 0; m < 4; ++m)
        #pragma unroll
        for (int n = 0; n < 4; ++n)
            acc[m][n] = (f32x4){0.f, 0.f, 0.f, 0.f};

    for (int k0 = 0; k0 < K; k0 += 32) {
        __syncthreads();
        {   // A: 512 chunks, 1/thread
            int l = tid;
            int row = l >> 2, sp = l & 3;
            int sl = sp ^ SWZ(row);
            int arow = br + row; if (arow >= M) arow = M - 1;
            gload_lds16(A + (size_t)arow * lda + k0 + sl * 8,
                        (char*)As + wv * 1024);
        }
        #pragma unroll
        for (int r = 0; r < 2; ++r) {   // B: 1024 chunks, 2/thread
            int l = r * 512 + tid;
            int row = l >> 2, sp = l & 3;
            int sl = sp ^ SWZ(row);
            gload_lds16(Bt + (size_t)row * ldb + k0 + sl * 8,
                        (char*)Bs + r * 8192 + wv * 1024);
        }
        __syncthreads();
        bf16x8 af[4], bf_[4];
        #pragma unroll
        for (int m = 0; m < 4; ++m) {
            int row = wr * 64 + m * 16 + (ln & 15);
            int sl = ((ln >> 4) ^ SWZ(row)) & 3;
            af[m] = *(const bf16x8*)((const char*)As + row * 64 + sl * 16);
        }
        #pragma unroll
        for (int n = 0; n < 4; ++n) {
            int row = wc * 64 + n * 16 + (ln & 15);
            int sl = ((ln >> 4) ^ SWZ(row)) & 3;
            bf_[n] = *(const bf16x8*)((const char*)Bs + row * 64 + sl * 16);
        }
        #pragma unroll
        for (int m = 0; m < 4; ++m)
            #pragma unroll
            for (int n = 0; n < 4; ++n)
                acc[m][n] = __builtin_amdgcn_mfma_f32_16x16x32_bf16(af[m], bf_[n], acc[m][n], 0, 0, 0);
    }

    #pragma unroll
    for (int m = 0; m < 4; ++m) {
        #pragma unroll
        for (int n = 0; n < 4; ++n) {
            #pragma unroll
            for (int j = 0; j < 4; ++j) {
                int r = br + wr * 64 + m * 16 + (ln >> 4) * 4 + j;
                int c = wc * 64 + n * 16 + (ln & 15);
                if (r < M) {
                    float v = acc[m][n][j];
                    u32 pk = __builtin_amdgcn_cvt_pk_fp8_f32(v, v, 0, false);
                    C[(size_t)r * 256 + c] = (u8)(pk & 0xff);
                }
            }
        }
    }
}

// ---------------- W3 GEMM: C[M,64] = A[M,K] @ Bt[64,K]^T, fp8 out ----------------
// tile 128x64, BK=32, 4 waves, each wave 32x64.

__global__ __launch_bounds__(256) void gemm_w3(
    const u16* __restrict__ A, int lda,
    const u16* __restrict__ Bt, int ldb,
    u8* __restrict__ C,                 // [M][64] fp8 (cols >=40 garbage-but-finite: B rows zeroed)
    int M, int K)
{
    __shared__ u16 As[128 * 32];
    __shared__ u16 Bs[64 * 32];
    int tid = threadIdx.x;
    int ln = tid & 63, wv = tid >> 6;
    int br = blockIdx.y * 128;

    f32x4 acc[2][4];
    #pragma unroll
    for (int m = 0; m < 2; ++m)
        #pragma unroll
        for (int n = 0; n < 4; ++n)
            acc[m][n] = (f32x4){0.f, 0.f, 0.f, 0.f};

    for (int k0 = 0; k0 < K; k0 += 32) {
        __syncthreads();
        #pragma unroll
        for (int r = 0; r < 2; ++r) {
            int l = r * 256 + tid;
            int row = l >> 2, sp = l & 3;
            int sl = sp ^ SWZ(row);
            int arow = br + row; if (arow >= M) arow = M - 1;
            gload_lds16(A + (size_t)arow * lda + k0 + sl * 8,
                        (char*)As + r * 4096 + wv * 1024);
        }
        {
            int l = tid;
            int row = l >> 2, sp = l & 3;
            int sl = sp ^ SWZ(row);
            gload_lds16(Bt + (size_t)row * ldb + k0 + sl * 8,
                        (char*)Bs + wv * 1024);
        }
        __syncthreads();
        bf16x8 af[2], bf_[4];
        #pragma unroll
        for (int m = 0; m < 2; ++m) {
            int row = wv * 32 + m * 16 + (ln & 15);
            int sl = ((ln >> 4) ^ SWZ(row)) & 3;
            af[m] = *(const bf16x8*)((const char*)As + row * 64 + sl * 16);
        }
        #pragma unroll
        for (int n = 0; n < 4; ++n) {
            int row = n * 16 + (ln & 15);
            int sl = ((ln >> 4) ^ SWZ(row)) & 3;
            bf_[n] = *(const bf16x8*)((const char*)Bs + row * 64 + sl * 16);
        }
        #pragma unroll
        for (int m = 0; m < 2; ++m)
            #pragma unroll
            for (int n = 0; n < 4; ++n)
                acc[m][n] = __builtin_amdgcn_mfma_f32_16x16x32_bf16(af[m], bf_[n], acc[m][n], 0, 0, 0);
    }

    #pragma unroll
    for (int m = 0; m < 2; ++m) {
        #pragma unroll
        for (int n = 0; n < 4; ++n) {
            #pragma unroll
            for (int j = 0; j < 4; ++j) {
                int r = br + wv * 32 + m * 16 + (ln >> 4) * 4 + j;
                int c = n * 16 + (ln & 15);
                if (r < M) {
                    float v = acc[m][n][j];
                    u32 pk = __builtin_amdgcn_cvt_pk_fp8_f32(v, v, 0, false);
                    C[(size_t)r * 64 + c] = (u8)(pk & 0xff);
                }
            }
        }
    }
}

// ---------------- fused final: out = lsm(h1@B0 + h2@B1 + h3@B2 + lb) ----------------

__global__ __launch_bounds__(256) void gemm3_lsm(
    const u16* __restrict__ A0, const u16* __restrict__ A1, const u16* __restrict__ A2,
    const u16* __restrict__ B0, const u16* __restrict__ B1, const u16* __restrict__ B2,
    const float* __restrict__ bias,
    float* __restrict__ out, int M)
{
    __shared__ u16 As[128 * 32];
    __shared__ u16 Bs[64 * 32];
    int tid = threadIdx.x;
    int ln = tid & 63, wv = tid >> 6;
    int br = blockIdx.x * 128;

    f32x4 acc[2][4];
    #pragma unroll
    for (int m = 0; m < 2; ++m)
        #pragma unroll
        for (int n = 0; n < 4; ++n)
            acc[m][n] = (f32x4){0.f, 0.f, 0.f, 0.f};

    auto do_seg = [&](const u16* __restrict__ A, const u16* __restrict__ B, int K) {
        for (int k0 = 0; k0 < K; k0 += 32) {
            __syncthreads();
            #pragma unroll
            for (int r = 0; r < 2; ++r) {
                int l = r * 256 + tid;
                int row = l >> 2, sp = l & 3;
                int sl = sp ^ SWZ(row);
                int arow = br + row; if (arow >= M) arow = M - 1;
                gload_lds16(A + (size_t)arow * K + k0 + sl * 8,
                            (char*)As + r * 4096 + wv * 1024);
            }
            {
                int l = tid;
                int row = l >> 2, sp = l & 3;
                int sl = sp ^ SWZ(row);
                gload_lds16(B + (size_t)row * K + k0 + sl * 8,
                            (char*)Bs + wv * 1024);
            }
            __syncthreads();
            bf16x8 af[2], bf_[4];
            #pragma unroll
            for (int m = 0; m < 2; ++m) {
                int row = wv * 32 + m * 16 + (ln & 15);
                int sl = ((ln >> 4) ^ SWZ(row)) & 3;
                af[m] = *(const bf16x8*)((const char*)As + row * 64 + sl * 16);
            }
            #pragma unroll
            for (int nn = 0; nn < 4; ++nn) {
                int row = nn * 16 + (ln & 15);
                int sl = ((ln >> 4) ^ SWZ(row)) & 3;
                bf_[nn] = *(const bf16x8*)((const char*)Bs + row * 64 + sl * 16);
            }
            #pragma unroll
            for (int m = 0; m < 2; ++m)
                #pragma unroll
                for (int nn = 0; nn < 4; ++nn)
                    acc[m][nn] = __builtin_amdgcn_mfma_f32_16x16x32_bf16(af[m], bf_[nn], acc[m][nn], 0, 0, 0);
        }
    };
    do_seg(A0, B0, 256);
    do_seg(A1, B1, 256);
    do_seg(A2, B2, 64);

    int l15 = ln & 15;
    #pragma unroll
    for (int m = 0; m < 2; ++m) {
        #pragma unroll
        for (int j = 0; j < 4; ++j) {
            int r = br + wv * 32 + m * 16 + (ln >> 4) * 4 + j;
            float v0 = acc[m][0][j] + bias[l15];
            float v1 = acc[m][1][j] + bias[16 + l15];
            float v2 = (l15 < 8) ? (acc[m][2][j] + bias[32 + l15]) : -INFINITY;
            float mx = fmaxf(fmaxf(v0, v1), v2);
            #pragma unroll
            for (int o = 8; o; o >>= 1) mx = fmaxf(mx, __shfl_xor(mx, o));
            float s = expf(v0 - mx) + expf(v1 - mx) + ((l15 < 8) ? expf(v2 - mx) : 0.f);
            #pragma unroll
            for (int o = 8; o; o >>= 1) s += __shfl_xor(s, o);
            float ls = logf(s);
            if (r < M) {
                out[(size_t)r * 40 + l15]      = v0 - mx - ls;
                out[(size_t)r * 40 + 16 + l15] = v1 - mx - ls;
                if (l15 < 8) out[(size_t)r * 40 + 32 + l15] = v2 - mx - ls;
            }
        }
    }
}

// ---------------- aggregation F=256 fp8: wave per node, 8-deep gather ----------------

__global__ __launch_bounds__(256) void agg256_fp8(
    const u8* __restrict__ ht,
    const int* __restrict__ off, const int* __restrict__ cnt,
    const int* __restrict__ srcs, const float* __restrict__ dis,
    const float* __restrict__ bias,
    u16* __restrict__ outb, int n)
{
    int wv = threadIdx.x >> 6, ln = threadIdx.x & 63;
    int i = blockIdx.x * 4 + wv;
    if (i >= n) return;
    int c = ln * 4;
    float di = dis[i], dd = di * di;
    u32 sv = *(const u32*)(ht + (size_t)i * 256 + c);
    f32x2 slo = __builtin_amdgcn_cvt_pk_f32_fp8(sv, false);
    f32x2 shi = __builtin_amdgcn_cvt_pk_f32_fp8(sv, true);
    float a0 = slo[0] * dd, a1 = slo[1] * dd, a2 = shi[0] * dd, a3 = shi[1] * dd;
    int beg = off[i], num = cnt[i];
    for (int base = 0; base < num; base += 64) {
        int rem = num - base; if (rem > 64) rem = 64;
        int sl = 0; float dsl = 0.f;
        if (ln < rem) { sl = srcs[beg + base + ln]; dsl = dis[sl]; }
        int j = 0;
        for (; j + 8 <= rem; j += 8) {
            int s[8]; float w[8]; u32 v[8];
            #pragma unroll
            for (int q = 0; q < 8; ++q) {
                s[q] = __shfl(sl, j + q);
                w[q] = __shfl(dsl, j + q) * di;
            }
            #pragma unroll
            for (int q = 0; q < 8; ++q)
                v[q] = *(const u32*)(ht + (size_t)s[q] * 256 + c);
            #pragma unroll
            for (int q = 0; q < 8; ++q) {
                f32x2 lo = __builtin_amdgcn_cvt_pk_f32_fp8(v[q], false);
                f32x2 hi = __builtin_amdgcn_cvt_pk_f32_fp8(v[q], true);
                a0 += lo[0] * w[q]; a1 += lo[1] * w[q];
                a2 += hi[0] * w[q]; a3 += hi[1] * w[q];
            }
        }
        for (; j + 4 <= rem; j += 4) {
            int s[4]; float w[4]; u32 v[4];
            #pragma unroll
            for (int q = 0; q < 4; ++q) {
                s[q] = __shfl(sl, j + q);
                w[q] = __shfl(dsl, j + q) * di;
            }
            #pragma unroll
            for (int q = 0; q < 4; ++q)
                v[q] = *(const u32*)(ht + (size_t)s[q] * 256 + c);
            #pragma unroll
            for (int q = 0; q < 4; ++q) {
                f32x2 lo = __builtin_amdgcn_cvt_pk_f32_fp8(v[q], false);
                f32x2 hi = __builtin_amdgcn_cvt_pk_f32_fp8(v[q], true);
                a0 += lo[0] * w[q]; a1 += lo[1] * w[q];
                a2 += hi[0] * w[q]; a3 += hi[1] * w[q];
            }
        }
        for (; j < rem; ++j) {
            int s0 = __shfl(sl, j);
            float w0 = __shfl(dsl, j) * di;
            u32 v0 = *(const u32*)(ht + (size_t)s0 * 256 + c);
            f32x2 lo = __builtin_amdgcn_cvt_pk_f32_fp8(v0, false);
            f32x2 hi = __builtin_amdgcn_cvt_pk_f32_fp8(v0, true);
            a0 += lo[0] * w0; a1 += lo[1] * w0;
            a2 += hi[0] * w0; a3 += hi[1] * w0;
        }
    }
    float4 bv = *(const float4*)(bias + c);
    ushort4 o;
    o.x = f2bf(fmaxf(a0 + bv.x, 0.f));
    o.y = f2bf(fmaxf(a1 + bv.y, 0.f));
    o.z = f2bf(fmaxf(a2 + bv.z, 0.f));
    o.w = f2bf(fmaxf(a3 + bv.w, 0.f));
    *(ushort4*)(outb + (size_t)i * 256 + c) = o;
}

// F=40 fp8 (stride 64 = one cache line/row): HALF-wave per node, u16 loads (2 feats/lane)
__global__ __launch_bounds__(256) void agg40_fp8(
    const u8* __restrict__ ht,
    const int* __restrict__ off, const int* __restrict__ cnt,
    const int* __restrict__ srcs, const float* __restrict__ dis,
    const float* __restrict__ bias,
    u16* __restrict__ outb, int n)
{
    int half = threadIdx.x >> 5;
    int l = threadIdx.x & 31;
    int i = blockIdx.x * 8 + half;
    if (i >= n) return;
    int c2 = l * 2;
    float di = dis[i], dd = di * di;
    u32 sv = (u32)*(const u16*)(ht + (size_t)i * 64 + c2);
    f32x2 sf = __builtin_amdgcn_cvt_pk_f32_fp8(sv, false);
    float a0 = sf[0] * dd, a1 = sf[1] * dd;
    int beg = off[i], num = cnt[i];
    for (int base = 0; base < num; base += 32) {
        int rem = num - base; if (rem > 32) rem = 32;
        int sl = 0; float dsl = 0.f;
        if (l < rem) { sl = srcs[beg + base + l]; dsl = dis[sl]; }
        int j = 0;
        for (; j + 8 <= rem; j += 8) {
            int s[8]; float w[8]; u32 v[8];
            #pragma unroll
            for (int q = 0; q < 8; ++q) {
                s[q] = __shfl(sl, j + q, 32);
                w[q] = __shfl(dsl, j + q, 32) * di;
            }
            #pragma unroll
            for (int q = 0; q < 8; ++q)
                v[q] = (u32)*(const u16*)(ht + (size_t)s[q] * 64 + c2);
            #pragma unroll
            for (int q = 0; q < 8; ++q) {
                f32x2 f = __builtin_amdgcn_cvt_pk_f32_fp8(v[q], false);
                a0 += f[0] * w[q]; a1 += f[1] * w[q];
            }
        }
        for (; j + 4 <= rem; j += 4) {
            int s[4]; float w[4]; u32 v[4];
            #pragma unroll
            for (int q = 0; q < 4; ++q) {
                s[q] = __shfl(sl, j + q, 32);
                w[q] = __shfl(dsl, j + q, 32) * di;
            }
            #pragma unroll
            for (int q = 0; q < 4; ++q)
                v[q] = (u32)*(const u16*)(ht + (size_t)s[q] * 64 + c2);
            #pragma unroll
            for (int q = 0; q < 4; ++q) {
                f32x2 f = __builtin_amdgcn_cvt_pk_f32_fp8(v[q], false);
                a0 += f[0] * w[q]; a1 += f[1] * w[q];
            }
        }
        for (; j < rem; ++j) {
            int s0 = __shfl(sl, j, 32);
            float w0 = __shfl(dsl, j, 32) * di;
            u32 v0 = (u32)*(const u16*)(ht + (size_t)s0 * 64 + c2);
            f32x2 f = __builtin_amdgcn_cvt_pk_f32_fp8(v0, false);
            a0 += f[0] * w0; a1 += f[1] * w0;
        }
    }
    u32 o;
    if (l < 20) {
        float b0 = bias[c2], b1 = bias[c2 + 1];
        o = (u32)f2bf(fmaxf(a0 + b0, 0.f)) | ((u32)f2bf(fmaxf(a1 + b1, 0.f)) << 16);
    } else {
        o = 0u;
    }
    *(u32*)(outb + (size_t)i * 64 + c2) = o;
}

// ---------------- launch ----------------

extern "C" void kernel_launch(void* const* d_in, const int* in_sizes, int n_in,
                              void* d_out, int out_size, void* d_ws, size_t ws_size,
                              hipStream_t stream)
{
    const float* x  = (const float*)d_in[0];
    const int*   ei = (const int*)d_in[1];
    const float* W1 = (const float*)d_in[2];
    const float* b1 = (const float*)d_in[3];
    const float* W2 = (const float*)d_in[4];
    const float* b2 = (const float*)d_in[5];
    const float* W3 = (const float*)d_in[6];
    const float* b3 = (const float*)d_in[7];
    const float* lw = (const float*)d_in[8];
    const float* lb = (const float*)d_in[9];

    int N = in_sizes[0] / 256;
    int E = in_sizes[1] / 2;
    const int* erow = ei;       // source nodes
    const int* ecol = ei + E;   // target nodes

    char* ws = (char*)d_ws;
    size_t o = 0;
    auto alloc = [&](size_t bytes) -> void* {
        void* p = ws + o;
        o += (bytes + 255) & ~(size_t)255;
        return p;
    };
    int*   cnt  = (int*)alloc((size_t)N * 4);
    int*   off  = (int*)alloc((size_t)(N + 1) * 4);
    int*   fil  = (int*)alloc((size_t)N * 4);
    int*   bsum = (int*)alloc(1024 * 4);
    float* dis  = (float*)alloc((size_t)N * 4);
    int*   srcs = (int*)alloc((size_t)E * 4);
    u16*   W1t  = (u16*)alloc(256 * 256 * 2);
    u16*   W2t  = (u16*)alloc(256 * 256 * 2);
    u16*   W3t  = (u16*)alloc(128 * 256 * 2);
    u16*   lwAt = (u16*)alloc(128 * 256 * 2);
    u16*   lwBt = (u16*)alloc(128 * 256 * 2);
    u16*   lwCt = (u16*)alloc(128 * 64 * 2);
    u16*   xb   = (u16*)alloc((size_t)N * 256 * 2);
    u8*    htb  = (u8*)alloc((size_t)N * 256 * 2);   // fp8 [N][256]; also reused as fp8 [N][64] ht3
    u16*   h1b  = (u16*)alloc((size_t)N * 256 * 2);
    u16*   h2b  = (u16*)alloc((size_t)N * 256 * 2);
    u16*   h3b  = (u16*)alloc((size_t)N * 64 * 2);
    u8*    ht3b = htb;                                // [N][64] fp8 view, reuse

    const int tb = 256;
    init_kernel<<<(N + tb - 1) / tb, tb, 0, stream>>>(cnt, N);
    hist_kernel<<<(E + tb - 1) / tb, tb, 0, stream>>>(ecol, cnt, E);
    int nb = (N + 511) / 512;
    scan1<<<nb, 512, 0, stream>>>(cnt, off, bsum, dis, N);
    scan2<<<1, 256, 0, stream>>>(bsum, nb);
    scan3<<<nb, 512, 0, stream>>>(off, fil, bsum, N);
    {
        int chunk = (N + 7) / 8;   // 8 dst windows, one per XCD cohort
        fill_kernel<<<2048, 256, 0, stream>>>(erow, ecol, fil, srcs, E, chunk);
    }

    cast_f2b<<<(N * 64 + tb - 1) / tb, tb, 0, stream>>>(x, xb, N * 64);
    prep_weights<<<(237568 + tb - 1) / tb, tb, 0, stream>>>(
        W1, W2, W3, lw, W1t, W2t, W3t, lwAt, lwBt, lwCt);

    dim3 gBig(1, (N + 127) / 128);
    int nAgg4 = (N + 3) / 4;
    int nAgg8 = (N + 7) / 8;

    // layer 1
    gemm256<<<gBig, 512, 0, stream>>>(xb, 256, W1t, 256, htb, N, 256);
    agg256_fp8<<<nAgg4, 256, 0, stream>>>(htb, off, cnt, srcs, dis, b1, h1b, N);
    // layer 2
    gemm256<<<gBig, 512, 0, stream>>>(h1b, 256, W2t, 256, htb, N, 256);
    agg256_fp8<<<nAgg4, 256, 0, stream>>>(htb, off, cnt, srcs, dis, b2, h2b, N);
    // layer 3 (fp8 path)
    gemm_w3<<<gBig, 256, 0, stream>>>(h2b, 256, W3t, 256, ht3b, N, 256);
    agg40_fp8<<<nAgg8, 256, 0, stream>>>(ht3b, off, cnt, srcs, dis, b3, h3b, N);

    // fused final projection + log_softmax
    gemm3_lsm<<<(N + 127) / 128, 256, 0, stream>>>(
        h1b, h2b, h3b, lwAt, lwBt, lwCt, lb, (float*)d_out, N);
}